// Round 2
// baseline (2490.393 us; speedup 1.0000x reference)
//
#include <hip/hip_runtime.h>
#include <hip/hip_bf16.h>
#include <math.h>

#define DI __device__ __forceinline__

constexpr int B = 8, C = 64, H = 128, W = 128, N = H * W;   // N = 16384
constexpr int HID = 170;
constexpr int QKVC = 3 * C;                                 // 192

DI float gelu_exact(float v) {
    return 0.5f * v * (1.0f + erff(v * 0.70710678118654752f));
}

// =========== fused LN + conv1x1(64->192) + dwconv3x3, tiled 16x16 (+halo 18x18) ===========
// ROLL: operate in rolled coordinate space (RSA pre-shift by -4): value at rolled coord r
// comes from source pixel (r+4)&127; dwconv zero-pad applies at rolled-canvas boundary.
template<bool ROLL>
__global__ __launch_bounds__(384) void cdw_kernel(
    const float* __restrict__ src,   // (B,64,N)
    const float* __restrict__ lnw, const float* __restrict__ lnb,
    const float* __restrict__ cw,    // (192,64)
    const float* __restrict__ dww,   // (192,1,3,3) -> rows of 9
    float* __restrict__ out)         // (B,192,N)
{
    __shared__ float cbuf[32 * 324];
    int blk = blockIdx.x;            // b*64 + tile
    int b = blk >> 6, tile = blk & 63;
    int ty0 = (tile >> 3) * 16, tx0 = (tile & 7) * 16;
    int t = threadIdx.x;
    float vals[64];
    bool ha = t < 324;
    bool inb = false;
    if (ha) {
        int hy = ty0 - 1 + t / 18;
        int hx = tx0 - 1 + t % 18;
        inb = (hy >= 0 && hy < 128 && hx >= 0 && hx < 128);
        if (inb) {
            int sy = ROLL ? ((hy + 4) & 127) : hy;
            int sx = ROLL ? ((hx + 4) & 127) : hx;
            const float* sb = src + (size_t)b * 64 * N + sy * W + sx;
            float s = 0.f;
#pragma unroll
            for (int c = 0; c < 64; ++c) { vals[c] = sb[(size_t)c * N]; s += vals[c]; }
            float mu = s * (1.0f / 64.0f);
            float vs = 0.f;
#pragma unroll
            for (int c = 0; c < 64; ++c) { float d = vals[c] - mu; vals[c] = d; vs += d * d; }
            float rstd = rsqrtf(vs * (1.0f / 64.0f) + 1e-5f);
#pragma unroll
            for (int c = 0; c < 64; ++c) vals[c] = vals[c] * rstd * lnw[c] + lnb[c];
        }
    }
    if (!ha || !inb) {
#pragma unroll
        for (int c = 0; c < 64; ++c) vals[c] = 0.f;
    }
    int h00 = (t >> 4) * 18 + (t & 15);               // top-left halo idx for center t<256
    int gout = (ty0 + (t >> 4)) * W + tx0 + (t & 15); // center global pixel (rolled space if ROLL)
    for (int ch = 0; ch < 6; ++ch) {
        if (ha) {
            for (int j = 0; j < 32; ++j) {
                const float* wr = cw + (ch * 32 + j) * 64;   // uniform -> s_load
                float a0 = 0.f, a1 = 0.f;
#pragma unroll
                for (int c = 0; c < 64; c += 2) { a0 += wr[c] * vals[c]; a1 += wr[c + 1] * vals[c + 1]; }
                cbuf[j * 324 + t] = a0 + a1;
            }
        }
        __syncthreads();
        if (t < 256) {
            for (int j = 0; j < 32; ++j) {
                const float* wd = dww + (ch * 32 + j) * 9;   // uniform -> s_load
                const float* cb = cbuf + j * 324 + h00;
                float a = wd[0] * cb[0]  + wd[1] * cb[1]  + wd[2] * cb[2]
                        + wd[3] * cb[18] + wd[4] * cb[19] + wd[5] * cb[20]
                        + wd[6] * cb[36] + wd[7] * cb[37] + wd[8] * cb[38];
                out[((size_t)b * QKVC + ch * 32 + j) * N + gout] = a;
            }
        }
        __syncthreads();
    }
}

// =========== RSA window attention + fused proj; one block per 8x8 window ===========
// reads qkv (B,192,N) in rolled space; writes x_ (B,64,N) with merge + roll(+4) applied
__global__ __launch_bounds__(256) void rsa_win_kernel(
    const float* __restrict__ qkv, const float* __restrict__ temp_p,
    const float* __restrict__ projw, float* __restrict__ out)
{
    __shared__ float qs[64 * 65];   // [p][c] stride 65; later overlaid by attn[c][d] stride 65
    __shared__ float ks[64 * 65];   // [p][c]; later overlaid by o[p][d] stride 65
    __shared__ float vt[64 * 64];   // [c][p]
    __shared__ float pwb[64 * 65];  // proj w [o][d] stride 65
    __shared__ float rq[64], rk[64];
    int blk = blockIdx.x;
    int b = blk >> 8, win = blk & 255;
    int y0 = (win >> 4) * 8, x0 = (win & 15) * 8;
    int t = threadIdx.x;
    const float* qb = qkv + (size_t)b * QKVC * N;
    for (int idx = t; idx < 4096; idx += 256) {
        int c = idx >> 6, p = idx & 63;
        int g = (y0 + (p >> 3)) * W + x0 + (p & 7);
        qs[p * 65 + c] = qb[(size_t)c * N + g];
        ks[p * 65 + c] = qb[(size_t)(64 + c) * N + g];
        vt[c * 64 + p] = qb[(size_t)(128 + c) * N + g];
        pwb[c * 65 + p] = projw[idx];   // pwb[o][d] with o=c, d=p
    }
    __syncthreads();
    if (t < 128) {
        int p = t & 63;
        const float* src = (t < 64) ? qs : ks;
        float s = 0.f;
#pragma unroll
        for (int c = 0; c < 64; ++c) { float v = src[p * 65 + c]; s += v * v; }
        float r = 1.0f / fmaxf(sqrtf(s), 1e-12f);
        if (t < 64) rq[p] = r; else rk[p] = r;
    }
    __syncthreads();
    for (int idx = t; idx < 4096; idx += 256) {
        int c = idx >> 6, p = idx & 63;
        qs[p * 65 + c] *= rq[p];
        ks[p * 65 + c] *= rk[p];
    }
    __syncthreads();
    float temp = temp_p[0];
    int c0 = (t & 15) * 4, d0 = (t >> 4) * 4;
    float s[4][4] = {};
    for (int p = 0; p < 64; ++p) {
        float qv[4], kv[4];
#pragma unroll
        for (int i = 0; i < 4; ++i) qv[i] = qs[p * 65 + c0 + i];
#pragma unroll
        for (int j = 0; j < 4; ++j) kv[j] = ks[p * 65 + d0 + j];
#pragma unroll
        for (int i = 0; i < 4; ++i)
#pragma unroll
            for (int j = 0; j < 4; ++j) s[i][j] += qv[i] * kv[j];
    }
    __syncthreads();               // all reads of qs/ks done before overlays
    float* at = qs;                // attn[c][d], stride 65
#pragma unroll
    for (int i = 0; i < 4; ++i)
#pragma unroll
        for (int j = 0; j < 4; ++j)
            at[(c0 + i) * 65 + d0 + j] = fmaxf(s[i][j] * temp, 0.f);
    __syncthreads();
    int p0 = (t & 15) * 4;         // same d0 as above
    float o[4][4] = {};
    for (int c = 0; c < 64; ++c) {
        float vv[4], av[4];
#pragma unroll
        for (int i = 0; i < 4; ++i) vv[i] = vt[c * 64 + p0 + i];
#pragma unroll
        for (int j = 0; j < 4; ++j) av[j] = at[c * 65 + d0 + j];
#pragma unroll
        for (int i = 0; i < 4; ++i)
#pragma unroll
            for (int j = 0; j < 4; ++j) o[i][j] += vv[i] * av[j];
    }
    // stage o[p][d] into ks region (PV never reads ks) for the proj GEMM
    float* obf = ks;
#pragma unroll
    for (int i = 0; i < 4; ++i)
#pragma unroll
        for (int j = 0; j < 4; ++j)
            obf[(p0 + i) * 65 + d0 + j] = o[i][j];
    __syncthreads();
    // proj: x_[oc, p] = sum_d projw[oc,d] * o[p,d];  thread -> p0 (t&15)*4, oc0 (t>>4)*4
    int oc0 = (t >> 4) * 4;
    float pr[4][4] = {};
    for (int d = 0; d < 64; ++d) {
        float ov[4], pv[4];
#pragma unroll
        for (int i = 0; i < 4; ++i) ov[i] = obf[(p0 + i) * 65 + d];
#pragma unroll
        for (int j = 0; j < 4; ++j) pv[j] = pwb[(oc0 + j) * 65 + d];
#pragma unroll
        for (int i = 0; i < 4; ++i)
#pragma unroll
            for (int j = 0; j < 4; ++j) pr[i][j] += ov[i] * pv[j];
    }
    float* ob = out + (size_t)b * C * N;
#pragma unroll
    for (int i = 0; i < 4; ++i) {
        int p = p0 + i;
        int g = (((y0 + (p >> 3)) + 4) & 127) * W + (((x0 + (p & 7)) + 4) & 127);
#pragma unroll
        for (int j = 0; j < 4; ++j)
            ob[(size_t)(oc0 + j) * N + g] = pr[i][j];
    }
}

// =========== LayerNorm over channels with fused add ===========
__global__ __launch_bounds__(256) void ln_kernel(
    const float* __restrict__ in, const float* __restrict__ add,
    const float* __restrict__ w, const float* __restrict__ bias,
    float* __restrict__ out)
{
    int pid = blockIdx.x * 256 + threadIdx.x;
    int b = pid >> 14, n = pid & (N - 1);
    size_t base = (size_t)b * C * N + n;
    float vals[C];
    float s = 0.f;
#pragma unroll
    for (int c = 0; c < C; ++c) {
        float v = in[base + (size_t)c * N];
        if (add) v += add[base + (size_t)c * N];
        vals[c] = v; s += v;
    }
    float mean = s * (1.0f / C);
    float vs = 0.f;
#pragma unroll
    for (int c = 0; c < C; ++c) { float d = vals[c] - mean; vals[c] = d; vs += d * d; }
    float rstd = rsqrtf(vs * (1.0f / C) + 1e-5f);
#pragma unroll
    for (int c = 0; c < C; ++c)
        out[base + (size_t)c * N] = vals[c] * rstd * w[c] + bias[c];
}

// =========== fused FFN: conv1x1(64->340) + dwconv + gelu-gate + conv1x1(170->64) + resid ===========
__global__ __launch_bounds__(384) void ffn_kernel(
    const float* __restrict__ ln,    // (B,64,N), already LN'd
    const float* __restrict__ w1,    // (340,64)
    const float* __restrict__ dww,   // (340,9)
    const float* __restrict__ w2t,   // (170,64) transposed out-weights
    const float* __restrict__ resid, // (B,64,N)
    float* __restrict__ out)         // (B,64,N)
{
    __shared__ float cbuf[34 * 324];
    int blk = blockIdx.x;
    int b = blk >> 6, tile = blk & 63;
    int ty0 = (tile >> 3) * 16, tx0 = (tile & 7) * 16;
    int t = threadIdx.x;
    float vals[64];
    bool ha = t < 324;
    bool inb = false;
    if (ha) {
        int hy = ty0 - 1 + t / 18;
        int hx = tx0 - 1 + t % 18;
        inb = (hy >= 0 && hy < 128 && hx >= 0 && hx < 128);
        if (inb) {
            const float* sb = ln + (size_t)b * 64 * N + hy * W + hx;
#pragma unroll
            for (int c = 0; c < 64; ++c) vals[c] = sb[(size_t)c * N];
        }
    }
    if (!ha || !inb) {
#pragma unroll
        for (int c = 0; c < 64; ++c) vals[c] = 0.f;
    }
    float acc[64];
#pragma unroll
    for (int o = 0; o < 64; ++o) acc[o] = 0.f;
    int h00 = (t >> 4) * 18 + (t & 15);
    for (int ch = 0; ch < 10; ++ch) {
        int c0 = ch * 17;
        if (ha) {
            for (int j = 0; j < 34; ++j) {
                int cg = (j < 17) ? (c0 + j) : (HID + c0 + j - 17);
                const float* wr = w1 + cg * 64;              // uniform -> s_load
                float a0 = 0.f, a1 = 0.f;
#pragma unroll
                for (int c = 0; c < 64; c += 2) { a0 += wr[c] * vals[c]; a1 += wr[c + 1] * vals[c + 1]; }
                cbuf[j * 324 + t] = a0 + a1;
            }
        }
        __syncthreads();
        if (t < 256) {
            for (int j = 0; j < 17; ++j) {
                const float* wda = dww + (c0 + j) * 9;
                const float* wdb = dww + (HID + c0 + j) * 9;
                const float* ca = cbuf + j * 324 + h00;
                const float* cb = cbuf + (17 + j) * 324 + h00;
                float a = wda[0] * ca[0]  + wda[1] * ca[1]  + wda[2] * ca[2]
                        + wda[3] * ca[18] + wda[4] * ca[19] + wda[5] * ca[20]
                        + wda[6] * ca[36] + wda[7] * ca[37] + wda[8] * ca[38];
                float bb = wdb[0] * cb[0]  + wdb[1] * cb[1]  + wdb[2] * cb[2]
                        + wdb[3] * cb[18] + wdb[4] * cb[19] + wdb[5] * cb[20]
                        + wdb[6] * cb[36] + wdb[7] * cb[37] + wdb[8] * cb[38];
                float g = gelu_exact(a) * bb;
                const float* wr2 = w2t + (c0 + j) * 64;      // uniform -> s_load
#pragma unroll
                for (int o = 0; o < 64; ++o) acc[o] += wr2[o] * g;
            }
        }
        __syncthreads();
    }
    if (t < 256) {
        size_t g = (size_t)b * 64 * N + (ty0 + (t >> 4)) * W + tx0 + (t & 15);
#pragma unroll
        for (int o = 0; o < 64; ++o) out[g + (size_t)o * N] = acc[o] + resid[g + (size_t)o * N];
    }
}

// =========== GSA phase A: per-(b,h,chunk) partial S[8][8], |q|^2[8], |k|^2[8] ===========
__global__ __launch_bounds__(256) void gsa_part_kernel(
    const float* __restrict__ qkv, float* __restrict__ part)
{
    int bh = blockIdx.y, chunk = blockIdx.x;    // bh in [0,64), chunk in [0,32)
    int b = bh >> 3, h = bh & 7;
    int t = threadIdx.x;
    const float* qb = qkv + ((size_t)b * QKVC + h * 8) * N;
    const float* kb = qb + (size_t)64 * N;
    float acc[80];
#pragma unroll
    for (int j = 0; j < 80; ++j) acc[j] = 0.f;
    for (int i = 0; i < 2; ++i) {
        int n = chunk * 512 + i * 256 + t;
        float qv[8], kv[8];
#pragma unroll
        for (int c = 0; c < 8; ++c) { qv[c] = qb[(size_t)c * N + n]; kv[c] = kb[(size_t)c * N + n]; }
#pragma unroll
        for (int c = 0; c < 8; ++c) {
            acc[64 + c] += qv[c] * qv[c];
            acc[72 + c] += kv[c] * kv[c];
#pragma unroll
            for (int d = 0; d < 8; ++d) acc[c * 8 + d] += qv[c] * kv[d];
        }
    }
#pragma unroll
    for (int j = 0; j < 80; ++j) {
        float v = acc[j];
#pragma unroll
        for (int m = 1; m < 64; m <<= 1) v += __shfl_xor(v, m, 64);
        acc[j] = v;
    }
    __shared__ float red[4 * 80];
    if ((t & 63) == 0) {
#pragma unroll
        for (int j = 0; j < 80; ++j) red[(t >> 6) * 80 + j] = acc[j];
    }
    __syncthreads();
    if (t < 80) {
        float s = red[t] + red[80 + t] + red[160 + t] + red[240 + t];
        part[((size_t)bh * 32 + chunk) * 80 + t] = s;
    }
}

// =========== GSA phase B: reduce chunks, l2norm + temp + relu -> attn[b,h,c,d] ===========
__global__ __launch_bounds__(128) void gsa_fin_kernel(
    const float* __restrict__ part, const float* __restrict__ temp_p,
    float* __restrict__ attn)
{
    int bh = blockIdx.x;
    int t = threadIdx.x;
    __shared__ float red[80];
    if (t < 80) {
        float s = 0.f;
        for (int ch = 0; ch < 32; ++ch) s += part[((size_t)bh * 32 + ch) * 80 + t];
        red[t] = s;
    }
    __syncthreads();
    if (t < 64) {
        int c = t >> 3, d = t & 7;
        float S  = red[c * 8 + d];
        float qn = fmaxf(sqrtf(red[64 + c]), 1e-12f);
        float kn = fmaxf(sqrtf(red[72 + d]), 1e-12f);
        attn[(size_t)bh * 64 + t] = fmaxf(temp_p[0] * S / (qn * kn), 0.f);
    }
}

// =========== GSA phase C: W_eff[b][o][h*8+d] = sum_c proj_w[o, c*8+h] * attn[b,h,c,d] ===========
__global__ __launch_bounds__(64) void weff_kernel(
    const float* __restrict__ attn, const float* __restrict__ pw,
    float* __restrict__ weff)
{
    int b = blockIdx.x;
    int o = threadIdx.x;
    __shared__ float al[512];
    for (int idx = o; idx < 512; idx += 64) al[idx] = attn[(size_t)b * 512 + idx];
    __syncthreads();
    for (int hd = 0; hd < 64; ++hd) {
        int h = hd >> 3, d = hd & 7;
        float acc = 0.f;
#pragma unroll
        for (int c = 0; c < 8; ++c)
            acc += pw[o * 64 + c * 8 + h] * al[h * 64 + c * 8 + d];
        weff[((size_t)b * 64 + o) * 64 + hd] = acc;
    }
}

// =========== GSA output GEMM: out[b,o,n] = sum_hd weff[b,o,hd] * v[b,hd,n] ===========
__global__ __launch_bounds__(256) void conv_pbw_kernel(
    const float* __restrict__ vin,   // qkv v-part base, batch stride 192*N
    const float* __restrict__ weff,  // (B,64,64)
    float* __restrict__ out)         // (B,64,N)
{
    int base = blockIdx.x * 512;
    int b = base >> 14;
    int n0 = (base & (N - 1)) + threadIdx.x;
    int n1 = n0 + 256;
    const float* ib = vin + (size_t)b * QKVC * N;
    float v0[64], v1[64];
#pragma unroll
    for (int c = 0; c < 64; ++c) {
        v0[c] = ib[(size_t)c * N + n0];
        v1[c] = ib[(size_t)c * N + n1];
    }
    const float* wb = weff + (size_t)b * 64 * 64;
    float* ob = out + (size_t)b * 64 * N;
#pragma unroll 2
    for (int o = 0; o < 64; ++o) {
        const float* wr = wb + o * 64;       // uniform -> s_load
        float a0 = 0.f, a1 = 0.f;
#pragma unroll
        for (int c = 0; c < 64; ++c) { a0 += wr[c] * v0[c]; a1 += wr[c] * v1[c]; }
        ob[(size_t)o * N + n0] = a0;
        ob[(size_t)o * N + n1] = a1;
    }
}

// =========== small: transpose (64 x HID) -> (HID x 64) ===========
__global__ __launch_bounds__(256) void transpose_w_kernel(
    const float* __restrict__ w, float* __restrict__ wt)
{
    int idx = blockIdx.x * 256 + threadIdx.x;
    if (idx < 64 * HID) {
        int o = idx / HID, c = idx % HID;
        wt[c * 64 + o] = w[idx];
    }
}

// =========== sentinel: unmistakable signature if workspace is too small ===========
__global__ void sentinel_kernel(float* out, int n) {
    int i = blockIdx.x * 256 + threadIdx.x;
    if (i < n) out[i] = 12345.0f;
}

extern "C" void kernel_launch(void* const* d_in, const int* in_sizes, int n_in,
                              void* d_out, int out_size, void* d_ws, size_t ws_size,
                              hipStream_t stream)
{
    const float* x         = (const float*)d_in[0];
    const float* ln_s0_w   = (const float*)d_in[1];
    const float* ln_s0_b   = (const float*)d_in[2];
    const float* ln_s2_w   = (const float*)d_in[3];
    const float* ln_s2_b   = (const float*)d_in[4];
    const float* rsa_qkv_w = (const float*)d_in[5];
    const float* rsa_dw_w  = (const float*)d_in[6];
    const float* rsa_proj_w= (const float*)d_in[7];
    const float* rsa_temp  = (const float*)d_in[8];
    const float* ffs_in_w  = (const float*)d_in[9];
    const float* ffs_dw_w  = (const float*)d_in[10];
    const float* ffs_out_w = (const float*)d_in[11];
    const float* ln_c0_w   = (const float*)d_in[12];
    const float* ln_c0_b   = (const float*)d_in[13];
    const float* ln_c2_w   = (const float*)d_in[14];
    const float* ln_c2_b   = (const float*)d_in[15];
    const float* gsa_qkv_w = (const float*)d_in[16];
    const float* gsa_dw_w  = (const float*)d_in[17];
    const float* gsa_proj_w= (const float*)d_in[18];
    const float* gsa_temp  = (const float*)d_in[19];
    const float* ffc_in_w  = (const float*)d_in[20];
    const float* ffc_dw_w  = (const float*)d_in[21];
    const float* ffc_out_w = (const float*)d_in[22];
    float* outp = (float*)d_out;

    // workspace layout (total 168,662,016 B ~= 161 MiB)
    char* ws = (char*)d_ws;
    float* Qbuf   = (float*)(ws + 0);             // (B,192,N) = 100,663,296 B
    float* S1     = (float*)(ws + 100663296ull);  // (B,64,N)  =  33,554,432 B
    float* S2     = (float*)(ws + 134217728ull);  // (B,64,N)
    float* part   = (float*)(ws + 167772160ull);  // 64*32*80  = 655,360 B
    float* attn_s = (float*)(ws + 168427520ull);  // 4096 f
    float* weffb  = (float*)(ws + 168443904ull);  // 8*64*64 f
    float* wt_s   = (float*)(ws + 168574976ull);  // 170*64 f
    float* wt_c   = (float*)(ws + 168618496ull);  // 170*64 f
    if (ws_size < 168662016ull) {
        int n = out_size < 4096 ? out_size : 4096;
        sentinel_kernel<<<16, 256, 0, stream>>>(outp, n);
        return;
    }

    dim3 blk256(256), blk384(384);

    transpose_w_kernel<<<43, blk256, 0, stream>>>(ffs_out_w, wt_s);
    transpose_w_kernel<<<43, blk256, 0, stream>>>(ffc_out_w, wt_c);

    // ---- spatial (RSA) half ----
    cdw_kernel<true><<<B * 64, blk384, 0, stream>>>(x, ln_s0_w, ln_s0_b, rsa_qkv_w, rsa_dw_w, Qbuf);
    rsa_win_kernel<<<B * 256, blk256, 0, stream>>>(Qbuf, rsa_temp, rsa_proj_w, S2);      // x_ spatial
    ln_kernel<<<B * N / 256, blk256, 0, stream>>>(S2, x, ln_s2_w, ln_s2_b, S1);          // LN(x_+x)
    ffn_kernel<<<B * 64, blk384, 0, stream>>>(S1, ffs_in_w, ffs_dw_w, wt_s, S2, outp);   // x -> d_out

    // ---- channel (GSA) half ----
    cdw_kernel<false><<<B * 64, blk384, 0, stream>>>(outp, ln_c0_w, ln_c0_b, gsa_qkv_w, gsa_dw_w, Qbuf);
    gsa_part_kernel<<<dim3(32, 64), blk256, 0, stream>>>(Qbuf, part);
    gsa_fin_kernel<<<64, dim3(128), 0, stream>>>(part, gsa_temp, attn_s);
    weff_kernel<<<8, dim3(64), 0, stream>>>(attn_s, gsa_proj_w, weffb);
    conv_pbw_kernel<<<B * N / 512, blk256, 0, stream>>>(Qbuf + (size_t)128 * N, weffb, S2); // x_ channel
    ln_kernel<<<B * N / 256, blk256, 0, stream>>>(S2, outp, ln_c2_w, ln_c2_b, S1);       // LN(x_+x)
    ffn_kernel<<<B * 64, blk384, 0, stream>>>(S1, ffc_in_w, ffc_dw_w, wt_c, S2, outp);   // final
}

// Round 3
// 1926.816 us; speedup vs baseline: 1.2925x; 1.2925x over previous
//
#include <hip/hip_runtime.h>
#include <hip/hip_bf16.h>
#include <math.h>

#define DI __device__ __forceinline__

constexpr int B = 8, C = 64, H = 128, W = 128, N = H * W;   // N = 16384
constexpr int HID = 170;
constexpr int QKVC = 3 * C;                                 // 192

DI float gelu_exact(float v) {
    return 0.5f * v * (1.0f + erff(v * 0.70710678118654752f));
}

// =========== fused LN + conv1x1(64->192) + dwconv3x3, tiled 16x16 (+halo 18x18) ===========
template<bool ROLL>
__global__ __launch_bounds__(384, 1) void cdw_kernel(
    const float* __restrict__ src,   // (B,64,N)
    const float* __restrict__ lnw, const float* __restrict__ lnb,
    const float* __restrict__ cw,    // (192,64)
    const float* __restrict__ dww,   // (192,9)
    float* __restrict__ out)         // (B,192,N)
{
    __shared__ float cbuf[32 * 324];
    int blk = blockIdx.x;            // b*64 + tile
    int b = blk >> 6, tile = blk & 63;
    int ty0 = (tile >> 3) * 16, tx0 = (tile & 7) * 16;
    int t = threadIdx.x;
    float vals[64];
    bool ha = t < 324;
    bool inb = false;
    if (ha) {
        int hy = ty0 - 1 + t / 18;
        int hx = tx0 - 1 + t % 18;
        inb = (hy >= 0 && hy < 128 && hx >= 0 && hx < 128);
        if (inb) {
            int sy = ROLL ? ((hy + 4) & 127) : hy;
            int sx = ROLL ? ((hx + 4) & 127) : hx;
            const float* sb = src + (size_t)b * 64 * N + sy * W + sx;
            float s = 0.f;
#pragma unroll
            for (int c = 0; c < 64; ++c) { vals[c] = sb[(size_t)c * N]; s += vals[c]; }
            float mu = s * (1.0f / 64.0f);
            float vs = 0.f;
#pragma unroll
            for (int c = 0; c < 64; ++c) { float d = vals[c] - mu; vals[c] = d; vs += d * d; }
            float rstd = rsqrtf(vs * (1.0f / 64.0f) + 1e-5f);
#pragma unroll
            for (int c = 0; c < 64; ++c) vals[c] = vals[c] * rstd * lnw[c] + lnb[c];
        }
    }
    if (!ha || !inb) {
#pragma unroll
        for (int c = 0; c < 64; ++c) vals[c] = 0.f;
    }
    int h00 = (t >> 4) * 18 + (t & 15);
    int gout = (ty0 + (t >> 4)) * W + tx0 + (t & 15);
    for (int ch = 0; ch < 6; ++ch) {
        if (ha) {
            for (int j = 0; j < 32; ++j) {
                const float* wr = cw + (ch * 32 + j) * 64;   // uniform -> s_load
                float a0 = 0.f, a1 = 0.f;
#pragma unroll
                for (int c = 0; c < 64; c += 2) { a0 += wr[c] * vals[c]; a1 += wr[c + 1] * vals[c + 1]; }
                cbuf[j * 324 + t] = a0 + a1;
            }
        }
        __syncthreads();
        if (t < 256) {
            for (int j = 0; j < 32; ++j) {
                const float* wd = dww + (ch * 32 + j) * 9;   // uniform -> s_load
                const float* cb = cbuf + j * 324 + h00;
                float a = wd[0] * cb[0]  + wd[1] * cb[1]  + wd[2] * cb[2]
                        + wd[3] * cb[18] + wd[4] * cb[19] + wd[5] * cb[20]
                        + wd[6] * cb[36] + wd[7] * cb[37] + wd[8] * cb[38];
                out[((size_t)b * QKVC + ch * 32 + j) * N + gout] = a;
            }
        }
        __syncthreads();
    }
}

// =========== RSA window attention + fused proj; one block per 8x8 window ===========
__global__ __launch_bounds__(256) void rsa_win_kernel(
    const float* __restrict__ qkv, const float* __restrict__ temp_p,
    const float* __restrict__ projw, float* __restrict__ out)
{
    __shared__ float qs[64 * 65];   // [p][c] stride 65; later overlaid by attn[c][d] stride 65
    __shared__ float ks[64 * 65];   // [p][c]; later overlaid by o[p][d] stride 65
    __shared__ float vt[64 * 64];   // [c][p]
    __shared__ float pwb[64 * 65];  // proj w [o][d] stride 65
    __shared__ float rq[64], rk[64];
    int blk = blockIdx.x;
    int b = blk >> 8, win = blk & 255;
    int y0 = (win >> 4) * 8, x0 = (win & 15) * 8;
    int t = threadIdx.x;
    const float* qb = qkv + (size_t)b * QKVC * N;
    for (int idx = t; idx < 4096; idx += 256) {
        int c = idx >> 6, p = idx & 63;
        int g = (y0 + (p >> 3)) * W + x0 + (p & 7);
        qs[p * 65 + c] = qb[(size_t)c * N + g];
        ks[p * 65 + c] = qb[(size_t)(64 + c) * N + g];
        vt[c * 64 + p] = qb[(size_t)(128 + c) * N + g];
        pwb[c * 65 + p] = projw[idx];   // pwb[o][d] with o=c, d=p
    }
    __syncthreads();
    if (t < 128) {
        int p = t & 63;
        const float* src = (t < 64) ? qs : ks;
        float s = 0.f;
#pragma unroll
        for (int c = 0; c < 64; ++c) { float v = src[p * 65 + c]; s += v * v; }
        float r = 1.0f / fmaxf(sqrtf(s), 1e-12f);
        if (t < 64) rq[p] = r; else rk[p] = r;
    }
    __syncthreads();
    for (int idx = t; idx < 4096; idx += 256) {
        int c = idx >> 6, p = idx & 63;
        qs[p * 65 + c] *= rq[p];
        ks[p * 65 + c] *= rk[p];
    }
    __syncthreads();
    float temp = temp_p[0];
    int c0 = (t & 15) * 4, d0 = (t >> 4) * 4;
    float s[4][4] = {};
    for (int p = 0; p < 64; ++p) {
        float qv[4], kv[4];
#pragma unroll
        for (int i = 0; i < 4; ++i) qv[i] = qs[p * 65 + c0 + i];
#pragma unroll
        for (int j = 0; j < 4; ++j) kv[j] = ks[p * 65 + d0 + j];
#pragma unroll
        for (int i = 0; i < 4; ++i)
#pragma unroll
            for (int j = 0; j < 4; ++j) s[i][j] += qv[i] * kv[j];
    }
    __syncthreads();
    float* at = qs;                // attn[c][d], stride 65
#pragma unroll
    for (int i = 0; i < 4; ++i)
#pragma unroll
        for (int j = 0; j < 4; ++j)
            at[(c0 + i) * 65 + d0 + j] = fmaxf(s[i][j] * temp, 0.f);
    __syncthreads();
    int p0 = (t & 15) * 4;
    float o[4][4] = {};
    for (int c = 0; c < 64; ++c) {
        float vv[4], av[4];
#pragma unroll
        for (int i = 0; i < 4; ++i) vv[i] = vt[c * 64 + p0 + i];
#pragma unroll
        for (int j = 0; j < 4; ++j) av[j] = at[c * 65 + d0 + j];
#pragma unroll
        for (int i = 0; i < 4; ++i)
#pragma unroll
            for (int j = 0; j < 4; ++j) o[i][j] += vv[i] * av[j];
    }
    float* obf = ks;               // o[p][d], stride 65
#pragma unroll
    for (int i = 0; i < 4; ++i)
#pragma unroll
        for (int j = 0; j < 4; ++j)
            obf[(p0 + i) * 65 + d0 + j] = o[i][j];
    __syncthreads();
    int oc0 = (t >> 4) * 4;
    float pr[4][4] = {};
    for (int d = 0; d < 64; ++d) {
        float ov[4], pv[4];
#pragma unroll
        for (int i = 0; i < 4; ++i) ov[i] = obf[(p0 + i) * 65 + d];
#pragma unroll
        for (int j = 0; j < 4; ++j) pv[j] = pwb[(oc0 + j) * 65 + d];
#pragma unroll
        for (int i = 0; i < 4; ++i)
#pragma unroll
            for (int j = 0; j < 4; ++j) pr[i][j] += ov[i] * pv[j];
    }
    float* ob = out + (size_t)b * C * N;
#pragma unroll
    for (int i = 0; i < 4; ++i) {
        int p = p0 + i;
        int g = (((y0 + (p >> 3)) + 4) & 127) * W + (((x0 + (p & 7)) + 4) & 127);
#pragma unroll
        for (int j = 0; j < 4; ++j)
            ob[(size_t)(oc0 + j) * N + g] = pr[i][j];
    }
}

// =========== LayerNorm over channels with fused add ===========
__global__ __launch_bounds__(256, 1) void ln_kernel(
    const float* __restrict__ in, const float* __restrict__ add,
    const float* __restrict__ w, const float* __restrict__ bias,
    float* __restrict__ out)
{
    int pid = blockIdx.x * 256 + threadIdx.x;
    int b = pid >> 14, n = pid & (N - 1);
    size_t base = (size_t)b * C * N + n;
    float vals[C];
    float s = 0.f;
#pragma unroll
    for (int c = 0; c < C; ++c) {
        float v = in[base + (size_t)c * N];
        if (add) v += add[base + (size_t)c * N];
        vals[c] = v; s += v;
    }
    float mean = s * (1.0f / C);
    float vs = 0.f;
#pragma unroll
    for (int c = 0; c < C; ++c) { float d = vals[c] - mean; vals[c] = d; vs += d * d; }
    float rstd = rsqrtf(vs * (1.0f / C) + 1e-5f);
#pragma unroll
    for (int c = 0; c < C; ++c)
        out[base + (size_t)c * N] = vals[c] * rstd * w[c] + bias[c];
}

// =========== FFN stage A: conv1x1 64->340, fp16 hidden out ===========
__global__ __launch_bounds__(256, 1) void ffn_a_kernel(
    const float* __restrict__ in,    // (B,64,N) LN'd
    const float* __restrict__ w1,    // (340,64)
    _Float16* __restrict__ hid)      // (B,340,N) fp16
{
    int pid = blockIdx.x * 256 + threadIdx.x;
    int b = pid >> 14, n = pid & (N - 1);
    const float* ib = in + (size_t)b * 64 * N + n;
    float v[64];
#pragma unroll
    for (int c = 0; c < 64; ++c) v[c] = ib[(size_t)c * N];
    _Float16* ob = hid + (size_t)b * 340 * N + n;
#pragma unroll 2
    for (int o = 0; o < 340; ++o) {
        const float* wr = w1 + o * 64;       // uniform -> s_load
        float a0 = 0.f, a1 = 0.f;
#pragma unroll
        for (int c = 0; c < 64; c += 2) { a0 += wr[c] * v[c]; a1 += wr[c + 1] * v[c + 1]; }
        ob[(size_t)o * N] = (_Float16)(a0 + a1);
    }
}

// =========== FFN stage B: dwconv3x3 + gelu gate, fp16 -> fp16 ===========
__global__ __launch_bounds__(256, 1) void ffn_b_kernel(
    const _Float16* __restrict__ hid,   // (B,340,N)
    const float* __restrict__ dww,      // (340,9)
    _Float16* __restrict__ gated)       // (B,170,N)
{
    int bc = blockIdx.y;                 // b*170 + c
    int b = bc / 170, c = bc % 170;
    int n = blockIdx.x * 256 + threadIdx.x;
    int y = n >> 7, x = n & 127;
    const _Float16* pa = hid + ((size_t)b * 340 + c) * N;
    const _Float16* pb = hid + ((size_t)b * 340 + 170 + c) * N;
    const float* wa = dww + c * 9;          // uniform -> s_load
    const float* wb = dww + (170 + c) * 9;
    float a = 0.f, g2 = 0.f;
#pragma unroll
    for (int dy = -1; dy <= 1; ++dy) {
        int yy = y + dy;
        if (yy < 0 || yy > 127) continue;
#pragma unroll
        for (int dx = -1; dx <= 1; ++dx) {
            int xx = x + dx;
            if (xx < 0 || xx > 127) continue;
            int idx = yy * W + xx, wi = (dy + 1) * 3 + dx + 1;
            a  += wa[wi] * (float)pa[idx];
            g2 += wb[wi] * (float)pb[idx];
        }
    }
    gated[((size_t)b * 170 + c) * N + n] = (_Float16)(gelu_exact(a) * g2);
}

// =========== FFN stage C: conv1x1 170->64 + residual ===========
__global__ __launch_bounds__(256, 1) void ffn_c_kernel(
    const _Float16* __restrict__ gated, // (B,170,N)
    const float* __restrict__ w2t,      // (170,64) transposed
    const float* __restrict__ resid,    // (B,64,N)
    float* __restrict__ out)            // (B,64,N)
{
    int pid = blockIdx.x * 256 + threadIdx.x;
    int b = pid >> 14, n = pid & (N - 1);
    const _Float16* ib = gated + (size_t)b * 170 * N + n;
    const float* rb = resid + (size_t)b * 64 * N + n;
    float acc[64];
#pragma unroll
    for (int o = 0; o < 64; ++o) acc[o] = rb[(size_t)o * N];
#pragma unroll 2
    for (int c = 0; c < 170; ++c) {
        float g = (float)ib[(size_t)c * N];
        const float* wr = w2t + c * 64;     // uniform -> s_load
#pragma unroll
        for (int o = 0; o < 64; ++o) acc[o] += wr[o] * g;
    }
    float* ob = out + (size_t)b * 64 * N + n;
#pragma unroll
    for (int o = 0; o < 64; ++o) ob[(size_t)o * N] = acc[o];
}

// =========== GSA phase A: per-(b,h,chunk) partial S[8][8], |q|^2[8], |k|^2[8] ===========
__global__ __launch_bounds__(256, 1) void gsa_part_kernel(
    const float* __restrict__ qkv, float* __restrict__ part)
{
    int bh = blockIdx.y, chunk = blockIdx.x;    // bh in [0,64), chunk in [0,32)
    int b = bh >> 3, h = bh & 7;
    int t = threadIdx.x;
    const float* qb = qkv + ((size_t)b * QKVC + h * 8) * N;
    const float* kb = qb + (size_t)64 * N;
    float acc[80];
#pragma unroll
    for (int j = 0; j < 80; ++j) acc[j] = 0.f;
    for (int i = 0; i < 2; ++i) {
        int n = chunk * 512 + i * 256 + t;
        float qv[8], kv[8];
#pragma unroll
        for (int c = 0; c < 8; ++c) { qv[c] = qb[(size_t)c * N + n]; kv[c] = kb[(size_t)c * N + n]; }
#pragma unroll
        for (int c = 0; c < 8; ++c) {
            acc[64 + c] += qv[c] * qv[c];
            acc[72 + c] += kv[c] * kv[c];
#pragma unroll
            for (int d = 0; d < 8; ++d) acc[c * 8 + d] += qv[c] * kv[d];
        }
    }
#pragma unroll
    for (int j = 0; j < 80; ++j) {
        float v = acc[j];
#pragma unroll
        for (int m = 1; m < 64; m <<= 1) v += __shfl_xor(v, m, 64);
        acc[j] = v;
    }
    __shared__ float red[4 * 80];
    if ((t & 63) == 0) {
#pragma unroll
        for (int j = 0; j < 80; ++j) red[(t >> 6) * 80 + j] = acc[j];
    }
    __syncthreads();
    if (t < 80) {
        float s = red[t] + red[80 + t] + red[160 + t] + red[240 + t];
        part[((size_t)bh * 32 + chunk) * 80 + t] = s;
    }
}

// =========== GSA phase B ===========
__global__ __launch_bounds__(128) void gsa_fin_kernel(
    const float* __restrict__ part, const float* __restrict__ temp_p,
    float* __restrict__ attn)
{
    int bh = blockIdx.x;
    int t = threadIdx.x;
    __shared__ float red[80];
    if (t < 80) {
        float s = 0.f;
        for (int ch = 0; ch < 32; ++ch) s += part[((size_t)bh * 32 + ch) * 80 + t];
        red[t] = s;
    }
    __syncthreads();
    if (t < 64) {
        int c = t >> 3, d = t & 7;
        float S  = red[c * 8 + d];
        float qn = fmaxf(sqrtf(red[64 + c]), 1e-12f);
        float kn = fmaxf(sqrtf(red[72 + d]), 1e-12f);
        attn[(size_t)bh * 64 + t] = fmaxf(temp_p[0] * S / (qn * kn), 0.f);
    }
}

// =========== GSA phase C: W_eff[b][o][h*8+d] = sum_c proj_w[o, c*8+h] * attn[b,h,c,d] ===========
__global__ __launch_bounds__(64) void weff_kernel(
    const float* __restrict__ attn, const float* __restrict__ pw,
    float* __restrict__ weff)
{
    int b = blockIdx.x;
    int o = threadIdx.x;
    __shared__ float al[512];
    for (int idx = o; idx < 512; idx += 64) al[idx] = attn[(size_t)b * 512 + idx];
    __syncthreads();
    for (int hd = 0; hd < 64; ++hd) {
        int h = hd >> 3, d = hd & 7;
        float acc = 0.f;
#pragma unroll
        for (int c = 0; c < 8; ++c)
            acc += pw[o * 64 + c * 8 + h] * al[h * 64 + c * 8 + d];
        weff[((size_t)b * 64 + o) * 64 + hd] = acc;
    }
}

// =========== GSA output GEMM: out[b,o,n] = sum_hd weff[b,o,hd] * v[b,hd,n] ===========
__global__ __launch_bounds__(256, 1) void conv_pbw_kernel(
    const float* __restrict__ vin,   // qkv v-part base, batch stride 192*N
    const float* __restrict__ weff,  // (B,64,64)
    float* __restrict__ out)         // (B,64,N)
{
    int pid = blockIdx.x * 256 + threadIdx.x;
    int b = pid >> 14, n = pid & (N - 1);
    const float* ib = vin + (size_t)b * QKVC * N + n;
    float v[64];
#pragma unroll
    for (int c = 0; c < 64; ++c) v[c] = ib[(size_t)c * N];
    const float* wb = weff + (size_t)b * 64 * 64;
    float* ob = out + (size_t)b * 64 * N + n;
#pragma unroll 2
    for (int o = 0; o < 64; ++o) {
        const float* wr = wb + o * 64;       // uniform -> s_load
        float a0 = 0.f, a1 = 0.f;
#pragma unroll
        for (int c = 0; c < 64; c += 2) { a0 += wr[c] * v[c]; a1 += wr[c + 1] * v[c + 1]; }
        ob[(size_t)o * N] = a0 + a1;
    }
}

// =========== small: transpose (64 x HID) -> (HID x 64) ===========
__global__ __launch_bounds__(256) void transpose_w_kernel(
    const float* __restrict__ w, float* __restrict__ wt)
{
    int idx = blockIdx.x * 256 + threadIdx.x;
    if (idx < 64 * HID) {
        int o = idx / HID, c = idx % HID;
        wt[c * 64 + o] = w[idx];
    }
}

// =========== sentinel: unmistakable signature if workspace is too small ===========
__global__ void sentinel_kernel(float* out, int n) {
    int i = blockIdx.x * 256 + threadIdx.x;
    if (i < n) out[i] = 12345.0f;
}

extern "C" void kernel_launch(void* const* d_in, const int* in_sizes, int n_in,
                              void* d_out, int out_size, void* d_ws, size_t ws_size,
                              hipStream_t stream)
{
    const float* x         = (const float*)d_in[0];
    const float* ln_s0_w   = (const float*)d_in[1];
    const float* ln_s0_b   = (const float*)d_in[2];
    const float* ln_s2_w   = (const float*)d_in[3];
    const float* ln_s2_b   = (const float*)d_in[4];
    const float* rsa_qkv_w = (const float*)d_in[5];
    const float* rsa_dw_w  = (const float*)d_in[6];
    const float* rsa_proj_w= (const float*)d_in[7];
    const float* rsa_temp  = (const float*)d_in[8];
    const float* ffs_in_w  = (const float*)d_in[9];
    const float* ffs_dw_w  = (const float*)d_in[10];
    const float* ffs_out_w = (const float*)d_in[11];
    const float* ln_c0_w   = (const float*)d_in[12];
    const float* ln_c0_b   = (const float*)d_in[13];
    const float* ln_c2_w   = (const float*)d_in[14];
    const float* ln_c2_b   = (const float*)d_in[15];
    const float* gsa_qkv_w = (const float*)d_in[16];
    const float* gsa_dw_w  = (const float*)d_in[17];
    const float* gsa_proj_w= (const float*)d_in[18];
    const float* gsa_temp  = (const float*)d_in[19];
    const float* ffc_in_w  = (const float*)d_in[20];
    const float* ffc_dw_w  = (const float*)d_in[21];
    const float* ffc_out_w = (const float*)d_in[22];
    float* outp = (float*)d_out;

    // workspace layout (total 168,662,016 B ~= 161 MiB) -- verified fits in round 2
    char* ws = (char*)d_ws;
    float*    Qbuf   = (float*)(ws + 0);             // (B,192,N) fp32 = 100,663,296 B
    _Float16* hidA   = (_Float16*)(ws + 0);          // (B,340,N) fp16 = 89,128,960 B (overlays dead Qbuf)
    _Float16* gated  = (_Float16*)(ws + 89128960ull);// (B,170,N) fp16 = 44,564,480 B (ends 133,693,440 < S2)
    float*    S1     = (float*)(ws + 100663296ull);  // (B,64,N)  = 33,554,432 B
    float*    S2     = (float*)(ws + 134217728ull);  // (B,64,N)
    float*    part   = (float*)(ws + 167772160ull);  // 64*32*80 f
    float*    attn_s = (float*)(ws + 168427520ull);  // 4096 f
    float*    weffb  = (float*)(ws + 168443904ull);  // 8*64*64 f
    float*    wt_s   = (float*)(ws + 168574976ull);  // 170*64 f
    float*    wt_c   = (float*)(ws + 168618496ull);  // 170*64 f
    if (ws_size < 168662016ull) {
        int n = out_size < 4096 ? out_size : 4096;
        sentinel_kernel<<<16, 256, 0, stream>>>(outp, n);
        return;
    }

    const int BN = B * N;
    dim3 blk256(256), blk384(384);

    transpose_w_kernel<<<43, blk256, 0, stream>>>(ffs_out_w, wt_s);
    transpose_w_kernel<<<43, blk256, 0, stream>>>(ffc_out_w, wt_c);

    // ---- spatial (RSA) half ----
    cdw_kernel<true><<<B * 64, blk384, 0, stream>>>(x, ln_s0_w, ln_s0_b, rsa_qkv_w, rsa_dw_w, Qbuf);
    rsa_win_kernel<<<B * 256, blk256, 0, stream>>>(Qbuf, rsa_temp, rsa_proj_w, S2);       // x_ spatial
    ln_kernel<<<BN / 256, blk256, 0, stream>>>(S2, x, ln_s2_w, ln_s2_b, S1);              // LN(x_+x)
    ffn_a_kernel<<<BN / 256, blk256, 0, stream>>>(S1, ffs_in_w, hidA);                    // Qbuf dead now
    ffn_b_kernel<<<dim3(N / 256, B * 170), blk256, 0, stream>>>(hidA, ffs_dw_w, gated);   // S1 dead now
    ffn_c_kernel<<<BN / 256, blk256, 0, stream>>>(gated, wt_s, S2, outp);                 // x -> d_out

    // ---- channel (GSA) half ----
    cdw_kernel<false><<<B * 64, blk384, 0, stream>>>(outp, ln_c0_w, ln_c0_b, gsa_qkv_w, gsa_dw_w, Qbuf);
    gsa_part_kernel<<<dim3(32, 64), blk256, 0, stream>>>(Qbuf, part);
    gsa_fin_kernel<<<64, dim3(128), 0, stream>>>(part, gsa_temp, attn_s);
    weff_kernel<<<8, dim3(64), 0, stream>>>(attn_s, gsa_proj_w, weffb);
    conv_pbw_kernel<<<BN / 256, blk256, 0, stream>>>(Qbuf + (size_t)128 * N, weffb, S2);  // x_ channel
    ln_kernel<<<BN / 256, blk256, 0, stream>>>(S2, outp, ln_c2_w, ln_c2_b, S1);           // LN(x_+x)
    ffn_a_kernel<<<BN / 256, blk256, 0, stream>>>(S1, ffc_in_w, hidA);                    // Qbuf dead now
    ffn_b_kernel<<<dim3(N / 256, B * 170), blk256, 0, stream>>>(hidA, ffc_dw_w, gated);
    ffn_c_kernel<<<BN / 256, blk256, 0, stream>>>(gated, wt_c, S2, outp);                 // final
}

// Round 4
// 1859.256 us; speedup vs baseline: 1.3395x; 1.0363x over previous
//
#include <hip/hip_runtime.h>
#include <hip/hip_bf16.h>
#include <math.h>

#define DI __device__ __forceinline__

constexpr int B = 8, C = 64, H = 128, W = 128, N = H * W;   // N = 16384
constexpr int HID = 170;
constexpr int QKVC = 3 * C;                                 // 192

DI float gelu_exact(float v) {
    return 0.5f * v * (1.0f + erff(v * 0.70710678118654752f));
}

// =========== LayerNorm over channels with fused add ===========
__global__ __launch_bounds__(256, 1) void ln_kernel(
    const float* __restrict__ in, const float* __restrict__ add,
    const float* __restrict__ w, const float* __restrict__ bias,
    float* __restrict__ out)
{
    int pid = blockIdx.x * 256 + threadIdx.x;
    int b = pid >> 14, n = pid & (N - 1);
    size_t base = (size_t)b * C * N + n;
    float vals[C];
    float s = 0.f;
#pragma unroll
    for (int c = 0; c < C; ++c) {
        float v = in[base + (size_t)c * N];
        if (add) v += add[base + (size_t)c * N];
        vals[c] = v; s += v;
    }
    float mean = s * (1.0f / C);
    float vs = 0.f;
#pragma unroll
    for (int c = 0; c < C; ++c) { float d = vals[c] - mean; vals[c] = d; vs += d * d; }
    float rstd = rsqrtf(vs * (1.0f / C) + 1e-5f);
#pragma unroll
    for (int c = 0; c < C; ++c)
        out[base + (size_t)c * N] = vals[c] * rstd * w[c] + bias[c];
}

// =========== conv1x1 64->192, optional rolled input read, fp16 out ===========
template<bool ROLL>
__global__ __launch_bounds__(256, 1) void conv192_kernel(
    const float* __restrict__ in,    // (B,64,N)
    const float* __restrict__ wq,    // (192,64)
    _Float16* __restrict__ out)      // (B,192,N), rolled space if ROLL
{
    int pid = blockIdx.x * 256 + threadIdx.x;
    int b = pid >> 14, n = pid & (N - 1);
    int r = n;
    if (ROLL) {
        int y = n >> 7, x = n & 127;
        r = (((y + 4) & 127) << 7) | ((x + 4) & 127);
    }
    const float* ib = in + (size_t)b * 64 * N + r;
    float v[64];
#pragma unroll
    for (int c = 0; c < 64; ++c) v[c] = ib[(size_t)c * N];
    _Float16* ob = out + (size_t)b * QKVC * N + n;
#pragma unroll 2
    for (int o = 0; o < QKVC; ++o) {
        const float* wr = wq + o * 64;       // uniform -> s_load
        float a0 = 0.f, a1 = 0.f;
#pragma unroll
        for (int c = 0; c < 64; c += 2) { a0 += wr[c] * v[c]; a1 += wr[c + 1] * v[c + 1]; }
        ob[(size_t)o * N] = (_Float16)(a0 + a1);
    }
}

// =========== depthwise 3x3, fp16 -> fp16, zero pad ===========
template<int CHAN>
__global__ __launch_bounds__(256, 1) void dw16_kernel(
    const _Float16* __restrict__ in, const float* __restrict__ w,
    _Float16* __restrict__ out)
{
    int bc = blockIdx.y;                 // b*CHAN + c
    int c = bc % CHAN;
    int n = blockIdx.x * 256 + threadIdx.x;
    int y = n >> 7, x = n & 127;
    const _Float16* ib = in + (size_t)bc * N;
    const float* wr = w + c * 9;         // uniform -> s_load
    float acc = 0.f;
#pragma unroll
    for (int dy = -1; dy <= 1; ++dy) {
        int yy = y + dy;
        if (yy < 0 || yy > 127) continue;
#pragma unroll
        for (int dx = -1; dx <= 1; ++dx) {
            int xx = x + dx;
            if (xx < 0 || xx > 127) continue;
            acc += wr[(dy + 1) * 3 + (dx + 1)] * (float)ib[yy * W + xx];
        }
    }
    out[(size_t)bc * N + n] = (_Float16)acc;
}

// =========== RSA window attention + fused proj; one block per 8x8 window ===========
__global__ __launch_bounds__(256) void rsa_win_kernel(
    const _Float16* __restrict__ qkv, const float* __restrict__ temp_p,
    const float* __restrict__ projw, float* __restrict__ out)
{
    __shared__ float qs[64 * 65];   // [p][c] stride 65; later overlaid by attn[c][d] stride 65
    __shared__ float ks[64 * 65];   // [p][c]; later overlaid by o[p][d] stride 65
    __shared__ float vt[64 * 64];   // [c][p]
    __shared__ float pwb[64 * 65];  // proj w [o][d] stride 65
    __shared__ float rq[64], rk[64];
    int blk = blockIdx.x;
    int b = blk >> 8, win = blk & 255;
    int y0 = (win >> 4) * 8, x0 = (win & 15) * 8;
    int t = threadIdx.x;
    const _Float16* qb = qkv + (size_t)b * QKVC * N;
    for (int idx = t; idx < 4096; idx += 256) {
        int c = idx >> 6, p = idx & 63;
        int g = (y0 + (p >> 3)) * W + x0 + (p & 7);
        qs[p * 65 + c] = (float)qb[(size_t)c * N + g];
        ks[p * 65 + c] = (float)qb[(size_t)(64 + c) * N + g];
        vt[c * 64 + p] = (float)qb[(size_t)(128 + c) * N + g];
        pwb[c * 65 + p] = projw[idx];   // pwb[o][d] with o=c, d=p
    }
    __syncthreads();
    if (t < 128) {
        int p = t & 63;
        const float* src = (t < 64) ? qs : ks;
        float s = 0.f;
#pragma unroll
        for (int c = 0; c < 64; ++c) { float v = src[p * 65 + c]; s += v * v; }
        float r = 1.0f / fmaxf(sqrtf(s), 1e-12f);
        if (t < 64) rq[p] = r; else rk[p] = r;
    }
    __syncthreads();
    for (int idx = t; idx < 4096; idx += 256) {
        int c = idx >> 6, p = idx & 63;
        qs[p * 65 + c] *= rq[p];
        ks[p * 65 + c] *= rk[p];
    }
    __syncthreads();
    float temp = temp_p[0];
    int c0 = (t & 15) * 4, d0 = (t >> 4) * 4;
    float s[4][4] = {};
    for (int p = 0; p < 64; ++p) {
        float qv[4], kv[4];
#pragma unroll
        for (int i = 0; i < 4; ++i) qv[i] = qs[p * 65 + c0 + i];
#pragma unroll
        for (int j = 0; j < 4; ++j) kv[j] = ks[p * 65 + d0 + j];
#pragma unroll
        for (int i = 0; i < 4; ++i)
#pragma unroll
            for (int j = 0; j < 4; ++j) s[i][j] += qv[i] * kv[j];
    }
    __syncthreads();
    float* at = qs;                // attn[c][d], stride 65
#pragma unroll
    for (int i = 0; i < 4; ++i)
#pragma unroll
        for (int j = 0; j < 4; ++j)
            at[(c0 + i) * 65 + d0 + j] = fmaxf(s[i][j] * temp, 0.f);
    __syncthreads();
    int p0 = (t & 15) * 4;
    float o[4][4] = {};
    for (int c = 0; c < 64; ++c) {
        float vv[4], av[4];
#pragma unroll
        for (int i = 0; i < 4; ++i) vv[i] = vt[c * 64 + p0 + i];
#pragma unroll
        for (int j = 0; j < 4; ++j) av[j] = at[c * 65 + d0 + j];
#pragma unroll
        for (int i = 0; i < 4; ++i)
#pragma unroll
            for (int j = 0; j < 4; ++j) o[i][j] += vv[i] * av[j];
    }
    float* obf = ks;               // o[p][d], stride 65
#pragma unroll
    for (int i = 0; i < 4; ++i)
#pragma unroll
        for (int j = 0; j < 4; ++j)
            obf[(p0 + i) * 65 + d0 + j] = o[i][j];
    __syncthreads();
    int oc0 = (t >> 4) * 4;
    float pr[4][4] = {};
    for (int d = 0; d < 64; ++d) {
        float ov[4], pv[4];
#pragma unroll
        for (int i = 0; i < 4; ++i) ov[i] = obf[(p0 + i) * 65 + d];
#pragma unroll
        for (int j = 0; j < 4; ++j) pv[j] = pwb[(oc0 + j) * 65 + d];
#pragma unroll
        for (int i = 0; i < 4; ++i)
#pragma unroll
            for (int j = 0; j < 4; ++j) pr[i][j] += ov[i] * pv[j];
    }
    float* ob = out + (size_t)b * C * N;
#pragma unroll
    for (int i = 0; i < 4; ++i) {
        int p = p0 + i;
        int g = (((y0 + (p >> 3)) + 4) & 127) * W + (((x0 + (p & 7)) + 4) & 127);
#pragma unroll
        for (int j = 0; j < 4; ++j)
            ob[(size_t)(oc0 + j) * N + g] = pr[i][j];
    }
}

// =========== FFN stage A: conv1x1 64->340, fp16 hidden out ===========
__global__ __launch_bounds__(256, 1) void ffn_a_kernel(
    const float* __restrict__ in,    // (B,64,N) LN'd
    const float* __restrict__ w1,    // (340,64)
    _Float16* __restrict__ hid)      // (B,340,N) fp16
{
    int pid = blockIdx.x * 256 + threadIdx.x;
    int b = pid >> 14, n = pid & (N - 1);
    const float* ib = in + (size_t)b * 64 * N + n;
    float v[64];
#pragma unroll
    for (int c = 0; c < 64; ++c) v[c] = ib[(size_t)c * N];
    _Float16* ob = hid + (size_t)b * 340 * N + n;
#pragma unroll 2
    for (int o = 0; o < 340; ++o) {
        const float* wr = w1 + o * 64;       // uniform -> s_load
        float a0 = 0.f, a1 = 0.f;
#pragma unroll
        for (int c = 0; c < 64; c += 2) { a0 += wr[c] * v[c]; a1 += wr[c + 1] * v[c + 1]; }
        ob[(size_t)o * N] = (_Float16)(a0 + a1);
    }
}

// =========== FFN stage B: dwconv3x3 + gelu gate, fp16 -> fp16 ===========
__global__ __launch_bounds__(256, 1) void ffn_b_kernel(
    const _Float16* __restrict__ hid,   // (B,340,N)
    const float* __restrict__ dww,      // (340,9)
    _Float16* __restrict__ gated)       // (B,170,N)
{
    int bc = blockIdx.y;                 // b*170 + c
    int b = bc / 170, c = bc % 170;
    int n = blockIdx.x * 256 + threadIdx.x;
    int y = n >> 7, x = n & 127;
    const _Float16* pa = hid + ((size_t)b * 340 + c) * N;
    const _Float16* pb = hid + ((size_t)b * 340 + 170 + c) * N;
    const float* wa = dww + c * 9;          // uniform -> s_load
    const float* wb = dww + (170 + c) * 9;
    float a = 0.f, g2 = 0.f;
#pragma unroll
    for (int dy = -1; dy <= 1; ++dy) {
        int yy = y + dy;
        if (yy < 0 || yy > 127) continue;
#pragma unroll
        for (int dx = -1; dx <= 1; ++dx) {
            int xx = x + dx;
            if (xx < 0 || xx > 127) continue;
            int idx = yy * W + xx, wi = (dy + 1) * 3 + dx + 1;
            a  += wa[wi] * (float)pa[idx];
            g2 += wb[wi] * (float)pb[idx];
        }
    }
    gated[((size_t)b * 170 + c) * N + n] = (_Float16)(gelu_exact(a) * g2);
}

// =========== FFN stage C: conv1x1 170->64 + residual ===========
__global__ __launch_bounds__(256, 1) void ffn_c_kernel(
    const _Float16* __restrict__ gated, // (B,170,N)
    const float* __restrict__ w2t,      // (170,64) transposed
    const float* __restrict__ resid,    // (B,64,N)
    float* __restrict__ out)            // (B,64,N)
{
    int pid = blockIdx.x * 256 + threadIdx.x;
    int b = pid >> 14, n = pid & (N - 1);
    const _Float16* ib = gated + (size_t)b * 170 * N + n;
    const float* rb = resid + (size_t)b * 64 * N + n;
    float acc[64];
#pragma unroll
    for (int o = 0; o < 64; ++o) acc[o] = rb[(size_t)o * N];
#pragma unroll 2
    for (int c = 0; c < 170; ++c) {
        float g = (float)ib[(size_t)c * N];
        const float* wr = w2t + c * 64;     // uniform -> s_load
#pragma unroll
        for (int o = 0; o < 64; ++o) acc[o] += wr[o] * g;
    }
    float* ob = out + (size_t)b * 64 * N + n;
#pragma unroll
    for (int o = 0; o < 64; ++o) ob[(size_t)o * N] = acc[o];
}

// =========== GSA phase A: per-(b,h,chunk) partial S[8][8], |q|^2[8], |k|^2[8] ===========
__global__ __launch_bounds__(256, 1) void gsa_part_kernel(
    const _Float16* __restrict__ qkv, float* __restrict__ part)
{
    int bh = blockIdx.y, chunk = blockIdx.x;    // bh in [0,64), chunk in [0,32)
    int b = bh >> 3, h = bh & 7;
    int t = threadIdx.x;
    const _Float16* qb = qkv + ((size_t)b * QKVC + h * 8) * N;
    const _Float16* kb = qb + (size_t)64 * N;
    float acc[80];
#pragma unroll
    for (int j = 0; j < 80; ++j) acc[j] = 0.f;
    for (int i = 0; i < 2; ++i) {
        int n = chunk * 512 + i * 256 + t;
        float qv[8], kv[8];
#pragma unroll
        for (int c = 0; c < 8; ++c) { qv[c] = (float)qb[(size_t)c * N + n]; kv[c] = (float)kb[(size_t)c * N + n]; }
#pragma unroll
        for (int c = 0; c < 8; ++c) {
            acc[64 + c] += qv[c] * qv[c];
            acc[72 + c] += kv[c] * kv[c];
#pragma unroll
            for (int d = 0; d < 8; ++d) acc[c * 8 + d] += qv[c] * kv[d];
        }
    }
#pragma unroll
    for (int j = 0; j < 80; ++j) {
        float v = acc[j];
#pragma unroll
        for (int m = 1; m < 64; m <<= 1) v += __shfl_xor(v, m, 64);
        acc[j] = v;
    }
    __shared__ float red[4 * 80];
    if ((t & 63) == 0) {
#pragma unroll
        for (int j = 0; j < 80; ++j) red[(t >> 6) * 80 + j] = acc[j];
    }
    __syncthreads();
    if (t < 80) {
        float s = red[t] + red[80 + t] + red[160 + t] + red[240 + t];
        part[((size_t)bh * 32 + chunk) * 80 + t] = s;
    }
}

// =========== GSA phase B ===========
__global__ __launch_bounds__(128) void gsa_fin_kernel(
    const float* __restrict__ part, const float* __restrict__ temp_p,
    float* __restrict__ attn)
{
    int bh = blockIdx.x;
    int t = threadIdx.x;
    __shared__ float red[80];
    if (t < 80) {
        float s = 0.f;
        for (int ch = 0; ch < 32; ++ch) s += part[((size_t)bh * 32 + ch) * 80 + t];
        red[t] = s;
    }
    __syncthreads();
    if (t < 64) {
        int c = t >> 3, d = t & 7;
        float S  = red[c * 8 + d];
        float qn = fmaxf(sqrtf(red[64 + c]), 1e-12f);
        float kn = fmaxf(sqrtf(red[72 + d]), 1e-12f);
        attn[(size_t)bh * 64 + t] = fmaxf(temp_p[0] * S / (qn * kn), 0.f);
    }
}

// =========== GSA phase C: W_eff[b][o][h*8+d] = sum_c proj_w[o, c*8+h] * attn[b,h,c,d] ===========
__global__ __launch_bounds__(64) void weff_kernel(
    const float* __restrict__ attn, const float* __restrict__ pw,
    float* __restrict__ weff)
{
    int b = blockIdx.x;
    int o = threadIdx.x;
    __shared__ float al[512];
    for (int idx = o; idx < 512; idx += 64) al[idx] = attn[(size_t)b * 512 + idx];
    __syncthreads();
    for (int hd = 0; hd < 64; ++hd) {
        int h = hd >> 3, d = hd & 7;
        float acc = 0.f;
#pragma unroll
        for (int c = 0; c < 8; ++c)
            acc += pw[o * 64 + c * 8 + h] * al[h * 64 + c * 8 + d];
        weff[((size_t)b * 64 + o) * 64 + hd] = acc;
    }
}

// =========== GSA output GEMM: out[b,o,n] = sum_hd weff[b,o,hd] * v[b,hd,n] ===========
__global__ __launch_bounds__(256, 1) void conv_pbw_kernel(
    const _Float16* __restrict__ vin,   // qkv v-part base, batch stride 192*N
    const float* __restrict__ weff,  // (B,64,64)
    float* __restrict__ out)         // (B,64,N)
{
    int pid = blockIdx.x * 256 + threadIdx.x;
    int b = pid >> 14, n = pid & (N - 1);
    const _Float16* ib = vin + (size_t)b * QKVC * N + n;
    float v[64];
#pragma unroll
    for (int c = 0; c < 64; ++c) v[c] = (float)ib[(size_t)c * N];
    const float* wb = weff + (size_t)b * 64 * 64;
    float* ob = out + (size_t)b * 64 * N + n;
#pragma unroll 2
    for (int o = 0; o < 64; ++o) {
        const float* wr = wb + o * 64;       // uniform -> s_load
        float a0 = 0.f, a1 = 0.f;
#pragma unroll
        for (int c = 0; c < 64; c += 2) { a0 += wr[c] * v[c]; a1 += wr[c + 1] * v[c + 1]; }
        ob[(size_t)o * N] = a0 + a1;
    }
}

// =========== small: transpose (64 x HID) -> (HID x 64) ===========
__global__ __launch_bounds__(256) void transpose_w_kernel(
    const float* __restrict__ w, float* __restrict__ wt)
{
    int idx = blockIdx.x * 256 + threadIdx.x;
    if (idx < 64 * HID) {
        int o = idx / HID, c = idx % HID;
        wt[c * 64 + o] = w[idx];
    }
}

// =========== sentinel: unmistakable signature if workspace is too small ===========
__global__ void sentinel_kernel(float* out, int n) {
    int i = blockIdx.x * 256 + threadIdx.x;
    if (i < n) out[i] = 12345.0f;
}

extern "C" void kernel_launch(void* const* d_in, const int* in_sizes, int n_in,
                              void* d_out, int out_size, void* d_ws, size_t ws_size,
                              hipStream_t stream)
{
    const float* x         = (const float*)d_in[0];
    const float* ln_s0_w   = (const float*)d_in[1];
    const float* ln_s0_b   = (const float*)d_in[2];
    const float* ln_s2_w   = (const float*)d_in[3];
    const float* ln_s2_b   = (const float*)d_in[4];
    const float* rsa_qkv_w = (const float*)d_in[5];
    const float* rsa_dw_w  = (const float*)d_in[6];
    const float* rsa_proj_w= (const float*)d_in[7];
    const float* rsa_temp  = (const float*)d_in[8];
    const float* ffs_in_w  = (const float*)d_in[9];
    const float* ffs_dw_w  = (const float*)d_in[10];
    const float* ffs_out_w = (const float*)d_in[11];
    const float* ln_c0_w   = (const float*)d_in[12];
    const float* ln_c0_b   = (const float*)d_in[13];
    const float* ln_c2_w   = (const float*)d_in[14];
    const float* ln_c2_b   = (const float*)d_in[15];
    const float* gsa_qkv_w = (const float*)d_in[16];
    const float* gsa_dw_w  = (const float*)d_in[17];
    const float* gsa_proj_w= (const float*)d_in[18];
    const float* gsa_temp  = (const float*)d_in[19];
    const float* ffc_in_w  = (const float*)d_in[20];
    const float* ffc_dw_w  = (const float*)d_in[21];
    const float* ffc_out_w = (const float*)d_in[22];
    float* outp = (float*)d_out;

    // workspace layout (total 168,662,016 B) -- same footprint as round 2/3 (verified fits)
    char* ws = (char*)d_ws;
    _Float16* tmp192 = (_Float16*)(ws + 0);          // (B,192,N) fp16 = 50,331,648 B (pre-dwconv)
    _Float16* Qbuf16 = (_Float16*)(ws + 50331648ull);// (B,192,N) fp16 = 50,331,648 B (qkv)
    _Float16* hidA   = (_Float16*)(ws + 0);          // (B,340,N) fp16 = 89,128,960 B (overlays tmp192+Qbuf16, both dead)
    _Float16* gated  = (_Float16*)(ws + 89128960ull);// (B,170,N) fp16 (overlays Qbuf16 tail + S1; S1 dead then)
    float*    S1     = (float*)(ws + 100663296ull);  // (B,64,N) fp32 = 33,554,432 B
    float*    S2     = (float*)(ws + 134217728ull);  // (B,64,N)
    float*    part   = (float*)(ws + 167772160ull);  // 64*32*80 f
    float*    attn_s = (float*)(ws + 168427520ull);  // 4096 f
    float*    weffb  = (float*)(ws + 168443904ull);  // 8*64*64 f
    float*    wt_s   = (float*)(ws + 168574976ull);  // 170*64 f
    float*    wt_c   = (float*)(ws + 168618496ull);  // 170*64 f
    if (ws_size < 168662016ull) {
        int n = out_size < 4096 ? out_size : 4096;
        sentinel_kernel<<<16, 256, 0, stream>>>(outp, n);
        return;
    }

    const int BN = B * N;
    dim3 blk256(256);

    transpose_w_kernel<<<43, blk256, 0, stream>>>(ffs_out_w, wt_s);
    transpose_w_kernel<<<43, blk256, 0, stream>>>(ffc_out_w, wt_c);

    // ---- spatial (RSA) half ----
    ln_kernel<<<BN / 256, blk256, 0, stream>>>(x, nullptr, ln_s0_w, ln_s0_b, S1);
    conv192_kernel<true><<<BN / 256, blk256, 0, stream>>>(S1, rsa_qkv_w, tmp192);
    dw16_kernel<192><<<dim3(N / 256, B * 192), blk256, 0, stream>>>(tmp192, rsa_dw_w, Qbuf16);
    rsa_win_kernel<<<B * 256, blk256, 0, stream>>>(Qbuf16, rsa_temp, rsa_proj_w, S2);     // x_ spatial
    ln_kernel<<<BN / 256, blk256, 0, stream>>>(S2, x, ln_s2_w, ln_s2_b, S1);              // LN(x_+x)
    ffn_a_kernel<<<BN / 256, blk256, 0, stream>>>(S1, ffs_in_w, hidA);                    // tmp192/Qbuf16 dead
    ffn_b_kernel<<<dim3(N / 256, B * 170), blk256, 0, stream>>>(hidA, ffs_dw_w, gated);   // S1 dead
    ffn_c_kernel<<<BN / 256, blk256, 0, stream>>>(gated, wt_s, S2, outp);                 // x -> d_out

    // ---- channel (GSA) half ----
    ln_kernel<<<BN / 256, blk256, 0, stream>>>(outp, nullptr, ln_c0_w, ln_c0_b, S1);
    conv192_kernel<false><<<BN / 256, blk256, 0, stream>>>(S1, gsa_qkv_w, tmp192);
    dw16_kernel<192><<<dim3(N / 256, B * 192), blk256, 0, stream>>>(tmp192, gsa_dw_w, Qbuf16);
    gsa_part_kernel<<<dim3(32, 64), blk256, 0, stream>>>(Qbuf16, part);
    gsa_fin_kernel<<<64, dim3(128), 0, stream>>>(part, gsa_temp, attn_s);
    weff_kernel<<<8, dim3(64), 0, stream>>>(attn_s, gsa_proj_w, weffb);
    conv_pbw_kernel<<<BN / 256, blk256, 0, stream>>>(Qbuf16 + (size_t)128 * N, weffb, S2); // x_ channel
    ln_kernel<<<BN / 256, blk256, 0, stream>>>(S2, outp, ln_c2_w, ln_c2_b, S1);           // LN(x_+x)
    ffn_a_kernel<<<BN / 256, blk256, 0, stream>>>(S1, ffc_in_w, hidA);
    ffn_b_kernel<<<dim3(N / 256, B * 170), blk256, 0, stream>>>(hidA, ffc_dw_w, gated);
    ffn_c_kernel<<<BN / 256, blk256, 0, stream>>>(gated, wt_c, S2, outp);                 // final
}

// Round 5
// 943.277 us; speedup vs baseline: 2.6402x; 1.9711x over previous
//
#include <hip/hip_runtime.h>
#include <hip/hip_bf16.h>
#include <math.h>

#define DI __device__ __forceinline__

constexpr int B = 8, C = 64, H = 128, W = 128, N = H * W;   // N = 16384
constexpr int HID = 170;
constexpr int QKVC = 3 * C;                                 // 192

typedef _Float16 half8 __attribute__((ext_vector_type(8)));
typedef float f32x4 __attribute__((ext_vector_type(4)));

DI float gelu_exact(float v) {
    return 0.5f * v * (1.0f + erff(v * 0.70710678118654752f));
}

// =========== LayerNorm over channels (+opt add), fp32 in -> fp16 out ===========
__global__ __launch_bounds__(256, 1) void ln16_kernel(
    const float* __restrict__ in, const float* __restrict__ add,
    const float* __restrict__ w, const float* __restrict__ bias,
    _Float16* __restrict__ out)
{
    int pid = blockIdx.x * 256 + threadIdx.x;
    int b = pid >> 14, n = pid & (N - 1);
    size_t base = (size_t)b * C * N + n;
    float vals[C];
    float s = 0.f;
#pragma unroll
    for (int c = 0; c < C; ++c) {
        float v = in[base + (size_t)c * N];
        if (add) v += add[base + (size_t)c * N];
        vals[c] = v; s += v;
    }
    float mean = s * (1.0f / C);
    float vs = 0.f;
#pragma unroll
    for (int c = 0; c < C; ++c) { float d = vals[c] - mean; vals[c] = d; vs += d * d; }
    float rstd = rsqrtf(vs * (1.0f / C) + 1e-5f);
#pragma unroll
    for (int c = 0; c < C; ++c)
        out[base + (size_t)c * N] = (_Float16)(vals[c] * rstd * w[c] + bias[c]);
}

// =========== weight pre-pack into MFMA A-fragment order, fp32 -> fp16 ===========
// frag f = mt*KT + kt; lane l element i <- W[mt*16 + (l&15)][kt*32 + (l>>4)*8 + i]
__global__ __launch_bounds__(64) void wpack_kernel(
    const float* __restrict__ Wm, int OREAL, int KREAL, int KT,
    _Float16* __restrict__ out)
{
    int f = blockIdx.x, l = threadIdx.x;
    int mt = f / KT, kt = f % KT;
    int row = mt * 16 + (l & 15);
    int col0 = kt * 32 + (l >> 4) * 8;
    half8 v;
#pragma unroll
    for (int i = 0; i < 8; ++i) {
        int col = col0 + i;
        v[i] = (row < OREAL && col < KREAL) ? (_Float16)Wm[row * KREAL + col] : (_Float16)0.f;
    }
    *(half8*)(out + (size_t)f * 512 + l * 8) = v;
}

// =========== per-batch weff pack (O=64, K=64 -> 8 frags/batch) ===========
__global__ __launch_bounds__(512) void weffpack_kernel(
    const float* __restrict__ weff, _Float16* __restrict__ out)
{
    int b = blockIdx.x;
    int f = threadIdx.x >> 6, l = threadIdx.x & 63;
    int mt = f >> 1, kt = f & 1;
    int row = mt * 16 + (l & 15);
    int col0 = kt * 32 + (l >> 4) * 8;
    const float* wb = weff + (size_t)b * 4096;
    half8 v;
#pragma unroll
    for (int i = 0; i < 8; ++i) v[i] = (_Float16)wb[row * 64 + col0 + i];
    *(half8*)(out + ((size_t)b * 8 + f) * 512 + l * 8) = v;
}

// =========== MFMA conv1x1 GEMM: out[b,o,n] = sum_c W[o,c] X[b,c,n] ===========
// MT m-tiles/wave, KT k-tiles, MG wave-m-groups (4/MG pixel groups), NSTRIP strips.
// X fp16 (batch stride XROWS*N). W packed frags. OUT32: fp32 out (+opt resid), else fp16.
template<int MT, int KT, int MG, int NSTRIP, int CIN, int OREAL, int XROWS,
         bool PBW, bool OUT32, bool RESID>
__global__ __launch_bounds__(256, 1) void gemm_kernel(
    const _Float16* __restrict__ X, const _Float16* __restrict__ Wp,
    const float* __restrict__ resid, void* __restrict__ outv)
{
    constexpr int PG = 4 / MG;
    constexpr int PPB = PG * 16 * NSTRIP;
    int t = threadIdx.x;
    int lane = t & 63, wv = t >> 6;
    int mg = wv % MG, pg = wv / MG;
    int pbase = blockIdx.x * PPB;
    int b = pbase >> 14, nb = pbase & (N - 1);

    // resident A fragments
    half8 a[MT][KT];
    const _Float16* wb = Wp + ((size_t)(PBW ? b * (MG * MT * KT) : 0) + mg * MT * KT) * 512 + lane * 8;
#pragma unroll
    for (int mt = 0; mt < MT; ++mt)
#pragma unroll
        for (int kt = 0; kt < KT; ++kt)
            a[mt][kt] = *(const half8*)(wb + (mt * KT + kt) * 512);

    const _Float16* xb = X + (size_t)b * XROWS * N;
    int krow0 = (lane >> 4) * 8;

    for (int s = 0; s < NSTRIP; ++s) {
        int col = nb + (s * PG + pg) * 16 + (lane & 15);
        const _Float16* xp = xb + col;
        half8 bf[KT];
#pragma unroll
        for (int kt = 0; kt < KT; ++kt)
#pragma unroll
            for (int i = 0; i < 8; ++i) {
                int c = kt * 32 + krow0 + i;
                if (KT * 32 <= CIN || c < CIN) bf[kt][i] = xp[(size_t)c * N];
                else bf[kt][i] = (_Float16)0.f;
            }
        f32x4 acc[MT];
#pragma unroll
        for (int mt = 0; mt < MT; ++mt) acc[mt] = (f32x4){0.f, 0.f, 0.f, 0.f};
#pragma unroll
        for (int kt = 0; kt < KT; ++kt)
#pragma unroll
            for (int mt = 0; mt < MT; ++mt)
                acc[mt] = __builtin_amdgcn_mfma_f32_16x16x32_f16(a[mt][kt], bf[kt], acc[mt], 0, 0, 0);

        int orow0 = mg * (MT * 16) + (lane >> 4) * 4;
#pragma unroll
        for (int mt = 0; mt < MT; ++mt)
#pragma unroll
            for (int r = 0; r < 4; ++r) {
                int orow = orow0 + mt * 16 + r;
                bool ok = (MG * MT * 16 == OREAL) || (orow < OREAL);
                if (ok) {
                    size_t oidx = ((size_t)b * OREAL + orow) * N + col;
                    if constexpr (OUT32) {
                        float vv = acc[mt][r];
                        if constexpr (RESID) vv += resid[((size_t)b * 64 + orow) * N + col];
                        ((float*)outv)[oidx] = vv;
                    } else {
                        ((_Float16*)outv)[oidx] = (_Float16)acc[mt][r];
                    }
                }
            }
    }
}

// =========== depthwise 3x3, fp16 -> fp16; ROLL folds RSA's -4 shift into the gather ===========
template<bool ROLL>
__global__ __launch_bounds__(256, 1) void dw16_kernel(
    const _Float16* __restrict__ in, const float* __restrict__ w,
    _Float16* __restrict__ out)
{
    int bc = blockIdx.y;                 // b*192 + c
    int c = bc % 192;
    int n = blockIdx.x * 256 + threadIdx.x;
    int y = n >> 7, x = n & 127;
    const _Float16* ib = in + (size_t)bc * N;
    const float* wr = w + c * 9;         // uniform -> s_load
    float acc = 0.f;
#pragma unroll
    for (int dy = -1; dy <= 1; ++dy) {
        int yy = y + dy;
        if (yy < 0 || yy > 127) continue;
#pragma unroll
        for (int dx = -1; dx <= 1; ++dx) {
            int xx = x + dx;
            if (xx < 0 || xx > 127) continue;
            int sy = ROLL ? ((yy + 4) & 127) : yy;
            int sx = ROLL ? ((xx + 4) & 127) : xx;
            acc += wr[(dy + 1) * 3 + (dx + 1)] * (float)ib[sy * W + sx];
        }
    }
    out[(size_t)bc * N + n] = (_Float16)acc;
}

// =========== RSA window attention + fused proj; one block per 8x8 window ===========
__global__ __launch_bounds__(256) void rsa_win_kernel(
    const _Float16* __restrict__ qkv, const float* __restrict__ temp_p,
    const float* __restrict__ projw, float* __restrict__ out)
{
    __shared__ float qs[64 * 65];
    __shared__ float ks[64 * 65];
    __shared__ float vt[64 * 64];
    __shared__ float pwb[64 * 65];
    __shared__ float rq[64], rk[64];
    int blk = blockIdx.x;
    int b = blk >> 8, win = blk & 255;
    int y0 = (win >> 4) * 8, x0 = (win & 15) * 8;
    int t = threadIdx.x;
    const _Float16* qb = qkv + (size_t)b * QKVC * N;
    for (int idx = t; idx < 4096; idx += 256) {
        int c = idx >> 6, p = idx & 63;
        int g = (y0 + (p >> 3)) * W + x0 + (p & 7);
        qs[p * 65 + c] = (float)qb[(size_t)c * N + g];
        ks[p * 65 + c] = (float)qb[(size_t)(64 + c) * N + g];
        vt[c * 64 + p] = (float)qb[(size_t)(128 + c) * N + g];
        pwb[c * 65 + p] = projw[idx];
    }
    __syncthreads();
    if (t < 128) {
        int p = t & 63;
        const float* src = (t < 64) ? qs : ks;
        float s = 0.f;
#pragma unroll
        for (int c = 0; c < 64; ++c) { float v = src[p * 65 + c]; s += v * v; }
        float r = 1.0f / fmaxf(sqrtf(s), 1e-12f);
        if (t < 64) rq[p] = r; else rk[p] = r;
    }
    __syncthreads();
    for (int idx = t; idx < 4096; idx += 256) {
        int c = idx >> 6, p = idx & 63;
        qs[p * 65 + c] *= rq[p];
        ks[p * 65 + c] *= rk[p];
    }
    __syncthreads();
    float temp = temp_p[0];
    int c0 = (t & 15) * 4, d0 = (t >> 4) * 4;
    float s[4][4] = {};
    for (int p = 0; p < 64; ++p) {
        float qv[4], kv[4];
#pragma unroll
        for (int i = 0; i < 4; ++i) qv[i] = qs[p * 65 + c0 + i];
#pragma unroll
        for (int j = 0; j < 4; ++j) kv[j] = ks[p * 65 + d0 + j];
#pragma unroll
        for (int i = 0; i < 4; ++i)
#pragma unroll
            for (int j = 0; j < 4; ++j) s[i][j] += qv[i] * kv[j];
    }
    __syncthreads();
    float* at = qs;
#pragma unroll
    for (int i = 0; i < 4; ++i)
#pragma unroll
        for (int j = 0; j < 4; ++j)
            at[(c0 + i) * 65 + d0 + j] = fmaxf(s[i][j] * temp, 0.f);
    __syncthreads();
    int p0 = (t & 15) * 4;
    float o[4][4] = {};
    for (int c = 0; c < 64; ++c) {
        float vv[4], av[4];
#pragma unroll
        for (int i = 0; i < 4; ++i) vv[i] = vt[c * 64 + p0 + i];
#pragma unroll
        for (int j = 0; j < 4; ++j) av[j] = at[c * 65 + d0 + j];
#pragma unroll
        for (int i = 0; i < 4; ++i)
#pragma unroll
            for (int j = 0; j < 4; ++j) o[i][j] += vv[i] * av[j];
    }
    float* obf = ks;
#pragma unroll
    for (int i = 0; i < 4; ++i)
#pragma unroll
        for (int j = 0; j < 4; ++j)
            obf[(p0 + i) * 65 + d0 + j] = o[i][j];
    __syncthreads();
    int oc0 = (t >> 4) * 4;
    float pr[4][4] = {};
    for (int d = 0; d < 64; ++d) {
        float ov[4], pv[4];
#pragma unroll
        for (int i = 0; i < 4; ++i) ov[i] = obf[(p0 + i) * 65 + d];
#pragma unroll
        for (int j = 0; j < 4; ++j) pv[j] = pwb[(oc0 + j) * 65 + d];
#pragma unroll
        for (int i = 0; i < 4; ++i)
#pragma unroll
            for (int j = 0; j < 4; ++j) pr[i][j] += ov[i] * pv[j];
    }
    float* ob = out + (size_t)b * C * N;
#pragma unroll
    for (int i = 0; i < 4; ++i) {
        int p = p0 + i;
        int g = (((y0 + (p >> 3)) + 4) & 127) * W + (((x0 + (p & 7)) + 4) & 127);
#pragma unroll
        for (int j = 0; j < 4; ++j)
            ob[(size_t)(oc0 + j) * N + g] = pr[i][j];
    }
}

// =========== FFN stage B: dwconv3x3 + gelu gate, fp16 -> fp16 ===========
__global__ __launch_bounds__(256, 1) void ffn_b_kernel(
    const _Float16* __restrict__ hid,   // (B,340,N)
    const float* __restrict__ dww,      // (340,9)
    _Float16* __restrict__ gated)       // (B,170,N)
{
    int bc = blockIdx.y;                 // b*170 + c
    int b = bc / 170, c = bc % 170;
    int n = blockIdx.x * 256 + threadIdx.x;
    int y = n >> 7, x = n & 127;
    const _Float16* pa = hid + ((size_t)b * 340 + c) * N;
    const _Float16* pb = hid + ((size_t)b * 340 + 170 + c) * N;
    const float* wa = dww + c * 9;
    const float* wb = dww + (170 + c) * 9;
    float a = 0.f, g2 = 0.f;
#pragma unroll
    for (int dy = -1; dy <= 1; ++dy) {
        int yy = y + dy;
        if (yy < 0 || yy > 127) continue;
#pragma unroll
        for (int dx = -1; dx <= 1; ++dx) {
            int xx = x + dx;
            if (xx < 0 || xx > 127) continue;
            int idx = yy * W + xx, wi = (dy + 1) * 3 + dx + 1;
            a  += wa[wi] * (float)pa[idx];
            g2 += wb[wi] * (float)pb[idx];
        }
    }
    gated[((size_t)b * 170 + c) * N + n] = (_Float16)(gelu_exact(a) * g2);
}

// =========== GSA phase A ===========
__global__ __launch_bounds__(256, 1) void gsa_part_kernel(
    const _Float16* __restrict__ qkv, float* __restrict__ part)
{
    int bh = blockIdx.y, chunk = blockIdx.x;
    int b = bh >> 3, h = bh & 7;
    int t = threadIdx.x;
    const _Float16* qb = qkv + ((size_t)b * QKVC + h * 8) * N;
    const _Float16* kb = qb + (size_t)64 * N;
    float acc[80];
#pragma unroll
    for (int j = 0; j < 80; ++j) acc[j] = 0.f;
    for (int i = 0; i < 2; ++i) {
        int n = chunk * 512 + i * 256 + t;
        float qv[8], kv[8];
#pragma unroll
        for (int c = 0; c < 8; ++c) { qv[c] = (float)qb[(size_t)c * N + n]; kv[c] = (float)kb[(size_t)c * N + n]; }
#pragma unroll
        for (int c = 0; c < 8; ++c) {
            acc[64 + c] += qv[c] * qv[c];
            acc[72 + c] += kv[c] * kv[c];
#pragma unroll
            for (int d = 0; d < 8; ++d) acc[c * 8 + d] += qv[c] * kv[d];
        }
    }
#pragma unroll
    for (int j = 0; j < 80; ++j) {
        float v = acc[j];
#pragma unroll
        for (int m = 1; m < 64; m <<= 1) v += __shfl_xor(v, m, 64);
        acc[j] = v;
    }
    __shared__ float red[4 * 80];
    if ((t & 63) == 0) {
#pragma unroll
        for (int j = 0; j < 80; ++j) red[(t >> 6) * 80 + j] = acc[j];
    }
    __syncthreads();
    if (t < 80) {
        float s = red[t] + red[80 + t] + red[160 + t] + red[240 + t];
        part[((size_t)bh * 32 + chunk) * 80 + t] = s;
    }
}

// =========== GSA phase B ===========
__global__ __launch_bounds__(128) void gsa_fin_kernel(
    const float* __restrict__ part, const float* __restrict__ temp_p,
    float* __restrict__ attn)
{
    int bh = blockIdx.x;
    int t = threadIdx.x;
    __shared__ float red[80];
    if (t < 80) {
        float s = 0.f;
        for (int ch = 0; ch < 32; ++ch) s += part[((size_t)bh * 32 + ch) * 80 + t];
        red[t] = s;
    }
    __syncthreads();
    if (t < 64) {
        int c = t >> 3, d = t & 7;
        float S  = red[c * 8 + d];
        float qn = fmaxf(sqrtf(red[64 + c]), 1e-12f);
        float kn = fmaxf(sqrtf(red[72 + d]), 1e-12f);
        attn[(size_t)bh * 64 + t] = fmaxf(temp_p[0] * S / (qn * kn), 0.f);
    }
}

// =========== GSA phase C: W_eff ===========
__global__ __launch_bounds__(64) void weff_kernel(
    const float* __restrict__ attn, const float* __restrict__ pw,
    float* __restrict__ weff)
{
    int b = blockIdx.x;
    int o = threadIdx.x;
    __shared__ float al[512];
    for (int idx = o; idx < 512; idx += 64) al[idx] = attn[(size_t)b * 512 + idx];
    __syncthreads();
    for (int hd = 0; hd < 64; ++hd) {
        int h = hd >> 3, d = hd & 7;
        float acc = 0.f;
#pragma unroll
        for (int c = 0; c < 8; ++c)
            acc += pw[o * 64 + c * 8 + h] * al[h * 64 + c * 8 + d];
        weff[((size_t)b * 64 + o) * 64 + hd] = acc;
    }
}

// =========== sentinel ===========
__global__ void sentinel_kernel(float* out, int n) {
    int i = blockIdx.x * 256 + threadIdx.x;
    if (i < n) out[i] = 12345.0f;
}

extern "C" void kernel_launch(void* const* d_in, const int* in_sizes, int n_in,
                              void* d_out, int out_size, void* d_ws, size_t ws_size,
                              hipStream_t stream)
{
    const float* x         = (const float*)d_in[0];
    const float* ln_s0_w   = (const float*)d_in[1];
    const float* ln_s0_b   = (const float*)d_in[2];
    const float* ln_s2_w   = (const float*)d_in[3];
    const float* ln_s2_b   = (const float*)d_in[4];
    const float* rsa_qkv_w = (const float*)d_in[5];
    const float* rsa_dw_w  = (const float*)d_in[6];
    const float* rsa_proj_w= (const float*)d_in[7];
    const float* rsa_temp  = (const float*)d_in[8];
    const float* ffs_in_w  = (const float*)d_in[9];
    const float* ffs_dw_w  = (const float*)d_in[10];
    const float* ffs_out_w = (const float*)d_in[11];
    const float* ln_c0_w   = (const float*)d_in[12];
    const float* ln_c0_b   = (const float*)d_in[13];
    const float* ln_c2_w   = (const float*)d_in[14];
    const float* ln_c2_b   = (const float*)d_in[15];
    const float* gsa_qkv_w = (const float*)d_in[16];
    const float* gsa_dw_w  = (const float*)d_in[17];
    const float* gsa_proj_w= (const float*)d_in[18];
    const float* gsa_temp  = (const float*)d_in[19];
    const float* ffc_in_w  = (const float*)d_in[20];
    const float* ffc_dw_w  = (const float*)d_in[21];
    const float* ffc_out_w = (const float*)d_in[22];
    float* outp = (float*)d_out;

    // ---- workspace layout (total 168,828,928 B) ----
    char* ws = (char*)d_ws;
    _Float16* tmp192 = (_Float16*)(ws + 0);            // (B,192,N) fp16 [0, 50,331,648)
    _Float16* Qbuf16 = (_Float16*)(ws + 50331648ull);  // (B,192,N) fp16 [50,331,648, 100,663,296)
    _Float16* hidA   = (_Float16*)(ws + 0);            // (B,340,N) fp16 overlay [0, 89,128,960)
    _Float16* L16    = (_Float16*)(ws + 89128960ull);  // (B,64,N) fp16 [89,128,960, 105,906,176)
    _Float16* gated  = (_Float16*)(ws + 89128960ull);  // (B,170,N) fp16 overlay (kills L16 after ffn_a)
    float*    S2     = (float*)(ws + 134217728ull);    // (B,64,N) fp32 [134,217,728, 167,772,160)
    float*    part   = (float*)(ws + 167772160ull);    // 655,360
    float*    attn_s = (float*)(ws + 168427520ull);    // 16,384
    float*    weffb  = (float*)(ws + 168443904ull);    // 131,072
    _Float16* wp_rsa = (_Float16*)(ws + 168574976ull); // 24,576
    _Float16* wp_gsa = (_Float16*)(ws + 168599552ull); // 24,576
    _Float16* wp_fsi = (_Float16*)(ws + 168624128ull); // 45,056
    _Float16* wp_fci = (_Float16*)(ws + 168669184ull); // 45,056
    _Float16* wp_fso = (_Float16*)(ws + 168714240ull); // 24,576
    _Float16* wp_fco = (_Float16*)(ws + 168738816ull); // 24,576
    _Float16* wp_pbw = (_Float16*)(ws + 168763392ull); // 65,536 -> ends 168,828,928
    if (ws_size < 168828928ull) {
        int n = out_size < 4096 ? out_size : 4096;
        sentinel_kernel<<<16, 256, 0, stream>>>(outp, n);
        return;
    }

    dim3 blk256(256);

    // ---- weight packs (tiny) ----
    wpack_kernel<<<24, 64, 0, stream>>>(rsa_qkv_w, 192, 64, 2, wp_rsa);
    wpack_kernel<<<24, 64, 0, stream>>>(gsa_qkv_w, 192, 64, 2, wp_gsa);
    wpack_kernel<<<44, 64, 0, stream>>>(ffs_in_w, 340, 64, 2, wp_fsi);
    wpack_kernel<<<44, 64, 0, stream>>>(ffc_in_w, 340, 64, 2, wp_fci);
    wpack_kernel<<<24, 64, 0, stream>>>(ffs_out_w, 64, 170, 6, wp_fso);
    wpack_kernel<<<24, 64, 0, stream>>>(ffc_out_w, 64, 170, 6, wp_fco);

    // ---- spatial (RSA) half ----
    ln16_kernel<<<512, blk256, 0, stream>>>(x, nullptr, ln_s0_w, ln_s0_b, L16);
    gemm_kernel<6, 2, 2, 2, 64, 192, 64, false, false, false>
        <<<2048, blk256, 0, stream>>>(L16, wp_rsa, nullptr, tmp192);
    dw16_kernel<true><<<dim3(64, B * 192), blk256, 0, stream>>>(tmp192, rsa_dw_w, Qbuf16);
    rsa_win_kernel<<<2048, blk256, 0, stream>>>(Qbuf16, rsa_temp, rsa_proj_w, S2);        // x_ spatial
    ln16_kernel<<<512, blk256, 0, stream>>>(S2, x, ln_s2_w, ln_s2_b, L16);                // LN(x_+x)
    gemm_kernel<11, 2, 2, 2, 64, 340, 64, false, false, false>
        <<<2048, blk256, 0, stream>>>(L16, wp_fsi, nullptr, hidA);
    ffn_b_kernel<<<dim3(64, B * 170), blk256, 0, stream>>>(hidA, ffs_dw_w, gated);
    gemm_kernel<2, 6, 2, 2, 170, 64, 170, false, true, true>
        <<<2048, blk256, 0, stream>>>(gated, wp_fso, S2, outp);                           // x -> d_out

    // ---- channel (GSA) half ----
    ln16_kernel<<<512, blk256, 0, stream>>>(outp, nullptr, ln_c0_w, ln_c0_b, L16);
    gemm_kernel<6, 2, 2, 2, 64, 192, 64, false, false, false>
        <<<2048, blk256, 0, stream>>>(L16, wp_gsa, nullptr, tmp192);
    dw16_kernel<false><<<dim3(64, B * 192), blk256, 0, stream>>>(tmp192, gsa_dw_w, Qbuf16);
    gsa_part_kernel<<<dim3(32, 64), blk256, 0, stream>>>(Qbuf16, part);
    gsa_fin_kernel<<<64, dim3(128), 0, stream>>>(part, gsa_temp, attn_s);
    weff_kernel<<<8, dim3(64), 0, stream>>>(attn_s, gsa_proj_w, weffb);
    weffpack_kernel<<<8, dim3(512), 0, stream>>>(weffb, wp_pbw);
    gemm_kernel<4, 2, 1, 1, 64, 64, 192, true, true, false>
        <<<2048, blk256, 0, stream>>>(Qbuf16 + (size_t)128 * N, wp_pbw, nullptr, S2);     // x_ channel
    ln16_kernel<<<512, blk256, 0, stream>>>(S2, outp, ln_c2_w, ln_c2_b, L16);             // LN(x_+x)
    gemm_kernel<11, 2, 2, 2, 64, 340, 64, false, false, false>
        <<<2048, blk256, 0, stream>>>(L16, wp_fci, nullptr, hidA);
    ffn_b_kernel<<<dim3(64, B * 170), blk256, 0, stream>>>(hidA, ffc_dw_w, gated);
    gemm_kernel<2, 6, 2, 2, 170, 64, 170, false, true, true>
        <<<2048, blk256, 0, stream>>>(gated, wp_fco, S2, outp);                           // final
}

// Round 6
// 840.816 us; speedup vs baseline: 2.9619x; 1.1219x over previous
//
#include <hip/hip_runtime.h>
#include <hip/hip_bf16.h>
#include <math.h>

#define DI __device__ __forceinline__

constexpr int B = 8, C = 64, H = 128, W = 128, N = H * W;   // N = 16384
constexpr int HID = 170;
constexpr int QKVC = 3 * C;                                 // 192

typedef _Float16 half8 __attribute__((ext_vector_type(8)));
typedef _Float16 half4v __attribute__((ext_vector_type(4)));
typedef float f32x4 __attribute__((ext_vector_type(4)));

DI float gelu_exact(float v) {
    return 0.5f * v * (1.0f + erff(v * 0.70710678118654752f));
}

// =========== LayerNorm over channels (+opt add), fp32 in -> fp16 out ===========
__global__ __launch_bounds__(256, 1) void ln16_kernel(
    const float* __restrict__ in, const float* __restrict__ add,
    const float* __restrict__ w, const float* __restrict__ bias,
    _Float16* __restrict__ out)
{
    int pid = blockIdx.x * 256 + threadIdx.x;
    int b = pid >> 14, n = pid & (N - 1);
    size_t base = (size_t)b * C * N + n;
    float vals[C];
    float s = 0.f;
#pragma unroll
    for (int c = 0; c < C; ++c) {
        float v = in[base + (size_t)c * N];
        if (add) v += add[base + (size_t)c * N];
        vals[c] = v; s += v;
    }
    float mean = s * (1.0f / C);
    float vs = 0.f;
#pragma unroll
    for (int c = 0; c < C; ++c) { float d = vals[c] - mean; vals[c] = d; vs += d * d; }
    float rstd = rsqrtf(vs * (1.0f / C) + 1e-5f);
#pragma unroll
    for (int c = 0; c < C; ++c)
        out[base + (size_t)c * N] = (_Float16)(vals[c] * rstd * w[c] + bias[c]);
}

// =========== weight pre-pack into MFMA A-fragment order, fp32 -> fp16 ===========
// frag f = mt*KT + kt; lane l element i <- W[mt*16 + (l&15)][kt*32 + (l>>4)*8 + i]
__global__ __launch_bounds__(64) void wpack_kernel(
    const float* __restrict__ Wm, int OREAL, int KREAL, int KT,
    _Float16* __restrict__ out)
{
    int f = blockIdx.x, l = threadIdx.x;
    int mt = f / KT, kt = f % KT;
    int row = mt * 16 + (l & 15);
    int col0 = kt * 32 + (l >> 4) * 8;
    half8 v;
#pragma unroll
    for (int i = 0; i < 8; ++i) {
        int col = col0 + i;
        v[i] = (row < OREAL && col < KREAL) ? (_Float16)Wm[row * KREAL + col] : (_Float16)0.f;
    }
    *(half8*)(out + (size_t)f * 512 + l * 8) = v;
}

// =========== per-batch weff pack (O=64, K=64 -> 8 frags/batch) ===========
__global__ __launch_bounds__(512) void weffpack_kernel(
    const float* __restrict__ weff, _Float16* __restrict__ out)
{
    int b = blockIdx.x;
    int f = threadIdx.x >> 6, l = threadIdx.x & 63;
    int mt = f >> 1, kt = f & 1;
    int row = mt * 16 + (l & 15);
    int col0 = kt * 32 + (l >> 4) * 8;
    const float* wb = weff + (size_t)b * 4096;
    half8 v;
#pragma unroll
    for (int i = 0; i < 8; ++i) v[i] = (_Float16)wb[row * 64 + col0 + i];
    *(half8*)(out + ((size_t)b * 8 + f) * 512 + l * 8) = v;
}

// =========== MFMA conv1x1 GEMM: out[b,o,n] = sum_c W[o,c] X[b,c,n] ===========
template<int MT, int KT, int MG, int NSTRIP, int CIN, int OREAL, int XROWS,
         bool PBW, bool OUT32, bool RESID>
__global__ __launch_bounds__(256, 1) void gemm_kernel(
    const _Float16* __restrict__ X, const _Float16* __restrict__ Wp,
    const float* __restrict__ resid, void* __restrict__ outv)
{
    constexpr int PG = 4 / MG;
    constexpr int PPB = PG * 16 * NSTRIP;
    int t = threadIdx.x;
    int lane = t & 63, wv = t >> 6;
    int mg = wv % MG, pg = wv / MG;
    int pbase = blockIdx.x * PPB;
    int b = pbase >> 14, nb = pbase & (N - 1);

    half8 a[MT][KT];
    const _Float16* wb = Wp + ((size_t)(PBW ? b * (MG * MT * KT) : 0) + mg * MT * KT) * 512 + lane * 8;
#pragma unroll
    for (int mt = 0; mt < MT; ++mt)
#pragma unroll
        for (int kt = 0; kt < KT; ++kt)
            a[mt][kt] = *(const half8*)(wb + (mt * KT + kt) * 512);

    const _Float16* xb = X + (size_t)b * XROWS * N;
    int krow0 = (lane >> 4) * 8;

    for (int s = 0; s < NSTRIP; ++s) {
        int col = nb + (s * PG + pg) * 16 + (lane & 15);
        const _Float16* xp = xb + col;
        half8 bf[KT];
#pragma unroll
        for (int kt = 0; kt < KT; ++kt)
#pragma unroll
            for (int i = 0; i < 8; ++i) {
                int c = kt * 32 + krow0 + i;
                if (KT * 32 <= CIN || c < CIN) bf[kt][i] = xp[(size_t)c * N];
                else bf[kt][i] = (_Float16)0.f;
            }
        f32x4 acc[MT];
#pragma unroll
        for (int mt = 0; mt < MT; ++mt) acc[mt] = (f32x4){0.f, 0.f, 0.f, 0.f};
#pragma unroll
        for (int kt = 0; kt < KT; ++kt)
#pragma unroll
            for (int mt = 0; mt < MT; ++mt)
                acc[mt] = __builtin_amdgcn_mfma_f32_16x16x32_f16(a[mt][kt], bf[kt], acc[mt], 0, 0, 0);

        int orow0 = mg * (MT * 16) + (lane >> 4) * 4;
#pragma unroll
        for (int mt = 0; mt < MT; ++mt)
#pragma unroll
            for (int r = 0; r < 4; ++r) {
                int orow = orow0 + mt * 16 + r;
                bool ok = (MG * MT * 16 == OREAL) || (orow < OREAL);
                if (ok) {
                    size_t oidx = ((size_t)b * OREAL + orow) * N + col;
                    if constexpr (OUT32) {
                        float vv = acc[mt][r];
                        if constexpr (RESID) vv += resid[((size_t)b * 64 + orow) * N + col];
                        ((float*)outv)[oidx] = vv;
                    } else {
                        ((_Float16*)outv)[oidx] = (_Float16)acc[mt][r];
                    }
                }
            }
    }
}

// =========== depthwise 3x3 fp16->fp16; ROLLWM: rolled gather + window-major write ===========
template<bool ROLLWM>
__global__ __launch_bounds__(256, 1) void dw16_kernel(
    const _Float16* __restrict__ in, const float* __restrict__ w,
    _Float16* __restrict__ out)
{
    int bc = blockIdx.y;                 // b*192 + c
    int c = bc % 192;
    int n = blockIdx.x * 256 + threadIdx.x;
    int y = n >> 7, x = n & 127;
    const _Float16* ib = in + (size_t)bc * N;
    const float* wr = w + c * 9;         // uniform -> s_load
    float acc = 0.f;
#pragma unroll
    for (int dy = -1; dy <= 1; ++dy) {
        int yy = y + dy;
        if (yy < 0 || yy > 127) continue;
#pragma unroll
        for (int dx = -1; dx <= 1; ++dx) {
            int xx = x + dx;
            if (xx < 0 || xx > 127) continue;
            int sy = ROLLWM ? ((yy + 4) & 127) : yy;
            int sx = ROLLWM ? ((xx + 4) & 127) : xx;
            acc += wr[(dy + 1) * 3 + (dx + 1)] * (float)ib[sy * W + sx];
        }
    }
    if (ROLLWM) {
        int win = ((y >> 3) << 4) | (x >> 3);
        int p = ((y & 7) << 3) | (x & 7);
        out[(size_t)bc * N + win * 64 + p] = (_Float16)acc;
    } else {
        out[(size_t)bc * N + n] = (_Float16)acc;
    }
}

// =========== RSA window attention (MFMA) + fused proj; one block per window ===========
// qkv window-major (B,192,256,64); pwp = packed proj frags; out = x_ (B,64,N) rolled back
__global__ __launch_bounds__(256, 3) void rsa_win_kernel(
    const _Float16* __restrict__ qkv, const float* __restrict__ temp_p,
    const _Float16* __restrict__ pwp, float* __restrict__ out)
{
    __shared__ _Float16 qT[64][72];   // q [c][p]
    __shared__ _Float16 kT[64][72];   // k [d][p]
    __shared__ _Float16 vP[64][76];   // v transposed [p][c]
    __shared__ _Float16 aT[64][76];   // attn [c][d]
    __shared__ _Float16 oP[64][76];   // out [p][d]
    __shared__ float tnorm[128];
    __shared__ _Float16 wsc[64];
    int blk = blockIdx.x, b = blk >> 8, win = blk & 255;
    int t = threadIdx.x, lane = t & 63, wv = t >> 6;
    int g = lane >> 4, lm = lane & 15;

    // proj A-frags (per-wave m-tile)
    half8 pa0 = *(const half8*)(pwp + (size_t)(wv * 2 + 0) * 512 + lane * 8);
    half8 pa1 = *(const half8*)(pwp + (size_t)(wv * 2 + 1) * 512 + lane * 8);

    // ---- stage ----
    const _Float16* base = qkv + (size_t)b * QKVC * N + win * 64;
    {
        int c = t >> 2, q0 = (t & 3) * 16;
        const _Float16* pq = base + (size_t)c * N + q0;
        half8 a0 = *(const half8*)(pq);
        half8 a1 = *(const half8*)(pq + 8);
        *(half8*)&qT[c][q0] = a0;
        *(half8*)&qT[c][q0 + 8] = a1;
        const _Float16* pk = base + (size_t)(64 + c) * N + q0;
        half8 b0 = *(const half8*)(pk);
        half8 b1 = *(const half8*)(pk + 8);
        *(half8*)&kT[c][q0] = b0;
        *(half8*)&kT[c][q0 + 8] = b1;
        const _Float16* pv = base + (size_t)(128 + c) * N + q0;
        half8 v0 = *(const half8*)(pv);
        half8 v1 = *(const half8*)(pv + 8);
#pragma unroll
        for (int j = 0; j < 8; ++j) vP[q0 + j][c] = v0[j];
#pragma unroll
        for (int j = 0; j < 8; ++j) vP[q0 + 8 + j][c] = v1[j];
    }
    __syncthreads();
    // ---- norms ----
    if (t < 128) {
        int p = t & 63;
        float s = 0.f;
        if (t < 64) {
#pragma unroll
            for (int c = 0; c < 64; ++c) { float a = (float)qT[c][p]; s += a * a; }
        } else {
#pragma unroll
            for (int c = 0; c < 64; ++c) { float a = (float)kT[c][p]; s += a * a; }
        }
        tnorm[t] = s;
    }
    __syncthreads();
    if (t < 64) {
        float r = temp_p[0] / (fmaxf(sqrtf(tnorm[t]), 1e-12f) * fmaxf(sqrtf(tnorm[64 + t]), 1e-12f));
        wsc[t] = (_Float16)r;
    }
    __syncthreads();

    // ---- GEMM1: S[c][d] = sum_p q[c][p] * (wsc[p] k[d][p]); wave owns c-rows [wv*16,+16) ----
    {
        half8 aq0 = *(const half8*)&qT[wv * 16 + lm][g * 8];
        half8 aq1 = *(const half8*)&qT[wv * 16 + lm][32 + g * 8];
        half8 ws0 = *(const half8*)&wsc[g * 8];
        half8 ws1 = *(const half8*)&wsc[32 + g * 8];
#pragma unroll
        for (int nt = 0; nt < 4; ++nt) {
            int d = nt * 16 + lm;
            half8 bk0 = *(const half8*)&kT[d][g * 8] * ws0;
            half8 bk1 = *(const half8*)&kT[d][32 + g * 8] * ws1;
            f32x4 acc = {0.f, 0.f, 0.f, 0.f};
            acc = __builtin_amdgcn_mfma_f32_16x16x32_f16(aq0, bk0, acc, 0, 0, 0);
            acc = __builtin_amdgcn_mfma_f32_16x16x32_f16(aq1, bk1, acc, 0, 0, 0);
#pragma unroll
            for (int r = 0; r < 4; ++r)
                aT[wv * 16 + g * 4 + r][d] = (_Float16)fmaxf(acc[r], 0.f);
        }
    }
    __syncthreads();

    // ---- GEMM2: out^T[d][p] = sum_c attn[c][d] v[p][c]; wave owns d-rows [wv*16,+16) ----
    {
        half8 a20, a21;
#pragma unroll
        for (int i = 0; i < 8; ++i) {
            a20[i] = aT[g * 8 + i][wv * 16 + lm];
            a21[i] = aT[32 + g * 8 + i][wv * 16 + lm];
        }
#pragma unroll
        for (int nt = 0; nt < 4; ++nt) {
            int p = nt * 16 + lm;
            half4v x0 = *(const half4v*)&vP[p][g * 8];
            half4v x1 = *(const half4v*)&vP[p][g * 8 + 4];
            half4v x2 = *(const half4v*)&vP[p][32 + g * 8];
            half4v x3 = *(const half4v*)&vP[p][32 + g * 8 + 4];
            half8 b20, b21;
#pragma unroll
            for (int j = 0; j < 4; ++j) { b20[j] = x0[j]; b20[4 + j] = x1[j]; b21[j] = x2[j]; b21[4 + j] = x3[j]; }
            f32x4 acc = {0.f, 0.f, 0.f, 0.f};
            acc = __builtin_amdgcn_mfma_f32_16x16x32_f16(a20, b20, acc, 0, 0, 0);
            acc = __builtin_amdgcn_mfma_f32_16x16x32_f16(a21, b21, acc, 0, 0, 0);
#pragma unroll
            for (int r = 0; r < 4; ++r)
                oP[p][wv * 16 + g * 4 + r] = (_Float16)acc[r];
        }
    }
    __syncthreads();

    // ---- GEMM3: x_[oc][p] = sum_d pw[oc][d] out[p][d]; wave owns oc-rows [wv*16,+16) ----
    {
        int y0 = (win >> 4) * 8, x0w = (win & 15) * 8;
        float* ob = out + (size_t)b * C * N;
#pragma unroll
        for (int nt = 0; nt < 4; ++nt) {
            int p = nt * 16 + lm;
            half4v x0 = *(const half4v*)&oP[p][g * 8];
            half4v x1 = *(const half4v*)&oP[p][g * 8 + 4];
            half4v x2 = *(const half4v*)&oP[p][32 + g * 8];
            half4v x3 = *(const half4v*)&oP[p][32 + g * 8 + 4];
            half8 b30, b31;
#pragma unroll
            for (int j = 0; j < 4; ++j) { b30[j] = x0[j]; b30[4 + j] = x1[j]; b31[j] = x2[j]; b31[4 + j] = x3[j]; }
            f32x4 acc = {0.f, 0.f, 0.f, 0.f};
            acc = __builtin_amdgcn_mfma_f32_16x16x32_f16(pa0, b30, acc, 0, 0, 0);
            acc = __builtin_amdgcn_mfma_f32_16x16x32_f16(pa1, b31, acc, 0, 0, 0);
            int gy = (y0 + (p >> 3) + 4) & 127;
            int gx = (x0w + (p & 7) + 4) & 127;
#pragma unroll
            for (int r = 0; r < 4; ++r)
                ob[(size_t)(wv * 16 + g * 4 + r) * N + gy * W + gx] = acc[r];
        }
    }
}

// =========== FFN stage B: dwconv3x3 + gelu gate, fp16 -> fp16 ===========
__global__ __launch_bounds__(256, 1) void ffn_b_kernel(
    const _Float16* __restrict__ hid,   // (B,340,N)
    const float* __restrict__ dww,      // (340,9)
    _Float16* __restrict__ gated)       // (B,170,N)
{
    int bc = blockIdx.y;                 // b*170 + c
    int b = bc / 170, c = bc % 170;
    int n = blockIdx.x * 256 + threadIdx.x;
    int y = n >> 7, x = n & 127;
    const _Float16* pa = hid + ((size_t)b * 340 + c) * N;
    const _Float16* pb = hid + ((size_t)b * 340 + 170 + c) * N;
    const float* wa = dww + c * 9;
    const float* wb = dww + (170 + c) * 9;
    float a = 0.f, g2 = 0.f;
#pragma unroll
    for (int dy = -1; dy <= 1; ++dy) {
        int yy = y + dy;
        if (yy < 0 || yy > 127) continue;
#pragma unroll
        for (int dx = -1; dx <= 1; ++dx) {
            int xx = x + dx;
            if (xx < 0 || xx > 127) continue;
            int idx = yy * W + xx, wi = (dy + 1) * 3 + dx + 1;
            a  += wa[wi] * (float)pa[idx];
            g2 += wb[wi] * (float)pb[idx];
        }
    }
    gated[((size_t)b * 170 + c) * N + n] = (_Float16)(gelu_exact(a) * g2);
}

// =========== GSA phase A ===========
__global__ __launch_bounds__(256, 1) void gsa_part_kernel(
    const _Float16* __restrict__ qkv, float* __restrict__ part)
{
    int bh = blockIdx.y, chunk = blockIdx.x;
    int b = bh >> 3, h = bh & 7;
    int t = threadIdx.x;
    const _Float16* qb = qkv + ((size_t)b * QKVC + h * 8) * N;
    const _Float16* kb = qb + (size_t)64 * N;
    float acc[80];
#pragma unroll
    for (int j = 0; j < 80; ++j) acc[j] = 0.f;
    for (int i = 0; i < 2; ++i) {
        int n = chunk * 512 + i * 256 + t;
        float qv[8], kv[8];
#pragma unroll
        for (int c = 0; c < 8; ++c) { qv[c] = (float)qb[(size_t)c * N + n]; kv[c] = (float)kb[(size_t)c * N + n]; }
#pragma unroll
        for (int c = 0; c < 8; ++c) {
            acc[64 + c] += qv[c] * qv[c];
            acc[72 + c] += kv[c] * kv[c];
#pragma unroll
            for (int d = 0; d < 8; ++d) acc[c * 8 + d] += qv[c] * kv[d];
        }
    }
#pragma unroll
    for (int j = 0; j < 80; ++j) {
        float v = acc[j];
#pragma unroll
        for (int m = 1; m < 64; m <<= 1) v += __shfl_xor(v, m, 64);
        acc[j] = v;
    }
    __shared__ float red[4 * 80];
    if ((t & 63) == 0) {
#pragma unroll
        for (int j = 0; j < 80; ++j) red[(t >> 6) * 80 + j] = acc[j];
    }
    __syncthreads();
    if (t < 80) {
        float s = red[t] + red[80 + t] + red[160 + t] + red[240 + t];
        part[((size_t)bh * 32 + chunk) * 80 + t] = s;
    }
}

// =========== GSA phase B ===========
__global__ __launch_bounds__(128) void gsa_fin_kernel(
    const float* __restrict__ part, const float* __restrict__ temp_p,
    float* __restrict__ attn)
{
    int bh = blockIdx.x;
    int t = threadIdx.x;
    __shared__ float red[80];
    if (t < 80) {
        float s = 0.f;
        for (int ch = 0; ch < 32; ++ch) s += part[((size_t)bh * 32 + ch) * 80 + t];
        red[t] = s;
    }
    __syncthreads();
    if (t < 64) {
        int c = t >> 3, d = t & 7;
        float S  = red[c * 8 + d];
        float qn = fmaxf(sqrtf(red[64 + c]), 1e-12f);
        float kn = fmaxf(sqrtf(red[72 + d]), 1e-12f);
        attn[(size_t)bh * 64 + t] = fmaxf(temp_p[0] * S / (qn * kn), 0.f);
    }
}

// =========== GSA phase C: W_eff ===========
__global__ __launch_bounds__(64) void weff_kernel(
    const float* __restrict__ attn, const float* __restrict__ pw,
    float* __restrict__ weff)
{
    int b = blockIdx.x;
    int o = threadIdx.x;
    __shared__ float al[512];
    for (int idx = o; idx < 512; idx += 64) al[idx] = attn[(size_t)b * 512 + idx];
    __syncthreads();
    for (int hd = 0; hd < 64; ++hd) {
        int h = hd >> 3, d = hd & 7;
        float acc = 0.f;
#pragma unroll
        for (int c = 0; c < 8; ++c)
            acc += pw[o * 64 + c * 8 + h] * al[h * 64 + c * 8 + d];
        weff[((size_t)b * 64 + o) * 64 + hd] = acc;
    }
}

// =========== sentinel ===========
__global__ void sentinel_kernel(float* out, int n) {
    int i = blockIdx.x * 256 + threadIdx.x;
    if (i < n) out[i] = 12345.0f;
}

extern "C" void kernel_launch(void* const* d_in, const int* in_sizes, int n_in,
                              void* d_out, int out_size, void* d_ws, size_t ws_size,
                              hipStream_t stream)
{
    const float* x         = (const float*)d_in[0];
    const float* ln_s0_w   = (const float*)d_in[1];
    const float* ln_s0_b   = (const float*)d_in[2];
    const float* ln_s2_w   = (const float*)d_in[3];
    const float* ln_s2_b   = (const float*)d_in[4];
    const float* rsa_qkv_w = (const float*)d_in[5];
    const float* rsa_dw_w  = (const float*)d_in[6];
    const float* rsa_proj_w= (const float*)d_in[7];
    const float* rsa_temp  = (const float*)d_in[8];
    const float* ffs_in_w  = (const float*)d_in[9];
    const float* ffs_dw_w  = (const float*)d_in[10];
    const float* ffs_out_w = (const float*)d_in[11];
    const float* ln_c0_w   = (const float*)d_in[12];
    const float* ln_c0_b   = (const float*)d_in[13];
    const float* ln_c2_w   = (const float*)d_in[14];
    const float* ln_c2_b   = (const float*)d_in[15];
    const float* gsa_qkv_w = (const float*)d_in[16];
    const float* gsa_dw_w  = (const float*)d_in[17];
    const float* gsa_proj_w= (const float*)d_in[18];
    const float* gsa_temp  = (const float*)d_in[19];
    const float* ffc_in_w  = (const float*)d_in[20];
    const float* ffc_dw_w  = (const float*)d_in[21];
    const float* ffc_out_w = (const float*)d_in[22];
    float* outp = (float*)d_out;

    // ---- workspace layout (total 168,828,928 B) ----
    char* ws = (char*)d_ws;
    _Float16* tmp192 = (_Float16*)(ws + 0);            // (B,192,N) fp16 [0, 50,331,648)
    _Float16* Qbuf16 = (_Float16*)(ws + 50331648ull);  // (B,192,N) fp16 [50,331,648, 100,663,296)
    _Float16* hidA   = (_Float16*)(ws + 0);            // (B,340,N) fp16 overlay [0, 89,128,960)
    _Float16* L16    = (_Float16*)(ws + 89128960ull);  // (B,64,N) fp16
    _Float16* gated  = (_Float16*)(ws + 89128960ull);  // (B,170,N) fp16 overlay, ends 133,693,440
    _Float16* wp_rsap= (_Float16*)(ws + 133693440ull); // 8,192 B (gap before S2; disjoint from gated)
    float*    S2     = (float*)(ws + 134217728ull);    // (B,64,N) fp32
    float*    part   = (float*)(ws + 167772160ull);    // 655,360
    float*    attn_s = (float*)(ws + 168427520ull);    // 16,384
    float*    weffb  = (float*)(ws + 168443904ull);    // 131,072
    _Float16* wp_rsa = (_Float16*)(ws + 168574976ull); // 24,576
    _Float16* wp_gsa = (_Float16*)(ws + 168599552ull); // 24,576
    _Float16* wp_fsi = (_Float16*)(ws + 168624128ull); // 45,056
    _Float16* wp_fci = (_Float16*)(ws + 168669184ull); // 45,056
    _Float16* wp_fso = (_Float16*)(ws + 168714240ull); // 24,576
    _Float16* wp_fco = (_Float16*)(ws + 168738816ull); // 24,576
    _Float16* wp_pbw = (_Float16*)(ws + 168763392ull); // 65,536 -> ends 168,828,928
    if (ws_size < 168828928ull) {
        int n = out_size < 4096 ? out_size : 4096;
        sentinel_kernel<<<16, 256, 0, stream>>>(outp, n);
        return;
    }

    dim3 blk256(256);

    // ---- weight packs (tiny) ----
    wpack_kernel<<<24, 64, 0, stream>>>(rsa_qkv_w, 192, 64, 2, wp_rsa);
    wpack_kernel<<<24, 64, 0, stream>>>(gsa_qkv_w, 192, 64, 2, wp_gsa);
    wpack_kernel<<<44, 64, 0, stream>>>(ffs_in_w, 340, 64, 2, wp_fsi);
    wpack_kernel<<<44, 64, 0, stream>>>(ffc_in_w, 340, 64, 2, wp_fci);
    wpack_kernel<<<24, 64, 0, stream>>>(ffs_out_w, 64, 170, 6, wp_fso);
    wpack_kernel<<<24, 64, 0, stream>>>(ffc_out_w, 64, 170, 6, wp_fco);
    wpack_kernel<<<8, 64, 0, stream>>>(rsa_proj_w, 64, 64, 2, wp_rsap);

    // ---- spatial (RSA) half ----
    ln16_kernel<<<512, blk256, 0, stream>>>(x, nullptr, ln_s0_w, ln_s0_b, L16);
    gemm_kernel<6, 2, 2, 2, 64, 192, 64, false, false, false>
        <<<2048, blk256, 0, stream>>>(L16, wp_rsa, nullptr, tmp192);
    dw16_kernel<true><<<dim3(64, B * 192), blk256, 0, stream>>>(tmp192, rsa_dw_w, Qbuf16);  // -> window-major
    rsa_win_kernel<<<2048, blk256, 0, stream>>>(Qbuf16, rsa_temp, wp_rsap, S2);             // x_ spatial
    ln16_kernel<<<512, blk256, 0, stream>>>(S2, x, ln_s2_w, ln_s2_b, L16);                  // LN(x_+x)
    gemm_kernel<11, 2, 2, 2, 64, 340, 64, false, false, false>
        <<<2048, blk256, 0, stream>>>(L16, wp_fsi, nullptr, hidA);
    ffn_b_kernel<<<dim3(64, B * 170), blk256, 0, stream>>>(hidA, ffs_dw_w, gated);
    gemm_kernel<2, 6, 2, 2, 170, 64, 170, false, true, true>
        <<<2048, blk256, 0, stream>>>(gated, wp_fso, S2, outp);                             // x -> d_out

    // ---- channel (GSA) half ----
    ln16_kernel<<<512, blk256, 0, stream>>>(outp, nullptr, ln_c0_w, ln_c0_b, L16);
    gemm_kernel<6, 2, 2, 2, 64, 192, 64, false, false, false>
        <<<2048, blk256, 0, stream>>>(L16, wp_gsa, nullptr, tmp192);
    dw16_kernel<false><<<dim3(64, B * 192), blk256, 0, stream>>>(tmp192, gsa_dw_w, Qbuf16); // linear
    gsa_part_kernel<<<dim3(32, 64), blk256, 0, stream>>>(Qbuf16, part);
    gsa_fin_kernel<<<64, dim3(128), 0, stream>>>(part, gsa_temp, attn_s);
    weff_kernel<<<8, dim3(64), 0, stream>>>(attn_s, gsa_proj_w, weffb);
    weffpack_kernel<<<8, dim3(512), 0, stream>>>(weffb, wp_pbw);
    gemm_kernel<4, 2, 1, 1, 64, 64, 192, true, true, false>
        <<<2048, blk256, 0, stream>>>(Qbuf16 + (size_t)128 * N, wp_pbw, nullptr, S2);       // x_ channel
    ln16_kernel<<<512, blk256, 0, stream>>>(S2, outp, ln_c2_w, ln_c2_b, L16);               // LN(x_+x)
    gemm_kernel<11, 2, 2, 2, 64, 340, 64, false, false, false>
        <<<2048, blk256, 0, stream>>>(L16, wp_fci, nullptr, hidA);
    ffn_b_kernel<<<dim3(64, B * 170), blk256, 0, stream>>>(hidA, ffc_dw_w, gated);
    gemm_kernel<2, 6, 2, 2, 170, 64, 170, false, true, true>
        <<<2048, blk256, 0, stream>>>(gated, wp_fco, S2, outp);                             // final
}

// Round 7
// 492.488 us; speedup vs baseline: 5.0568x; 1.7073x over previous
//
#include <hip/hip_runtime.h>
#include <hip/hip_bf16.h>
#include <math.h>

#define DI __device__ __forceinline__

constexpr int B = 8, C = 64, H = 128, W = 128, N = H * W;   // N = 16384
constexpr int HID = 170;
constexpr int QKVC = 3 * C;                                 // 192

typedef _Float16 half8 __attribute__((ext_vector_type(8)));
typedef _Float16 half4v __attribute__((ext_vector_type(4)));
typedef float f32x4 __attribute__((ext_vector_type(4)));

DI float gelu_exact(float v) {
    return 0.5f * v * (1.0f + erff(v * 0.70710678118654752f));
}

// =========== LayerNorm over channels (+opt add), fp32 in -> fp16 out ===========
__global__ __launch_bounds__(256, 1) void ln16_kernel(
    const float* __restrict__ in, const float* __restrict__ add,
    const float* __restrict__ w, const float* __restrict__ bias,
    _Float16* __restrict__ out)
{
    int pid = blockIdx.x * 256 + threadIdx.x;
    int b = pid >> 14, n = pid & (N - 1);
    size_t base = (size_t)b * C * N + n;
    float vals[C];
    float s = 0.f;
#pragma unroll
    for (int c = 0; c < C; ++c) {
        float v = in[base + (size_t)c * N];
        if (add) v += add[base + (size_t)c * N];
        vals[c] = v; s += v;
    }
    float mean = s * (1.0f / C);
    float vs = 0.f;
#pragma unroll
    for (int c = 0; c < C; ++c) { float d = vals[c] - mean; vals[c] = d; vs += d * d; }
    float rstd = rsqrtf(vs * (1.0f / C) + 1e-5f);
#pragma unroll
    for (int c = 0; c < C; ++c)
        out[base + (size_t)c * N] = (_Float16)(vals[c] * rstd * w[c] + bias[c]);
}

// =========== weight pre-pack into MFMA A-fragment order, fp32 -> fp16 ===========
__global__ __launch_bounds__(64) void wpack_kernel(
    const float* __restrict__ Wm, int OREAL, int KREAL, int KT,
    _Float16* __restrict__ out)
{
    int f = blockIdx.x, l = threadIdx.x;
    int mt = f / KT, kt = f % KT;
    int row = mt * 16 + (l & 15);
    int col0 = kt * 32 + (l >> 4) * 8;
    half8 v;
#pragma unroll
    for (int i = 0; i < 8; ++i) {
        int col = col0 + i;
        v[i] = (row < OREAL && col < KREAL) ? (_Float16)Wm[row * KREAL + col] : (_Float16)0.f;
    }
    *(half8*)(out + (size_t)f * 512 + l * 8) = v;
}

// =========== per-batch weff pack (O=64, K=64 -> 8 frags/batch) ===========
__global__ __launch_bounds__(512) void weffpack_kernel(
    const float* __restrict__ weff, _Float16* __restrict__ out)
{
    int b = blockIdx.x;
    int f = threadIdx.x >> 6, l = threadIdx.x & 63;
    int mt = f >> 1, kt = f & 1;
    int row = mt * 16 + (l & 15);
    int col0 = kt * 32 + (l >> 4) * 8;
    const float* wb = weff + (size_t)b * 4096;
    half8 v;
#pragma unroll
    for (int i = 0; i < 8; ++i) v[i] = (_Float16)wb[row * 64 + col0 + i];
    *(half8*)(out + ((size_t)b * 8 + f) * 512 + l * 8) = v;
}

// =========== MFMA conv1x1 GEMM: out[b,o,n] = sum_c W[o,c] X[b,c,n] ===========
template<int MT, int KT, int MG, int NSTRIP, int CIN, int OREAL, int XROWS,
         bool PBW, bool OUT32, bool RESID>
__global__ __launch_bounds__(256, 1) void gemm_kernel(
    const _Float16* __restrict__ X, const _Float16* __restrict__ Wp,
    const float* __restrict__ resid, void* __restrict__ outv)
{
    constexpr int PG = 4 / MG;
    constexpr int PPB = PG * 16 * NSTRIP;
    int t = threadIdx.x;
    int lane = t & 63, wv = t >> 6;
    int mg = wv % MG, pg = wv / MG;
    int pbase = blockIdx.x * PPB;
    int b = pbase >> 14, nb = pbase & (N - 1);

    half8 a[MT][KT];
    const _Float16* wb = Wp + ((size_t)(PBW ? b * (MG * MT * KT) : 0) + mg * MT * KT) * 512 + lane * 8;
#pragma unroll
    for (int mt = 0; mt < MT; ++mt)
#pragma unroll
        for (int kt = 0; kt < KT; ++kt)
            a[mt][kt] = *(const half8*)(wb + (mt * KT + kt) * 512);

    const _Float16* xb = X + (size_t)b * XROWS * N;
    int krow0 = (lane >> 4) * 8;

    for (int s = 0; s < NSTRIP; ++s) {
        int col = nb + (s * PG + pg) * 16 + (lane & 15);
        const _Float16* xp = xb + col;
        half8 bf[KT];
#pragma unroll
        for (int kt = 0; kt < KT; ++kt)
#pragma unroll
            for (int i = 0; i < 8; ++i) {
                int c = kt * 32 + krow0 + i;
                if (KT * 32 <= CIN || c < CIN) bf[kt][i] = xp[(size_t)c * N];
                else bf[kt][i] = (_Float16)0.f;
            }
        f32x4 acc[MT];
#pragma unroll
        for (int mt = 0; mt < MT; ++mt) acc[mt] = (f32x4){0.f, 0.f, 0.f, 0.f};
#pragma unroll
        for (int kt = 0; kt < KT; ++kt)
#pragma unroll
            for (int mt = 0; mt < MT; ++mt)
                acc[mt] = __builtin_amdgcn_mfma_f32_16x16x32_f16(a[mt][kt], bf[kt], acc[mt], 0, 0, 0);

        int orow0 = mg * (MT * 16) + (lane >> 4) * 4;
#pragma unroll
        for (int mt = 0; mt < MT; ++mt)
#pragma unroll
            for (int r = 0; r < 4; ++r) {
                int orow = orow0 + mt * 16 + r;
                bool ok = (MG * MT * 16 == OREAL) || (orow < OREAL);
                if (ok) {
                    size_t oidx = ((size_t)b * OREAL + orow) * N + col;
                    if constexpr (OUT32) {
                        float vv = acc[mt][r];
                        if constexpr (RESID) vv += resid[((size_t)b * 64 + orow) * N + col];
                        ((float*)outv)[oidx] = vv;
                    } else {
                        ((_Float16*)outv)[oidx] = (_Float16)acc[mt][r];
                    }
                }
            }
    }
}

// =========== depthwise 3x3, vectorized 8 px/thread ===========
// ROLLWM: rolled gather (+4 mod 128) + window-major write (for RSA)
template<bool ROLLWM>
__global__ __launch_bounds__(256, 1) void dw16_kernel(
    const _Float16* __restrict__ in, const float* __restrict__ w,
    _Float16* __restrict__ out)
{
    int bc = blockIdx.y;                 // b*192 + c
    int c = bc % 192;
    int n0 = (blockIdx.x * 256 + threadIdx.x) * 8;
    int y = n0 >> 7, x0 = n0 & 127;
    const _Float16* ib = in + (size_t)bc * N;
    const float* wr = w + c * 9;         // uniform -> s_load

    float v[3][10];
#pragma unroll
    for (int r = 0; r < 3; ++r) {
        int yy = y - 1 + r;
        if (yy < 0 || yy > 127) {
#pragma unroll
            for (int j = 0; j < 10; ++j) v[r][j] = 0.f;
            continue;
        }
        if (!ROLLWM) {
            const _Float16* rp = ib + yy * W + x0;
            half8 m = *(const half8*)rp;
            v[r][0] = (x0 > 0) ? (float)rp[-1] : 0.f;
#pragma unroll
            for (int j = 0; j < 8; ++j) v[r][1 + j] = (float)m[j];
            v[r][9] = (x0 < 120) ? (float)rp[8] : 0.f;
        } else {
            int sy = (yy + 4) & 127;
            const _Float16* rp = ib + sy * W;
            if (x0 <= 112) {
                half8 b0 = *(const half8*)(rp + x0);
                half8 b1 = *(const half8*)(rp + x0 + 8);
#pragma unroll
                for (int j = 0; j < 10; ++j) {
                    int idx = 3 + j;                 // sx = x0 + 3 + j
                    float val = (idx < 8) ? (float)b0[idx] : (float)b1[idx - 8];
                    v[r][j] = val;
                }
                if (x0 == 0) v[r][0] = 0.f;          // xx = -1
            } else {                                 // x0 == 120, wrap path
#pragma unroll
                for (int j = 0; j < 10; ++j) {
                    int xx = 119 + j;
                    v[r][j] = (xx <= 127) ? (float)rp[(xx + 4) & 127] : 0.f;
                }
            }
        }
    }
    half8 o;
#pragma unroll
    for (int i = 0; i < 8; ++i) {
        float acc = 0.f;
#pragma unroll
        for (int r = 0; r < 3; ++r)
#pragma unroll
            for (int dx = 0; dx < 3; ++dx)
                acc += wr[r * 3 + dx] * v[r][i + dx];
        o[i] = (_Float16)acc;
    }
    if (ROLLWM) {
        int win = ((y >> 3) << 4) | (x0 >> 3);
        int p = (y & 7) << 3;                        // 8 px = one window row
        *(half8*)(out + (size_t)bc * N + win * 64 + p) = o;
    } else {
        *(half8*)(out + (size_t)bc * N + n0) = o;
    }
}

// =========== RSA window attention (MFMA) + fused proj; one block per window ===========
__global__ __launch_bounds__(256, 3) void rsa_win_kernel(
    const _Float16* __restrict__ qkv, const float* __restrict__ temp_p,
    const _Float16* __restrict__ pwp, float* __restrict__ out)
{
    __shared__ _Float16 qT[64][72];
    __shared__ _Float16 kT[64][72];
    __shared__ _Float16 vP[64][76];
    __shared__ _Float16 aT[64][76];
    __shared__ _Float16 oP[64][76];
    __shared__ float tnorm[128];
    __shared__ _Float16 wsc[64];
    int blk = blockIdx.x, b = blk >> 8, win = blk & 255;
    int t = threadIdx.x, lane = t & 63, wv = t >> 6;
    int g = lane >> 4, lm = lane & 15;

    half8 pa0 = *(const half8*)(pwp + (size_t)(wv * 2 + 0) * 512 + lane * 8);
    half8 pa1 = *(const half8*)(pwp + (size_t)(wv * 2 + 1) * 512 + lane * 8);

    const _Float16* base = qkv + (size_t)b * QKVC * N + win * 64;
    {
        int c = t >> 2, q0 = (t & 3) * 16;
        const _Float16* pq = base + (size_t)c * N + q0;
        half8 a0 = *(const half8*)(pq);
        half8 a1 = *(const half8*)(pq + 8);
        *(half8*)&qT[c][q0] = a0;
        *(half8*)&qT[c][q0 + 8] = a1;
        const _Float16* pk = base + (size_t)(64 + c) * N + q0;
        half8 b0 = *(const half8*)(pk);
        half8 b1 = *(const half8*)(pk + 8);
        *(half8*)&kT[c][q0] = b0;
        *(half8*)&kT[c][q0 + 8] = b1;
        const _Float16* pv = base + (size_t)(128 + c) * N + q0;
        half8 v0 = *(const half8*)(pv);
        half8 v1 = *(const half8*)(pv + 8);
#pragma unroll
        for (int j = 0; j < 8; ++j) vP[q0 + j][c] = v0[j];
#pragma unroll
        for (int j = 0; j < 8; ++j) vP[q0 + 8 + j][c] = v1[j];
    }
    __syncthreads();
    if (t < 128) {
        int p = t & 63;
        float s = 0.f;
        if (t < 64) {
#pragma unroll
            for (int c = 0; c < 64; ++c) { float a = (float)qT[c][p]; s += a * a; }
        } else {
#pragma unroll
            for (int c = 0; c < 64; ++c) { float a = (float)kT[c][p]; s += a * a; }
        }
        tnorm[t] = s;
    }
    __syncthreads();
    if (t < 64) {
        float r = temp_p[0] / (fmaxf(sqrtf(tnorm[t]), 1e-12f) * fmaxf(sqrtf(tnorm[64 + t]), 1e-12f));
        wsc[t] = (_Float16)r;
    }
    __syncthreads();

    {
        half8 aq0 = *(const half8*)&qT[wv * 16 + lm][g * 8];
        half8 aq1 = *(const half8*)&qT[wv * 16 + lm][32 + g * 8];
        half8 ws0 = *(const half8*)&wsc[g * 8];
        half8 ws1 = *(const half8*)&wsc[32 + g * 8];
#pragma unroll
        for (int nt = 0; nt < 4; ++nt) {
            int d = nt * 16 + lm;
            half8 bk0 = *(const half8*)&kT[d][g * 8] * ws0;
            half8 bk1 = *(const half8*)&kT[d][32 + g * 8] * ws1;
            f32x4 acc = {0.f, 0.f, 0.f, 0.f};
            acc = __builtin_amdgcn_mfma_f32_16x16x32_f16(aq0, bk0, acc, 0, 0, 0);
            acc = __builtin_amdgcn_mfma_f32_16x16x32_f16(aq1, bk1, acc, 0, 0, 0);
#pragma unroll
            for (int r = 0; r < 4; ++r)
                aT[wv * 16 + g * 4 + r][d] = (_Float16)fmaxf(acc[r], 0.f);
        }
    }
    __syncthreads();

    {
        half8 a20, a21;
#pragma unroll
        for (int i = 0; i < 8; ++i) {
            a20[i] = aT[g * 8 + i][wv * 16 + lm];
            a21[i] = aT[32 + g * 8 + i][wv * 16 + lm];
        }
#pragma unroll
        for (int nt = 0; nt < 4; ++nt) {
            int p = nt * 16 + lm;
            half4v x0 = *(const half4v*)&vP[p][g * 8];
            half4v x1 = *(const half4v*)&vP[p][g * 8 + 4];
            half4v x2 = *(const half4v*)&vP[p][32 + g * 8];
            half4v x3 = *(const half4v*)&vP[p][32 + g * 8 + 4];
            half8 b20, b21;
#pragma unroll
            for (int j = 0; j < 4; ++j) { b20[j] = x0[j]; b20[4 + j] = x1[j]; b21[j] = x2[j]; b21[4 + j] = x3[j]; }
            f32x4 acc = {0.f, 0.f, 0.f, 0.f};
            acc = __builtin_amdgcn_mfma_f32_16x16x32_f16(a20, b20, acc, 0, 0, 0);
            acc = __builtin_amdgcn_mfma_f32_16x16x32_f16(a21, b21, acc, 0, 0, 0);
#pragma unroll
            for (int r = 0; r < 4; ++r)
                oP[p][wv * 16 + g * 4 + r] = (_Float16)acc[r];
        }
    }
    __syncthreads();

    {
        int y0 = (win >> 4) * 8, x0w = (win & 15) * 8;
        float* ob = out + (size_t)b * C * N;
#pragma unroll
        for (int nt = 0; nt < 4; ++nt) {
            int p = nt * 16 + lm;
            half4v x0 = *(const half4v*)&oP[p][g * 8];
            half4v x1 = *(const half4v*)&oP[p][g * 8 + 4];
            half4v x2 = *(const half4v*)&oP[p][32 + g * 8];
            half4v x3 = *(const half4v*)&oP[p][32 + g * 8 + 4];
            half8 b30, b31;
#pragma unroll
            for (int j = 0; j < 4; ++j) { b30[j] = x0[j]; b30[4 + j] = x1[j]; b31[j] = x2[j]; b31[4 + j] = x3[j]; }
            f32x4 acc = {0.f, 0.f, 0.f, 0.f};
            acc = __builtin_amdgcn_mfma_f32_16x16x32_f16(pa0, b30, acc, 0, 0, 0);
            acc = __builtin_amdgcn_mfma_f32_16x16x32_f16(pa1, b31, acc, 0, 0, 0);
            int gy = (y0 + (p >> 3) + 4) & 127;
            int gx = (x0w + (p & 7) + 4) & 127;
#pragma unroll
            for (int r = 0; r < 4; ++r)
                ob[(size_t)(wv * 16 + g * 4 + r) * N + gy * W + gx] = acc[r];
        }
    }
}

// =========== FFN stage B: dwconv3x3 + gelu gate, vectorized 8 px/thread ===========
__global__ __launch_bounds__(256, 1) void ffn_b_kernel(
    const _Float16* __restrict__ hid,   // (B,340,N)
    const float* __restrict__ dww,      // (340,9)
    _Float16* __restrict__ gated)       // (B,170,N)
{
    int bc = blockIdx.y;                 // b*170 + c
    int b = bc / 170, c = bc % 170;
    int n0 = (blockIdx.x * 256 + threadIdx.x) * 8;
    int y = n0 >> 7, x0 = n0 & 127;
    const _Float16* pa = hid + ((size_t)b * 340 + c) * N;
    const _Float16* pb = pa + (size_t)170 * N;
    const float* wa = dww + c * 9;          // uniform -> s_load
    const float* wb = wa + 170 * 9;

    float va[3][10], vb[3][10];
#pragma unroll
    for (int r = 0; r < 3; ++r) {
        int yy = y - 1 + r;
        if (yy < 0 || yy > 127) {
#pragma unroll
            for (int j = 0; j < 10; ++j) { va[r][j] = 0.f; vb[r][j] = 0.f; }
            continue;
        }
        const _Float16* ra = pa + yy * W + x0;
        const _Float16* rb = pb + yy * W + x0;
        half8 ma = *(const half8*)ra;
        half8 mb = *(const half8*)rb;
        va[r][0] = (x0 > 0) ? (float)ra[-1] : 0.f;
        vb[r][0] = (x0 > 0) ? (float)rb[-1] : 0.f;
#pragma unroll
        for (int j = 0; j < 8; ++j) { va[r][1 + j] = (float)ma[j]; vb[r][1 + j] = (float)mb[j]; }
        va[r][9] = (x0 < 120) ? (float)ra[8] : 0.f;
        vb[r][9] = (x0 < 120) ? (float)rb[8] : 0.f;
    }
    half8 o;
#pragma unroll
    for (int i = 0; i < 8; ++i) {
        float a = 0.f, g2 = 0.f;
#pragma unroll
        for (int r = 0; r < 3; ++r)
#pragma unroll
            for (int dx = 0; dx < 3; ++dx) {
                a  += wa[r * 3 + dx] * va[r][i + dx];
                g2 += wb[r * 3 + dx] * vb[r][i + dx];
            }
        o[i] = (_Float16)(gelu_exact(a) * g2);
    }
    *(half8*)(gated + ((size_t)b * 170 + c) * N + n0) = o;
}

// =========== GSA phase A ===========
__global__ __launch_bounds__(256, 1) void gsa_part_kernel(
    const _Float16* __restrict__ qkv, float* __restrict__ part)
{
    int bh = blockIdx.y, chunk = blockIdx.x;
    int b = bh >> 3, h = bh & 7;
    int t = threadIdx.x;
    const _Float16* qb = qkv + ((size_t)b * QKVC + h * 8) * N;
    const _Float16* kb = qb + (size_t)64 * N;
    float acc[80];
#pragma unroll
    for (int j = 0; j < 80; ++j) acc[j] = 0.f;
    for (int i = 0; i < 2; ++i) {
        int n = chunk * 512 + i * 256 + t;
        float qv[8], kv[8];
#pragma unroll
        for (int c = 0; c < 8; ++c) { qv[c] = (float)qb[(size_t)c * N + n]; kv[c] = (float)kb[(size_t)c * N + n]; }
#pragma unroll
        for (int c = 0; c < 8; ++c) {
            acc[64 + c] += qv[c] * qv[c];
            acc[72 + c] += kv[c] * kv[c];
#pragma unroll
            for (int d = 0; d < 8; ++d) acc[c * 8 + d] += qv[c] * kv[d];
        }
    }
#pragma unroll
    for (int j = 0; j < 80; ++j) {
        float v = acc[j];
#pragma unroll
        for (int m = 1; m < 64; m <<= 1) v += __shfl_xor(v, m, 64);
        acc[j] = v;
    }
    __shared__ float red[4 * 80];
    if ((t & 63) == 0) {
#pragma unroll
        for (int j = 0; j < 80; ++j) red[(t >> 6) * 80 + j] = acc[j];
    }
    __syncthreads();
    if (t < 80) {
        float s = red[t] + red[80 + t] + red[160 + t] + red[240 + t];
        part[((size_t)bh * 32 + chunk) * 80 + t] = s;
    }
}

// =========== GSA phase B ===========
__global__ __launch_bounds__(128) void gsa_fin_kernel(
    const float* __restrict__ part, const float* __restrict__ temp_p,
    float* __restrict__ attn)
{
    int bh = blockIdx.x;
    int t = threadIdx.x;
    __shared__ float red[80];
    if (t < 80) {
        float s = 0.f;
        for (int ch = 0; ch < 32; ++ch) s += part[((size_t)bh * 32 + ch) * 80 + t];
        red[t] = s;
    }
    __syncthreads();
    if (t < 64) {
        int c = t >> 3, d = t & 7;
        float S  = red[c * 8 + d];
        float qn = fmaxf(sqrtf(red[64 + c]), 1e-12f);
        float kn = fmaxf(sqrtf(red[72 + d]), 1e-12f);
        attn[(size_t)bh * 64 + t] = fmaxf(temp_p[0] * S / (qn * kn), 0.f);
    }
}

// =========== GSA phase C: W_eff ===========
__global__ __launch_bounds__(64) void weff_kernel(
    const float* __restrict__ attn, const float* __restrict__ pw,
    float* __restrict__ weff)
{
    int b = blockIdx.x;
    int o = threadIdx.x;
    __shared__ float al[512];
    for (int idx = o; idx < 512; idx += 64) al[idx] = attn[(size_t)b * 512 + idx];
    __syncthreads();
    for (int hd = 0; hd < 64; ++hd) {
        int h = hd >> 3, d = hd & 7;
        float acc = 0.f;
#pragma unroll
        for (int c = 0; c < 8; ++c)
            acc += pw[o * 64 + c * 8 + h] * al[h * 64 + c * 8 + d];
        weff[((size_t)b * 64 + o) * 64 + hd] = acc;
    }
}

// =========== sentinel ===========
__global__ void sentinel_kernel(float* out, int n) {
    int i = blockIdx.x * 256 + threadIdx.x;
    if (i < n) out[i] = 12345.0f;
}

extern "C" void kernel_launch(void* const* d_in, const int* in_sizes, int n_in,
                              void* d_out, int out_size, void* d_ws, size_t ws_size,
                              hipStream_t stream)
{
    const float* x         = (const float*)d_in[0];
    const float* ln_s0_w   = (const float*)d_in[1];
    const float* ln_s0_b   = (const float*)d_in[2];
    const float* ln_s2_w   = (const float*)d_in[3];
    const float* ln_s2_b   = (const float*)d_in[4];
    const float* rsa_qkv_w = (const float*)d_in[5];
    const float* rsa_dw_w  = (const float*)d_in[6];
    const float* rsa_proj_w= (const float*)d_in[7];
    const float* rsa_temp  = (const float*)d_in[8];
    const float* ffs_in_w  = (const float*)d_in[9];
    const float* ffs_dw_w  = (const float*)d_in[10];
    const float* ffs_out_w = (const float*)d_in[11];
    const float* ln_c0_w   = (const float*)d_in[12];
    const float* ln_c0_b   = (const float*)d_in[13];
    const float* ln_c2_w   = (const float*)d_in[14];
    const float* ln_c2_b   = (const float*)d_in[15];
    const float* gsa_qkv_w = (const float*)d_in[16];
    const float* gsa_dw_w  = (const float*)d_in[17];
    const float* gsa_proj_w= (const float*)d_in[18];
    const float* gsa_temp  = (const float*)d_in[19];
    const float* ffc_in_w  = (const float*)d_in[20];
    const float* ffc_dw_w  = (const float*)d_in[21];
    const float* ffc_out_w = (const float*)d_in[22];
    float* outp = (float*)d_out;

    // ---- workspace layout (total 168,828,928 B) ----
    char* ws = (char*)d_ws;
    _Float16* tmp192 = (_Float16*)(ws + 0);            // (B,192,N) fp16 [0, 50,331,648)
    _Float16* Qbuf16 = (_Float16*)(ws + 50331648ull);  // (B,192,N) fp16 [50,331,648, 100,663,296)
    _Float16* hidA   = (_Float16*)(ws + 0);            // (B,340,N) fp16 overlay [0, 89,128,960)
    _Float16* L16    = (_Float16*)(ws + 89128960ull);  // (B,64,N) fp16
    _Float16* gated  = (_Float16*)(ws + 89128960ull);  // (B,170,N) fp16 overlay, ends 133,693,440
    _Float16* wp_rsap= (_Float16*)(ws + 133693440ull); // 8,192 B
    float*    S2     = (float*)(ws + 134217728ull);    // (B,64,N) fp32
    float*    part   = (float*)(ws + 167772160ull);    // 655,360
    float*    attn_s = (float*)(ws + 168427520ull);    // 16,384
    float*    weffb  = (float*)(ws + 168443904ull);    // 131,072
    _Float16* wp_rsa = (_Float16*)(ws + 168574976ull); // 24,576
    _Float16* wp_gsa = (_Float16*)(ws + 168599552ull); // 24,576
    _Float16* wp_fsi = (_Float16*)(ws + 168624128ull); // 45,056
    _Float16* wp_fci = (_Float16*)(ws + 168669184ull); // 45,056
    _Float16* wp_fso = (_Float16*)(ws + 168714240ull); // 24,576
    _Float16* wp_fco = (_Float16*)(ws + 168738816ull); // 24,576
    _Float16* wp_pbw = (_Float16*)(ws + 168763392ull); // 65,536 -> ends 168,828,928
    if (ws_size < 168828928ull) {
        int n = out_size < 4096 ? out_size : 4096;
        sentinel_kernel<<<16, 256, 0, stream>>>(outp, n);
        return;
    }

    dim3 blk256(256);

    wpack_kernel<<<24, 64, 0, stream>>>(rsa_qkv_w, 192, 64, 2, wp_rsa);
    wpack_kernel<<<24, 64, 0, stream>>>(gsa_qkv_w, 192, 64, 2, wp_gsa);
    wpack_kernel<<<44, 64, 0, stream>>>(ffs_in_w, 340, 64, 2, wp_fsi);
    wpack_kernel<<<44, 64, 0, stream>>>(ffc_in_w, 340, 64, 2, wp_fci);
    wpack_kernel<<<24, 64, 0, stream>>>(ffs_out_w, 64, 170, 6, wp_fso);
    wpack_kernel<<<24, 64, 0, stream>>>(ffc_out_w, 64, 170, 6, wp_fco);
    wpack_kernel<<<8, 64, 0, stream>>>(rsa_proj_w, 64, 64, 2, wp_rsap);

    // ---- spatial (RSA) half ----
    ln16_kernel<<<512, blk256, 0, stream>>>(x, nullptr, ln_s0_w, ln_s0_b, L16);
    gemm_kernel<6, 2, 2, 2, 64, 192, 64, false, false, false>
        <<<2048, blk256, 0, stream>>>(L16, wp_rsa, nullptr, tmp192);
    dw16_kernel<true><<<dim3(8, B * 192), blk256, 0, stream>>>(tmp192, rsa_dw_w, Qbuf16);   // -> window-major
    rsa_win_kernel<<<2048, blk256, 0, stream>>>(Qbuf16, rsa_temp, wp_rsap, S2);             // x_ spatial
    ln16_kernel<<<512, blk256, 0, stream>>>(S2, x, ln_s2_w, ln_s2_b, L16);                  // LN(x_+x)
    gemm_kernel<11, 2, 2, 2, 64, 340, 64, false, false, false>
        <<<2048, blk256, 0, stream>>>(L16, wp_fsi, nullptr, hidA);
    ffn_b_kernel<<<dim3(8, B * 170), blk256, 0, stream>>>(hidA, ffs_dw_w, gated);
    gemm_kernel<2, 6, 2, 2, 170, 64, 170, false, true, true>
        <<<2048, blk256, 0, stream>>>(gated, wp_fso, S2, outp);                             // x -> d_out

    // ---- channel (GSA) half ----
    ln16_kernel<<<512, blk256, 0, stream>>>(outp, nullptr, ln_c0_w, ln_c0_b, L16);
    gemm_kernel<6, 2, 2, 2, 64, 192, 64, false, false, false>
        <<<2048, blk256, 0, stream>>>(L16, wp_gsa, nullptr, tmp192);
    dw16_kernel<false><<<dim3(8, B * 192), blk256, 0, stream>>>(tmp192, gsa_dw_w, Qbuf16);  // linear
    gsa_part_kernel<<<dim3(32, 64), blk256, 0, stream>>>(Qbuf16, part);
    gsa_fin_kernel<<<64, dim3(128), 0, stream>>>(part, gsa_temp, attn_s);
    weff_kernel<<<8, dim3(64), 0, stream>>>(attn_s, gsa_proj_w, weffb);
    weffpack_kernel<<<8, dim3(512), 0, stream>>>(weffb, wp_pbw);
    gemm_kernel<4, 2, 1, 1, 64, 64, 192, true, true, false>
        <<<2048, blk256, 0, stream>>>(Qbuf16 + (size_t)128 * N, wp_pbw, nullptr, S2);       // x_ channel
    ln16_kernel<<<512, blk256, 0, stream>>>(S2, outp, ln_c2_w, ln_c2_b, L16);               // LN(x_+x)
    gemm_kernel<11, 2, 2, 2, 64, 340, 64, false, false, false>
        <<<2048, blk256, 0, stream>>>(L16, wp_fci, nullptr, hidA);
    ffn_b_kernel<<<dim3(8, B * 170), blk256, 0, stream>>>(hidA, ffc_dw_w, gated);
    gemm_kernel<2, 6, 2, 2, 170, 64, 170, false, true, true>
        <<<2048, blk256, 0, stream>>>(gated, wp_fco, S2, outp);                             // final
}

// Round 8
// 451.507 us; speedup vs baseline: 5.5157x; 1.0908x over previous
//
#include <hip/hip_runtime.h>
#include <hip/hip_bf16.h>
#include <math.h>

#define DI __device__ __forceinline__

constexpr int B = 8, C = 64, H = 128, W = 128, N = H * W;   // N = 16384
constexpr int HID = 170;
constexpr int QKVC = 3 * C;                                 // 192

typedef _Float16 half8 __attribute__((ext_vector_type(8)));
typedef _Float16 half4v __attribute__((ext_vector_type(4)));
typedef float f32x4 __attribute__((ext_vector_type(4)));

// gelu exact ~= v * sigmoid(1.5957691*(v + 0.044715 v^3)); max abs err ~3e-4
DI float gelu_fast(float v) {
    return v / (1.0f + __expf(-1.5957691216057308f * (v + 0.044715f * v * v * v)));
}

// =========== weight pre-pack into MFMA A-fragment order, fp32 -> fp16 ===========
__global__ __launch_bounds__(64) void wpack_kernel(
    const float* __restrict__ Wm, int OREAL, int KREAL, int KT,
    _Float16* __restrict__ out)
{
    int f = blockIdx.x, l = threadIdx.x;
    int mt = f / KT, kt = f % KT;
    int row = mt * 16 + (l & 15);
    int col0 = kt * 32 + (l >> 4) * 8;
    half8 v;
#pragma unroll
    for (int i = 0; i < 8; ++i) {
        int col = col0 + i;
        v[i] = (row < OREAL && col < KREAL) ? (_Float16)Wm[row * KREAL + col] : (_Float16)0.f;
    }
    *(half8*)(out + (size_t)f * 512 + l * 8) = v;
}

// =========== per-batch weff pack (O=64, K=64 -> 8 frags/batch) ===========
__global__ __launch_bounds__(512) void weffpack_kernel(
    const float* __restrict__ weff, _Float16* __restrict__ out)
{
    int b = blockIdx.x;
    int f = threadIdx.x >> 6, l = threadIdx.x & 63;
    int mt = f >> 1, kt = f & 1;
    int row = mt * 16 + (l & 15);
    int col0 = kt * 32 + (l >> 4) * 8;
    const float* wb = weff + (size_t)b * 4096;
    half8 v;
#pragma unroll
    for (int i = 0; i < 8; ++i) v[i] = (_Float16)wb[row * 64 + col0 + i];
    *(half8*)(out + ((size_t)b * 8 + f) * 512 + l * 8) = v;
}

// =========== fused LayerNorm + MFMA GEMM (CIN=64): out[b,o,n] = W @ LN(X (+Xadd)) ===========
// Per-pixel LN stats via 4-lane shfl reduction (channels of a pixel live in lanes lm, lm+16, lm+32, lm+48)
template<int MT, int OREAL, bool ADDIN>
__global__ __launch_bounds__(256, 1) void lngemm_kernel(
    const float* __restrict__ X, const float* __restrict__ Xadd,
    const float* __restrict__ lnw, const float* __restrict__ lnb,
    const _Float16* __restrict__ Wp, _Float16* __restrict__ outp)
{
    constexpr int MG = 2, NSTRIP = 2, PG = 2, PPB = 64;
    int t = threadIdx.x, lane = t & 63, wv = t >> 6;
    int mg = wv % MG, pg = wv / MG;
    int pbase = blockIdx.x * PPB;
    int b = pbase >> 14, nb = pbase & (N - 1);

    half8 a[MT][2];
    const _Float16* wb = Wp + (size_t)(mg * MT * 2) * 512 + lane * 8;
#pragma unroll
    for (int mt = 0; mt < MT; ++mt)
#pragma unroll
        for (int kt = 0; kt < 2; ++kt)
            a[mt][kt] = *(const half8*)(wb + (mt * 2 + kt) * 512);

    int krow0 = (lane >> 4) * 8;
    float wreg[2][8], breg[2][8];
#pragma unroll
    for (int kt = 0; kt < 2; ++kt)
#pragma unroll
        for (int i = 0; i < 8; ++i) {
            int c = kt * 32 + krow0 + i;
            wreg[kt][i] = lnw[c];
            breg[kt][i] = lnb[c];
        }

    const float* xb = X + (size_t)b * 64 * N;
    const float* ab = ADDIN ? (Xadd + (size_t)b * 64 * N) : nullptr;

    for (int s = 0; s < NSTRIP; ++s) {
        int col = nb + (s * PG + pg) * 16 + (lane & 15);
        float vv[2][8];
        float sm = 0.f, ss = 0.f;
#pragma unroll
        for (int kt = 0; kt < 2; ++kt)
#pragma unroll
            for (int i = 0; i < 8; ++i) {
                int c = kt * 32 + krow0 + i;
                float v = xb[(size_t)c * N + col];
                if (ADDIN) v += ab[(size_t)c * N + col];
                vv[kt][i] = v; sm += v; ss += v * v;
            }
        sm += __shfl_xor(sm, 16); ss += __shfl_xor(ss, 16);
        sm += __shfl_xor(sm, 32); ss += __shfl_xor(ss, 32);
        float mu = sm * (1.0f / 64.0f);
        float var = ss * (1.0f / 64.0f) - mu * mu;
        float rstd = rsqrtf(var + 1e-5f);
        half8 bf[2];
#pragma unroll
        for (int kt = 0; kt < 2; ++kt)
#pragma unroll
            for (int i = 0; i < 8; ++i)
                bf[kt][i] = (_Float16)((vv[kt][i] - mu) * rstd * wreg[kt][i] + breg[kt][i]);

        f32x4 acc[MT];
#pragma unroll
        for (int mt = 0; mt < MT; ++mt) acc[mt] = (f32x4){0.f, 0.f, 0.f, 0.f};
#pragma unroll
        for (int kt = 0; kt < 2; ++kt)
#pragma unroll
            for (int mt = 0; mt < MT; ++mt)
                acc[mt] = __builtin_amdgcn_mfma_f32_16x16x32_f16(a[mt][kt], bf[kt], acc[mt], 0, 0, 0);

        int orow0 = mg * (MT * 16) + (lane >> 4) * 4;
#pragma unroll
        for (int mt = 0; mt < MT; ++mt)
#pragma unroll
            for (int r = 0; r < 4; ++r) {
                int orow = orow0 + mt * 16 + r;
                bool ok = (MG * MT * 16 == OREAL) || (orow < OREAL);
                if (ok)
                    outp[((size_t)b * OREAL + orow) * N + col] = (_Float16)acc[mt][r];
            }
    }
}

// =========== MFMA conv1x1 GEMM (fp16 input): out[b,o,n] = sum_c W[o,c] X[b,c,n] ===========
template<int MT, int KT, int MG, int NSTRIP, int CIN, int OREAL, int XROWS,
         bool PBW, bool OUT32, bool RESID>
__global__ __launch_bounds__(256, 1) void gemm_kernel(
    const _Float16* __restrict__ X, const _Float16* __restrict__ Wp,
    const float* __restrict__ resid, void* __restrict__ outv)
{
    constexpr int PG = 4 / MG;
    constexpr int PPB = PG * 16 * NSTRIP;
    int t = threadIdx.x;
    int lane = t & 63, wv = t >> 6;
    int mg = wv % MG, pg = wv / MG;
    int pbase = blockIdx.x * PPB;
    int b = pbase >> 14, nb = pbase & (N - 1);

    half8 a[MT][KT];
    const _Float16* wb = Wp + ((size_t)(PBW ? b * (MG * MT * KT) : 0) + mg * MT * KT) * 512 + lane * 8;
#pragma unroll
    for (int mt = 0; mt < MT; ++mt)
#pragma unroll
        for (int kt = 0; kt < KT; ++kt)
            a[mt][kt] = *(const half8*)(wb + (mt * KT + kt) * 512);

    const _Float16* xb = X + (size_t)b * XROWS * N;
    int krow0 = (lane >> 4) * 8;

    for (int s = 0; s < NSTRIP; ++s) {
        int col = nb + (s * PG + pg) * 16 + (lane & 15);
        const _Float16* xp = xb + col;
        half8 bf[KT];
#pragma unroll
        for (int kt = 0; kt < KT; ++kt)
#pragma unroll
            for (int i = 0; i < 8; ++i) {
                int c = kt * 32 + krow0 + i;
                if (KT * 32 <= CIN || c < CIN) bf[kt][i] = xp[(size_t)c * N];
                else bf[kt][i] = (_Float16)0.f;
            }
        f32x4 acc[MT];
#pragma unroll
        for (int mt = 0; mt < MT; ++mt) acc[mt] = (f32x4){0.f, 0.f, 0.f, 0.f};
#pragma unroll
        for (int kt = 0; kt < KT; ++kt)
#pragma unroll
            for (int mt = 0; mt < MT; ++mt)
                acc[mt] = __builtin_amdgcn_mfma_f32_16x16x32_f16(a[mt][kt], bf[kt], acc[mt], 0, 0, 0);

        int orow0 = mg * (MT * 16) + (lane >> 4) * 4;
#pragma unroll
        for (int mt = 0; mt < MT; ++mt)
#pragma unroll
            for (int r = 0; r < 4; ++r) {
                int orow = orow0 + mt * 16 + r;
                bool ok = (MG * MT * 16 == OREAL) || (orow < OREAL);
                if (ok) {
                    size_t oidx = ((size_t)b * OREAL + orow) * N + col;
                    if constexpr (OUT32) {
                        float vv = acc[mt][r];
                        if constexpr (RESID) vv += resid[((size_t)b * 64 + orow) * N + col];
                        ((float*)outv)[oidx] = vv;
                    } else {
                        ((_Float16*)outv)[oidx] = (_Float16)acc[mt][r];
                    }
                }
            }
    }
}

// =========== depthwise 3x3, vectorized 8 px/thread ===========
// ROLLWM: rolled gather (+4 mod 128) + window-major write (for RSA)
template<bool ROLLWM>
__global__ __launch_bounds__(256, 1) void dw16_kernel(
    const _Float16* __restrict__ in, const float* __restrict__ w,
    _Float16* __restrict__ out)
{
    int bc = blockIdx.y;                 // b*192 + c
    int c = bc % 192;
    int n0 = (blockIdx.x * 256 + threadIdx.x) * 8;
    int y = n0 >> 7, x0 = n0 & 127;
    const _Float16* ib = in + (size_t)bc * N;
    const float* wr = w + c * 9;         // uniform -> s_load

    float v[3][10];
#pragma unroll
    for (int r = 0; r < 3; ++r) {
        int yy = y - 1 + r;
        if (yy < 0 || yy > 127) {
#pragma unroll
            for (int j = 0; j < 10; ++j) v[r][j] = 0.f;
            continue;
        }
        if (!ROLLWM) {
            const _Float16* rp = ib + yy * W + x0;
            half8 m = *(const half8*)rp;
            v[r][0] = (x0 > 0) ? (float)rp[-1] : 0.f;
#pragma unroll
            for (int j = 0; j < 8; ++j) v[r][1 + j] = (float)m[j];
            v[r][9] = (x0 < 120) ? (float)rp[8] : 0.f;
        } else {
            int sy = (yy + 4) & 127;
            const _Float16* rp = ib + sy * W;
            if (x0 <= 112) {
                half8 b0 = *(const half8*)(rp + x0);
                half8 b1 = *(const half8*)(rp + x0 + 8);
#pragma unroll
                for (int j = 0; j < 10; ++j) {
                    int idx = 3 + j;                 // sx = x0 + 3 + j
                    float val = (idx < 8) ? (float)b0[idx] : (float)b1[idx - 8];
                    v[r][j] = val;
                }
                if (x0 == 0) v[r][0] = 0.f;          // xx = -1
            } else {                                 // x0 == 120, wrap path
#pragma unroll
                for (int j = 0; j < 10; ++j) {
                    int xx = 119 + j;
                    v[r][j] = (xx <= 127) ? (float)rp[(xx + 4) & 127] : 0.f;
                }
            }
        }
    }
    half8 o;
#pragma unroll
    for (int i = 0; i < 8; ++i) {
        float acc = 0.f;
#pragma unroll
        for (int r = 0; r < 3; ++r)
#pragma unroll
            for (int dx = 0; dx < 3; ++dx)
                acc += wr[r * 3 + dx] * v[r][i + dx];
        o[i] = (_Float16)acc;
    }
    if (ROLLWM) {
        int win = ((y >> 3) << 4) | (x0 >> 3);
        int p = (y & 7) << 3;                        // 8 px = one window row
        *(half8*)(out + (size_t)bc * N + win * 64 + p) = o;
    } else {
        *(half8*)(out + (size_t)bc * N + n0) = o;
    }
}

// =========== RSA window attention (MFMA) + fused proj; one block per window ===========
__global__ __launch_bounds__(256, 3) void rsa_win_kernel(
    const _Float16* __restrict__ qkv, const float* __restrict__ temp_p,
    const _Float16* __restrict__ pwp, float* __restrict__ out)
{
    __shared__ _Float16 qT[64][72];
    __shared__ _Float16 kT[64][72];
    __shared__ _Float16 vP[64][76];
    __shared__ _Float16 aT[64][76];
    __shared__ _Float16 oP[64][76];
    __shared__ float tnorm[128];
    __shared__ _Float16 wsc[64];
    int blk = blockIdx.x, b = blk >> 8, win = blk & 255;
    int t = threadIdx.x, lane = t & 63, wv = t >> 6;
    int g = lane >> 4, lm = lane & 15;

    half8 pa0 = *(const half8*)(pwp + (size_t)(wv * 2 + 0) * 512 + lane * 8);
    half8 pa1 = *(const half8*)(pwp + (size_t)(wv * 2 + 1) * 512 + lane * 8);

    const _Float16* base = qkv + (size_t)b * QKVC * N + win * 64;
    {
        int c = t >> 2, q0 = (t & 3) * 16;
        const _Float16* pq = base + (size_t)c * N + q0;
        half8 a0 = *(const half8*)(pq);
        half8 a1 = *(const half8*)(pq + 8);
        *(half8*)&qT[c][q0] = a0;
        *(half8*)&qT[c][q0 + 8] = a1;
        const _Float16* pk = base + (size_t)(64 + c) * N + q0;
        half8 b0 = *(const half8*)(pk);
        half8 b1 = *(const half8*)(pk + 8);
        *(half8*)&kT[c][q0] = b0;
        *(half8*)&kT[c][q0 + 8] = b1;
        const _Float16* pv = base + (size_t)(128 + c) * N + q0;
        half8 v0 = *(const half8*)(pv);
        half8 v1 = *(const half8*)(pv + 8);
#pragma unroll
        for (int j = 0; j < 8; ++j) vP[q0 + j][c] = v0[j];
#pragma unroll
        for (int j = 0; j < 8; ++j) vP[q0 + 8 + j][c] = v1[j];
    }
    __syncthreads();
    if (t < 128) {
        int p = t & 63;
        float s = 0.f;
        if (t < 64) {
#pragma unroll
            for (int c = 0; c < 64; ++c) { float a = (float)qT[c][p]; s += a * a; }
        } else {
#pragma unroll
            for (int c = 0; c < 64; ++c) { float a = (float)kT[c][p]; s += a * a; }
        }
        tnorm[t] = s;
    }
    __syncthreads();
    if (t < 64) {
        float r = temp_p[0] / (fmaxf(sqrtf(tnorm[t]), 1e-12f) * fmaxf(sqrtf(tnorm[64 + t]), 1e-12f));
        wsc[t] = (_Float16)r;
    }
    __syncthreads();

    {
        half8 aq0 = *(const half8*)&qT[wv * 16 + lm][g * 8];
        half8 aq1 = *(const half8*)&qT[wv * 16 + lm][32 + g * 8];
        half8 ws0 = *(const half8*)&wsc[g * 8];
        half8 ws1 = *(const half8*)&wsc[32 + g * 8];
#pragma unroll
        for (int nt = 0; nt < 4; ++nt) {
            int d = nt * 16 + lm;
            half8 bk0 = *(const half8*)&kT[d][g * 8] * ws0;
            half8 bk1 = *(const half8*)&kT[d][32 + g * 8] * ws1;
            f32x4 acc = {0.f, 0.f, 0.f, 0.f};
            acc = __builtin_amdgcn_mfma_f32_16x16x32_f16(aq0, bk0, acc, 0, 0, 0);
            acc = __builtin_amdgcn_mfma_f32_16x16x32_f16(aq1, bk1, acc, 0, 0, 0);
#pragma unroll
            for (int r = 0; r < 4; ++r)
                aT[wv * 16 + g * 4 + r][d] = (_Float16)fmaxf(acc[r], 0.f);
        }
    }
    __syncthreads();

    {
        half8 a20, a21;
#pragma unroll
        for (int i = 0; i < 8; ++i) {
            a20[i] = aT[g * 8 + i][wv * 16 + lm];
            a21[i] = aT[32 + g * 8 + i][wv * 16 + lm];
        }
#pragma unroll
        for (int nt = 0; nt < 4; ++nt) {
            int p = nt * 16 + lm;
            half4v x0 = *(const half4v*)&vP[p][g * 8];
            half4v x1 = *(const half4v*)&vP[p][g * 8 + 4];
            half4v x2 = *(const half4v*)&vP[p][32 + g * 8];
            half4v x3 = *(const half4v*)&vP[p][32 + g * 8 + 4];
            half8 b20, b21;
#pragma unroll
            for (int j = 0; j < 4; ++j) { b20[j] = x0[j]; b20[4 + j] = x1[j]; b21[j] = x2[j]; b21[4 + j] = x3[j]; }
            f32x4 acc = {0.f, 0.f, 0.f, 0.f};
            acc = __builtin_amdgcn_mfma_f32_16x16x32_f16(a20, b20, acc, 0, 0, 0);
            acc = __builtin_amdgcn_mfma_f32_16x16x32_f16(a21, b21, acc, 0, 0, 0);
#pragma unroll
            for (int r = 0; r < 4; ++r)
                oP[p][wv * 16 + g * 4 + r] = (_Float16)acc[r];
        }
    }
    __syncthreads();

    {
        int y0 = (win >> 4) * 8, x0w = (win & 15) * 8;
        float* ob = out + (size_t)b * C * N;
#pragma unroll
        for (int nt = 0; nt < 4; ++nt) {
            int p = nt * 16 + lm;
            half4v x0 = *(const half4v*)&oP[p][g * 8];
            half4v x1 = *(const half4v*)&oP[p][g * 8 + 4];
            half4v x2 = *(const half4v*)&oP[p][32 + g * 8];
            half4v x3 = *(const half4v*)&oP[p][32 + g * 8 + 4];
            half8 b30, b31;
#pragma unroll
            for (int j = 0; j < 4; ++j) { b30[j] = x0[j]; b30[4 + j] = x1[j]; b31[j] = x2[j]; b31[4 + j] = x3[j]; }
            f32x4 acc = {0.f, 0.f, 0.f, 0.f};
            acc = __builtin_amdgcn_mfma_f32_16x16x32_f16(pa0, b30, acc, 0, 0, 0);
            acc = __builtin_amdgcn_mfma_f32_16x16x32_f16(pa1, b31, acc, 0, 0, 0);
            int gy = (y0 + (p >> 3) + 4) & 127;
            int gx = (x0w + (p & 7) + 4) & 127;
#pragma unroll
            for (int r = 0; r < 4; ++r)
                ob[(size_t)(wv * 16 + g * 4 + r) * N + gy * W + gx] = acc[r];
        }
    }
}

// =========== FFN stage B: dwconv3x3 + gelu gate, vectorized 8 px/thread ===========
__global__ __launch_bounds__(256, 1) void ffn_b_kernel(
    const _Float16* __restrict__ hid,   // (B,340,N)
    const float* __restrict__ dww,      // (340,9)
    _Float16* __restrict__ gated)       // (B,170,N)
{
    int bc = blockIdx.y;                 // b*170 + c
    int b = bc / 170, c = bc % 170;
    int n0 = (blockIdx.x * 256 + threadIdx.x) * 8;
    int y = n0 >> 7, x0 = n0 & 127;
    const _Float16* pa = hid + ((size_t)b * 340 + c) * N;
    const _Float16* pb = pa + (size_t)170 * N;
    const float* wa = dww + c * 9;          // uniform -> s_load
    const float* wb = wa + 170 * 9;

    float va[3][10], vb[3][10];
#pragma unroll
    for (int r = 0; r < 3; ++r) {
        int yy = y - 1 + r;
        if (yy < 0 || yy > 127) {
#pragma unroll
            for (int j = 0; j < 10; ++j) { va[r][j] = 0.f; vb[r][j] = 0.f; }
            continue;
        }
        const _Float16* ra = pa + yy * W + x0;
        const _Float16* rb = pb + yy * W + x0;
        half8 ma = *(const half8*)ra;
        half8 mb = *(const half8*)rb;
        va[r][0] = (x0 > 0) ? (float)ra[-1] : 0.f;
        vb[r][0] = (x0 > 0) ? (float)rb[-1] : 0.f;
#pragma unroll
        for (int j = 0; j < 8; ++j) { va[r][1 + j] = (float)ma[j]; vb[r][1 + j] = (float)mb[j]; }
        va[r][9] = (x0 < 120) ? (float)ra[8] : 0.f;
        vb[r][9] = (x0 < 120) ? (float)rb[8] : 0.f;
    }
    half8 o;
#pragma unroll
    for (int i = 0; i < 8; ++i) {
        float a = 0.f, g2 = 0.f;
#pragma unroll
        for (int r = 0; r < 3; ++r)
#pragma unroll
            for (int dx = 0; dx < 3; ++dx) {
                a  += wa[r * 3 + dx] * va[r][i + dx];
                g2 += wb[r * 3 + dx] * vb[r][i + dx];
            }
        o[i] = (_Float16)(gelu_fast(a) * g2);
    }
    *(half8*)(gated + ((size_t)b * 170 + c) * N + n0) = o;
}

// =========== GSA phase A ===========
__global__ __launch_bounds__(256, 1) void gsa_part_kernel(
    const _Float16* __restrict__ qkv, float* __restrict__ part)
{
    int bh = blockIdx.y, chunk = blockIdx.x;
    int b = bh >> 3, h = bh & 7;
    int t = threadIdx.x;
    const _Float16* qb = qkv + ((size_t)b * QKVC + h * 8) * N;
    const _Float16* kb = qb + (size_t)64 * N;
    float acc[80];
#pragma unroll
    for (int j = 0; j < 80; ++j) acc[j] = 0.f;
    for (int i = 0; i < 2; ++i) {
        int n = chunk * 512 + i * 256 + t;
        float qv[8], kv[8];
#pragma unroll
        for (int c = 0; c < 8; ++c) { qv[c] = (float)qb[(size_t)c * N + n]; kv[c] = (float)kb[(size_t)c * N + n]; }
#pragma unroll
        for (int c = 0; c < 8; ++c) {
            acc[64 + c] += qv[c] * qv[c];
            acc[72 + c] += kv[c] * kv[c];
#pragma unroll
            for (int d = 0; d < 8; ++d) acc[c * 8 + d] += qv[c] * kv[d];
        }
    }
#pragma unroll
    for (int j = 0; j < 80; ++j) {
        float v = acc[j];
#pragma unroll
        for (int m = 1; m < 64; m <<= 1) v += __shfl_xor(v, m, 64);
        acc[j] = v;
    }
    __shared__ float red[4 * 80];
    if ((t & 63) == 0) {
#pragma unroll
        for (int j = 0; j < 80; ++j) red[(t >> 6) * 80 + j] = acc[j];
    }
    __syncthreads();
    if (t < 80) {
        float s = red[t] + red[80 + t] + red[160 + t] + red[240 + t];
        part[((size_t)bh * 32 + chunk) * 80 + t] = s;
    }
}

// =========== GSA phase B ===========
__global__ __launch_bounds__(128) void gsa_fin_kernel(
    const float* __restrict__ part, const float* __restrict__ temp_p,
    float* __restrict__ attn)
{
    int bh = blockIdx.x;
    int t = threadIdx.x;
    __shared__ float red[80];
    if (t < 80) {
        float s = 0.f;
        for (int ch = 0; ch < 32; ++ch) s += part[((size_t)bh * 32 + ch) * 80 + t];
        red[t] = s;
    }
    __syncthreads();
    if (t < 64) {
        int c = t >> 3, d = t & 7;
        float S  = red[c * 8 + d];
        float qn = fmaxf(sqrtf(red[64 + c]), 1e-12f);
        float kn = fmaxf(sqrtf(red[72 + d]), 1e-12f);
        attn[(size_t)bh * 64 + t] = fmaxf(temp_p[0] * S / (qn * kn), 0.f);
    }
}

// =========== GSA phase C: W_eff ===========
__global__ __launch_bounds__(64) void weff_kernel(
    const float* __restrict__ attn, const float* __restrict__ pw,
    float* __restrict__ weff)
{
    int b = blockIdx.x;
    int o = threadIdx.x;
    __shared__ float al[512];
    for (int idx = o; idx < 512; idx += 64) al[idx] = attn[(size_t)b * 512 + idx];
    __syncthreads();
    for (int hd = 0; hd < 64; ++hd) {
        int h = hd >> 3, d = hd & 7;
        float acc = 0.f;
#pragma unroll
        for (int c = 0; c < 8; ++c)
            acc += pw[o * 64 + c * 8 + h] * al[h * 64 + c * 8 + d];
        weff[((size_t)b * 64 + o) * 64 + hd] = acc;
    }
}

// =========== sentinel ===========
__global__ void sentinel_kernel(float* out, int n) {
    int i = blockIdx.x * 256 + threadIdx.x;
    if (i < n) out[i] = 12345.0f;
}

extern "C" void kernel_launch(void* const* d_in, const int* in_sizes, int n_in,
                              void* d_out, int out_size, void* d_ws, size_t ws_size,
                              hipStream_t stream)
{
    const float* x         = (const float*)d_in[0];
    const float* ln_s0_w   = (const float*)d_in[1];
    const float* ln_s0_b   = (const float*)d_in[2];
    const float* ln_s2_w   = (const float*)d_in[3];
    const float* ln_s2_b   = (const float*)d_in[4];
    const float* rsa_qkv_w = (const float*)d_in[5];
    const float* rsa_dw_w  = (const float*)d_in[6];
    const float* rsa_proj_w= (const float*)d_in[7];
    const float* rsa_temp  = (const float*)d_in[8];
    const float* ffs_in_w  = (const float*)d_in[9];
    const float* ffs_dw_w  = (const float*)d_in[10];
    const float* ffs_out_w = (const float*)d_in[11];
    const float* ln_c0_w   = (const float*)d_in[12];
    const float* ln_c0_b   = (const float*)d_in[13];
    const float* ln_c2_w   = (const float*)d_in[14];
    const float* ln_c2_b   = (const float*)d_in[15];
    const float* gsa_qkv_w = (const float*)d_in[16];
    const float* gsa_dw_w  = (const float*)d_in[17];
    const float* gsa_proj_w= (const float*)d_in[18];
    const float* gsa_temp  = (const float*)d_in[19];
    const float* ffc_in_w  = (const float*)d_in[20];
    const float* ffc_dw_w  = (const float*)d_in[21];
    const float* ffc_out_w = (const float*)d_in[22];
    float* outp = (float*)d_out;

    // ---- workspace layout (total 168,828,928 B; same footprint as verified rounds) ----
    char* ws = (char*)d_ws;
    _Float16* tmp192 = (_Float16*)(ws + 0);            // (B,192,N) fp16 [0, 50,331,648)
    _Float16* Qbuf16 = (_Float16*)(ws + 50331648ull);  // (B,192,N) fp16 [50,331,648, 100,663,296)
    _Float16* hidA   = (_Float16*)(ws + 0);            // (B,340,N) fp16 overlay [0, 89,128,960)
    _Float16* gated  = (_Float16*)(ws + 89128960ull);  // (B,170,N) fp16, ends 133,693,440
    _Float16* wp_rsap= (_Float16*)(ws + 133693440ull); // 8,192 B
    float*    S2     = (float*)(ws + 134217728ull);    // (B,64,N) fp32
    float*    part   = (float*)(ws + 167772160ull);    // 655,360
    float*    attn_s = (float*)(ws + 168427520ull);    // 16,384
    float*    weffb  = (float*)(ws + 168443904ull);    // 131,072
    _Float16* wp_rsa = (_Float16*)(ws + 168574976ull); // 24,576
    _Float16* wp_gsa = (_Float16*)(ws + 168599552ull); // 24,576
    _Float16* wp_fsi = (_Float16*)(ws + 168624128ull); // 45,056
    _Float16* wp_fci = (_Float16*)(ws + 168669184ull); // 45,056
    _Float16* wp_fso = (_Float16*)(ws + 168714240ull); // 24,576
    _Float16* wp_fco = (_Float16*)(ws + 168738816ull); // 24,576
    _Float16* wp_pbw = (_Float16*)(ws + 168763392ull); // 65,536 -> ends 168,828,928
    if (ws_size < 168828928ull) {
        int n = out_size < 4096 ? out_size : 4096;
        sentinel_kernel<<<16, 256, 0, stream>>>(outp, n);
        return;
    }

    dim3 blk256(256);

    wpack_kernel<<<24, 64, 0, stream>>>(rsa_qkv_w, 192, 64, 2, wp_rsa);
    wpack_kernel<<<24, 64, 0, stream>>>(gsa_qkv_w, 192, 64, 2, wp_gsa);
    wpack_kernel<<<44, 64, 0, stream>>>(ffs_in_w, 340, 64, 2, wp_fsi);
    wpack_kernel<<<44, 64, 0, stream>>>(ffc_in_w, 340, 64, 2, wp_fci);
    wpack_kernel<<<24, 64, 0, stream>>>(ffs_out_w, 64, 170, 6, wp_fso);
    wpack_kernel<<<24, 64, 0, stream>>>(ffc_out_w, 64, 170, 6, wp_fco);
    wpack_kernel<<<8, 64, 0, stream>>>(rsa_proj_w, 64, 64, 2, wp_rsap);

    // ---- spatial (RSA) half ----
    lngemm_kernel<6, 192, false><<<2048, blk256, 0, stream>>>(x, nullptr, ln_s0_w, ln_s0_b, wp_rsa, tmp192);
    dw16_kernel<true><<<dim3(8, B * 192), blk256, 0, stream>>>(tmp192, rsa_dw_w, Qbuf16);   // -> window-major
    rsa_win_kernel<<<2048, blk256, 0, stream>>>(Qbuf16, rsa_temp, wp_rsap, S2);             // x_ spatial
    lngemm_kernel<11, 340, true><<<2048, blk256, 0, stream>>>(S2, x, ln_s2_w, ln_s2_b, wp_fsi, hidA);
    ffn_b_kernel<<<dim3(8, B * 170), blk256, 0, stream>>>(hidA, ffs_dw_w, gated);
    gemm_kernel<2, 6, 2, 2, 170, 64, 170, false, true, true>
        <<<2048, blk256, 0, stream>>>(gated, wp_fso, S2, outp);                             // x -> d_out

    // ---- channel (GSA) half ----
    lngemm_kernel<6, 192, false><<<2048, blk256, 0, stream>>>(outp, nullptr, ln_c0_w, ln_c0_b, wp_gsa, tmp192);
    dw16_kernel<false><<<dim3(8, B * 192), blk256, 0, stream>>>(tmp192, gsa_dw_w, Qbuf16);  // linear
    gsa_part_kernel<<<dim3(32, 64), blk256, 0, stream>>>(Qbuf16, part);
    gsa_fin_kernel<<<64, dim3(128), 0, stream>>>(part, gsa_temp, attn_s);
    weff_kernel<<<8, dim3(64), 0, stream>>>(attn_s, gsa_proj_w, weffb);
    weffpack_kernel<<<8, dim3(512), 0, stream>>>(weffb, wp_pbw);
    gemm_kernel<4, 2, 1, 1, 64, 64, 192, true, true, false>
        <<<2048, blk256, 0, stream>>>(Qbuf16 + (size_t)128 * N, wp_pbw, nullptr, S2);       // x_ channel
    lngemm_kernel<11, 340, true><<<2048, blk256, 0, stream>>>(S2, outp, ln_c2_w, ln_c2_b, wp_fci, hidA);
    ffn_b_kernel<<<dim3(8, B * 170), blk256, 0, stream>>>(hidA, ffc_dw_w, gated);
    gemm_kernel<2, 6, 2, 2, 170, 64, 170, false, true, true>
        <<<2048, blk256, 0, stream>>>(gated, wp_fco, S2, outp);                             // final
}

// Round 9
// 426.881 us; speedup vs baseline: 5.8339x; 1.0577x over previous
//
#include <hip/hip_runtime.h>
#include <hip/hip_bf16.h>
#include <math.h>

#define DI __device__ __forceinline__

constexpr int B = 8, C = 64, H = 128, W = 128, N = H * W;   // N = 16384
constexpr int HID = 170;
constexpr int QKVC = 3 * C;                                 // 192

typedef _Float16 half8 __attribute__((ext_vector_type(8)));
typedef _Float16 half4v __attribute__((ext_vector_type(4)));
typedef float f32x4 __attribute__((ext_vector_type(4)));

// gelu exact ~= v * sigmoid(1.5957691*(v + 0.044715 v^3)); max abs err ~3e-4
DI float gelu_fast(float v) {
    return v / (1.0f + __expf(-1.5957691216057308f * (v + 0.044715f * v * v * v)));
}

// =========== weight pre-pack into MFMA A-fragment order, fp32 -> fp16 ===========
__global__ __launch_bounds__(64) void wpack_kernel(
    const float* __restrict__ Wm, int OREAL, int KREAL, int KT,
    _Float16* __restrict__ out)
{
    int f = blockIdx.x, l = threadIdx.x;
    int mt = f / KT, kt = f % KT;
    int row = mt * 16 + (l & 15);
    int col0 = kt * 32 + (l >> 4) * 8;
    half8 v;
#pragma unroll
    for (int i = 0; i < 8; ++i) {
        int col = col0 + i;
        v[i] = (row < OREAL && col < KREAL) ? (_Float16)Wm[row * KREAL + col] : (_Float16)0.f;
    }
    *(half8*)(out + (size_t)f * 512 + l * 8) = v;
}

// =========== per-batch weff pack (O=64, K=64 -> 8 frags/batch) ===========
__global__ __launch_bounds__(512) void weffpack_kernel(
    const float* __restrict__ weff, _Float16* __restrict__ out)
{
    int b = blockIdx.x;
    int f = threadIdx.x >> 6, l = threadIdx.x & 63;
    int mt = f >> 1, kt = f & 1;
    int row = mt * 16 + (l & 15);
    int col0 = kt * 32 + (l >> 4) * 8;
    const float* wb = weff + (size_t)b * 4096;
    half8 v;
#pragma unroll
    for (int i = 0; i < 8; ++i) v[i] = (_Float16)wb[row * 64 + col0 + i];
    *(half8*)(out + ((size_t)b * 8 + f) * 512 + l * 8) = v;
}

// =========== fused LayerNorm + MFMA GEMM (CIN=64) ===========
// PRIM16: primary input fp16; ADDIN: + fp32 residual. LN stats via 4-lane shfl.
template<int MT, int OREAL, bool PRIM16, bool ADDIN>
__global__ __launch_bounds__(256, 1) void lngemm_kernel(
    const void* __restrict__ Xv, const float* __restrict__ Xadd,
    const float* __restrict__ lnw, const float* __restrict__ lnb,
    const _Float16* __restrict__ Wp, _Float16* __restrict__ outp)
{
    constexpr int MG = 2, NSTRIP = 2, PG = 2, PPB = 64;
    int t = threadIdx.x, lane = t & 63, wv = t >> 6;
    int mg = wv % MG, pg = wv / MG;
    int pbase = blockIdx.x * PPB;
    int b = pbase >> 14, nb = pbase & (N - 1);

    half8 a[MT][2];
    const _Float16* wb = Wp + (size_t)(mg * MT * 2) * 512 + lane * 8;
#pragma unroll
    for (int mt = 0; mt < MT; ++mt)
#pragma unroll
        for (int kt = 0; kt < 2; ++kt)
            a[mt][kt] = *(const half8*)(wb + (mt * 2 + kt) * 512);

    int krow0 = (lane >> 4) * 8;
    float wreg[2][8], breg[2][8];
#pragma unroll
    for (int kt = 0; kt < 2; ++kt)
#pragma unroll
        for (int i = 0; i < 8; ++i) {
            int c = kt * 32 + krow0 + i;
            wreg[kt][i] = lnw[c];
            breg[kt][i] = lnb[c];
        }

    const float*    xb32 = PRIM16 ? nullptr : ((const float*)Xv) + (size_t)b * 64 * N;
    const _Float16* xb16 = PRIM16 ? ((const _Float16*)Xv) + (size_t)b * 64 * N : nullptr;
    const float* ab = ADDIN ? (Xadd + (size_t)b * 64 * N) : nullptr;

    for (int s = 0; s < NSTRIP; ++s) {
        int col = nb + (s * PG + pg) * 16 + (lane & 15);
        float vv[2][8];
        float sm = 0.f, ss = 0.f;
#pragma unroll
        for (int kt = 0; kt < 2; ++kt)
#pragma unroll
            for (int i = 0; i < 8; ++i) {
                int c = kt * 32 + krow0 + i;
                float v = PRIM16 ? (float)xb16[(size_t)c * N + col] : xb32[(size_t)c * N + col];
                if (ADDIN) v += ab[(size_t)c * N + col];
                vv[kt][i] = v; sm += v; ss += v * v;
            }
        sm += __shfl_xor(sm, 16); ss += __shfl_xor(ss, 16);
        sm += __shfl_xor(sm, 32); ss += __shfl_xor(ss, 32);
        float mu = sm * (1.0f / 64.0f);
        float var = ss * (1.0f / 64.0f) - mu * mu;
        float rstd = rsqrtf(var + 1e-5f);
        half8 bf[2];
#pragma unroll
        for (int kt = 0; kt < 2; ++kt)
#pragma unroll
            for (int i = 0; i < 8; ++i)
                bf[kt][i] = (_Float16)((vv[kt][i] - mu) * rstd * wreg[kt][i] + breg[kt][i]);

        f32x4 acc[MT];
#pragma unroll
        for (int mt = 0; mt < MT; ++mt) acc[mt] = (f32x4){0.f, 0.f, 0.f, 0.f};
#pragma unroll
        for (int kt = 0; kt < 2; ++kt)
#pragma unroll
            for (int mt = 0; mt < MT; ++mt)
                acc[mt] = __builtin_amdgcn_mfma_f32_16x16x32_f16(a[mt][kt], bf[kt], acc[mt], 0, 0, 0);

        int orow0 = mg * (MT * 16) + (lane >> 4) * 4;
#pragma unroll
        for (int mt = 0; mt < MT; ++mt)
#pragma unroll
            for (int r = 0; r < 4; ++r) {
                int orow = orow0 + mt * 16 + r;
                bool ok = (MG * MT * 16 == OREAL) || (orow < OREAL);
                if (ok)
                    outp[((size_t)b * OREAL + orow) * N + col] = (_Float16)acc[mt][r];
            }
    }
}

// =========== MFMA conv1x1 GEMM (fp16 input); resid fp16; OUT32 -> fp32 out ===========
template<int MT, int KT, int MG, int NSTRIP, int CIN, int OREAL, int XROWS,
         bool PBW, bool OUT32, bool RESID>
__global__ __launch_bounds__(256, 1) void gemm_kernel(
    const _Float16* __restrict__ X, const _Float16* __restrict__ Wp,
    const _Float16* __restrict__ resid, void* __restrict__ outv)
{
    constexpr int PG = 4 / MG;
    constexpr int PPB = PG * 16 * NSTRIP;
    int t = threadIdx.x;
    int lane = t & 63, wv = t >> 6;
    int mg = wv % MG, pg = wv / MG;
    int pbase = blockIdx.x * PPB;
    int b = pbase >> 14, nb = pbase & (N - 1);

    half8 a[MT][KT];
    const _Float16* wb = Wp + ((size_t)(PBW ? b * (MG * MT * KT) : 0) + mg * MT * KT) * 512 + lane * 8;
#pragma unroll
    for (int mt = 0; mt < MT; ++mt)
#pragma unroll
        for (int kt = 0; kt < KT; ++kt)
            a[mt][kt] = *(const half8*)(wb + (mt * KT + kt) * 512);

    const _Float16* xb = X + (size_t)b * XROWS * N;
    int krow0 = (lane >> 4) * 8;

    for (int s = 0; s < NSTRIP; ++s) {
        int col = nb + (s * PG + pg) * 16 + (lane & 15);
        const _Float16* xp = xb + col;
        half8 bf[KT];
#pragma unroll
        for (int kt = 0; kt < KT; ++kt)
#pragma unroll
            for (int i = 0; i < 8; ++i) {
                int c = kt * 32 + krow0 + i;
                if (KT * 32 <= CIN || c < CIN) bf[kt][i] = xp[(size_t)c * N];
                else bf[kt][i] = (_Float16)0.f;
            }
        f32x4 acc[MT];
#pragma unroll
        for (int mt = 0; mt < MT; ++mt) acc[mt] = (f32x4){0.f, 0.f, 0.f, 0.f};
#pragma unroll
        for (int kt = 0; kt < KT; ++kt)
#pragma unroll
            for (int mt = 0; mt < MT; ++mt)
                acc[mt] = __builtin_amdgcn_mfma_f32_16x16x32_f16(a[mt][kt], bf[kt], acc[mt], 0, 0, 0);

        int orow0 = mg * (MT * 16) + (lane >> 4) * 4;
#pragma unroll
        for (int mt = 0; mt < MT; ++mt)
#pragma unroll
            for (int r = 0; r < 4; ++r) {
                int orow = orow0 + mt * 16 + r;
                bool ok = (MG * MT * 16 == OREAL) || (orow < OREAL);
                if (ok) {
                    size_t oidx = ((size_t)b * OREAL + orow) * N + col;
                    if constexpr (OUT32) {
                        float vv = acc[mt][r];
                        if constexpr (RESID) vv += (float)resid[((size_t)b * 64 + orow) * N + col];
                        ((float*)outv)[oidx] = vv;
                    } else {
                        ((_Float16*)outv)[oidx] = (_Float16)acc[mt][r];
                    }
                }
            }
    }
}

// =========== depthwise 3x3, packed fp16, 8 px/thread ===========
// ROLLWM: rolled gather (+4 mod 128) + window-major write (for RSA)
template<bool ROLLWM>
__global__ __launch_bounds__(256, 1) void dw16_kernel(
    const _Float16* __restrict__ in, const float* __restrict__ w,
    _Float16* __restrict__ out)
{
    int bc = blockIdx.y;                 // b*192 + c
    int c = bc % 192;
    int n0 = (blockIdx.x * 256 + threadIdx.x) * 8;
    int y = n0 >> 7, x0 = n0 & 127;
    const _Float16* ib = in + (size_t)bc * N;
    const float* wr = w + c * 9;         // uniform -> s_load
    _Float16 wh[9];
#pragma unroll
    for (int i = 0; i < 9; ++i) wh[i] = (_Float16)wr[i];

    half8 acc = {0, 0, 0, 0, 0, 0, 0, 0};
#pragma unroll
    for (int r = 0; r < 3; ++r) {
        int yy = y - 1 + r;
        if (yy < 0 || yy > 127) continue;
        half8 sL, m, sR;
        if (!ROLLWM) {
            const _Float16* rp = ib + yy * W + x0;
            m = *(const half8*)rp;
            half8 pv = {0, 0, 0, 0, 0, 0, 0, 0};
            half8 nv = {0, 0, 0, 0, 0, 0, 0, 0};
            pv[7] = (x0 > 0) ? rp[-1] : (_Float16)0.f;
            nv[0] = (x0 < 120) ? rp[8] : (_Float16)0.f;
            sL = __builtin_shufflevector(pv, m, 7, 8, 9, 10, 11, 12, 13, 14);
            sR = __builtin_shufflevector(m, nv, 1, 2, 3, 4, 5, 6, 7, 8);
        } else {
            int sy = (yy + 4) & 127;
            const _Float16* rp = ib + sy * W;
            if (x0 <= 112) {
                half8 b0 = *(const half8*)(rp + x0);
                half8 b1 = *(const half8*)(rp + x0 + 8);
                sL = __builtin_shufflevector(b0, b1, 3, 4, 5, 6, 7, 8, 9, 10);
                m  = __builtin_shufflevector(b0, b1, 4, 5, 6, 7, 8, 9, 10, 11);
                sR = __builtin_shufflevector(b0, b1, 5, 6, 7, 8, 9, 10, 11, 12);
                if (x0 == 0) sL[0] = (_Float16)0.f;   // xx = -1
            } else {                                   // x0 == 120, wrap path
                _Float16 tmp[10];
#pragma unroll
                for (int j = 0; j < 10; ++j) {
                    int xx = 119 + j;
                    tmp[j] = (xx <= 127) ? rp[(xx + 4) & 127] : (_Float16)0.f;
                }
#pragma unroll
                for (int j = 0; j < 8; ++j) { sL[j] = tmp[j]; m[j] = tmp[j + 1]; sR[j] = tmp[j + 2]; }
            }
        }
        acc += sL * wh[r * 3 + 0] + m * wh[r * 3 + 1] + sR * wh[r * 3 + 2];
    }
    if (ROLLWM) {
        int win = ((y >> 3) << 4) | (x0 >> 3);
        int p = (y & 7) << 3;                        // 8 px = one window row
        *(half8*)(out + (size_t)bc * N + win * 64 + p) = acc;
    } else {
        *(half8*)(out + (size_t)bc * N + n0) = acc;
    }
}

// =========== RSA window attention (MFMA) + fused proj; one block per window ===========
__global__ __launch_bounds__(256, 3) void rsa_win_kernel(
    const _Float16* __restrict__ qkv, const float* __restrict__ temp_p,
    const _Float16* __restrict__ pwp, _Float16* __restrict__ out)
{
    __shared__ _Float16 qT[64][72];
    __shared__ _Float16 kT[64][72];
    __shared__ _Float16 vP[64][76];
    __shared__ _Float16 aT[64][76];
    __shared__ _Float16 oP[64][76];
    __shared__ float tnorm[128];
    __shared__ _Float16 wsc[64];
    int blk = blockIdx.x, b = blk >> 8, win = blk & 255;
    int t = threadIdx.x, lane = t & 63, wv = t >> 6;
    int g = lane >> 4, lm = lane & 15;

    half8 pa0 = *(const half8*)(pwp + (size_t)(wv * 2 + 0) * 512 + lane * 8);
    half8 pa1 = *(const half8*)(pwp + (size_t)(wv * 2 + 1) * 512 + lane * 8);

    const _Float16* base = qkv + (size_t)b * QKVC * N + win * 64;
    {
        int c = t >> 2, q0 = (t & 3) * 16;
        const _Float16* pq = base + (size_t)c * N + q0;
        half8 a0 = *(const half8*)(pq);
        half8 a1 = *(const half8*)(pq + 8);
        *(half8*)&qT[c][q0] = a0;
        *(half8*)&qT[c][q0 + 8] = a1;
        const _Float16* pk = base + (size_t)(64 + c) * N + q0;
        half8 b0 = *(const half8*)(pk);
        half8 b1 = *(const half8*)(pk + 8);
        *(half8*)&kT[c][q0] = b0;
        *(half8*)&kT[c][q0 + 8] = b1;
        const _Float16* pv = base + (size_t)(128 + c) * N + q0;
        half8 v0 = *(const half8*)(pv);
        half8 v1 = *(const half8*)(pv + 8);
#pragma unroll
        for (int j = 0; j < 8; ++j) vP[q0 + j][c] = v0[j];
#pragma unroll
        for (int j = 0; j < 8; ++j) vP[q0 + 8 + j][c] = v1[j];
    }
    __syncthreads();
    if (t < 128) {
        int p = t & 63;
        float s = 0.f;
        if (t < 64) {
#pragma unroll
            for (int c = 0; c < 64; ++c) { float a = (float)qT[c][p]; s += a * a; }
        } else {
#pragma unroll
            for (int c = 0; c < 64; ++c) { float a = (float)kT[c][p]; s += a * a; }
        }
        tnorm[t] = s;
    }
    __syncthreads();
    if (t < 64) {
        float r = temp_p[0] / (fmaxf(sqrtf(tnorm[t]), 1e-12f) * fmaxf(sqrtf(tnorm[64 + t]), 1e-12f));
        wsc[t] = (_Float16)r;
    }
    __syncthreads();

    {
        half8 aq0 = *(const half8*)&qT[wv * 16 + lm][g * 8];
        half8 aq1 = *(const half8*)&qT[wv * 16 + lm][32 + g * 8];
        half8 ws0 = *(const half8*)&wsc[g * 8];
        half8 ws1 = *(const half8*)&wsc[32 + g * 8];
#pragma unroll
        for (int nt = 0; nt < 4; ++nt) {
            int d = nt * 16 + lm;
            half8 bk0 = *(const half8*)&kT[d][g * 8] * ws0;
            half8 bk1 = *(const half8*)&kT[d][32 + g * 8] * ws1;
            f32x4 acc = {0.f, 0.f, 0.f, 0.f};
            acc = __builtin_amdgcn_mfma_f32_16x16x32_f16(aq0, bk0, acc, 0, 0, 0);
            acc = __builtin_amdgcn_mfma_f32_16x16x32_f16(aq1, bk1, acc, 0, 0, 0);
#pragma unroll
            for (int r = 0; r < 4; ++r)
                aT[wv * 16 + g * 4 + r][d] = (_Float16)fmaxf(acc[r], 0.f);
        }
    }
    __syncthreads();

    {
        half8 a20, a21;
#pragma unroll
        for (int i = 0; i < 8; ++i) {
            a20[i] = aT[g * 8 + i][wv * 16 + lm];
            a21[i] = aT[32 + g * 8 + i][wv * 16 + lm];
        }
#pragma unroll
        for (int nt = 0; nt < 4; ++nt) {
            int p = nt * 16 + lm;
            half4v x0 = *(const half4v*)&vP[p][g * 8];
            half4v x1 = *(const half4v*)&vP[p][g * 8 + 4];
            half4v x2 = *(const half4v*)&vP[p][32 + g * 8];
            half4v x3 = *(const half4v*)&vP[p][32 + g * 8 + 4];
            half8 b20, b21;
#pragma unroll
            for (int j = 0; j < 4; ++j) { b20[j] = x0[j]; b20[4 + j] = x1[j]; b21[j] = x2[j]; b21[4 + j] = x3[j]; }
            f32x4 acc = {0.f, 0.f, 0.f, 0.f};
            acc = __builtin_amdgcn_mfma_f32_16x16x32_f16(a20, b20, acc, 0, 0, 0);
            acc = __builtin_amdgcn_mfma_f32_16x16x32_f16(a21, b21, acc, 0, 0, 0);
#pragma unroll
            for (int r = 0; r < 4; ++r)
                oP[p][wv * 16 + g * 4 + r] = (_Float16)acc[r];
        }
    }
    __syncthreads();

    {
        int y0 = (win >> 4) * 8, x0w = (win & 15) * 8;
        _Float16* ob = out + (size_t)b * C * N;
#pragma unroll
        for (int nt = 0; nt < 4; ++nt) {
            int p = nt * 16 + lm;
            half4v x0 = *(const half4v*)&oP[p][g * 8];
            half4v x1 = *(const half4v*)&oP[p][g * 8 + 4];
            half4v x2 = *(const half4v*)&oP[p][32 + g * 8];
            half4v x3 = *(const half4v*)&oP[p][32 + g * 8 + 4];
            half8 b30, b31;
#pragma unroll
            for (int j = 0; j < 4; ++j) { b30[j] = x0[j]; b30[4 + j] = x1[j]; b31[j] = x2[j]; b31[4 + j] = x3[j]; }
            f32x4 acc = {0.f, 0.f, 0.f, 0.f};
            acc = __builtin_amdgcn_mfma_f32_16x16x32_f16(pa0, b30, acc, 0, 0, 0);
            acc = __builtin_amdgcn_mfma_f32_16x16x32_f16(pa1, b31, acc, 0, 0, 0);
            int gy = (y0 + (p >> 3) + 4) & 127;
            int gx = (x0w + (p & 7) + 4) & 127;
#pragma unroll
            for (int r = 0; r < 4; ++r)
                ob[(size_t)(wv * 16 + g * 4 + r) * N + gy * W + gx] = (_Float16)acc[r];
        }
    }
}

// =========== FFN stage B: dwconv3x3 + gelu gate, packed fp16, 8 px/thread ===========
__global__ __launch_bounds__(256, 1) void ffn_b_kernel(
    const _Float16* __restrict__ hid,   // (B,340,N)
    const float* __restrict__ dww,      // (340,9)
    _Float16* __restrict__ gated)       // (B,170,N)
{
    int bc = blockIdx.y;                 // b*170 + c
    int b = bc / 170, c = bc % 170;
    int n0 = (blockIdx.x * 256 + threadIdx.x) * 8;
    int y = n0 >> 7, x0 = n0 & 127;
    const _Float16* pa = hid + ((size_t)b * 340 + c) * N;
    const _Float16* pb = pa + (size_t)170 * N;
    const float* wa = dww + c * 9;          // uniform -> s_load
    const float* wbp = wa + 170 * 9;
    _Float16 wha[9], whb[9];
#pragma unroll
    for (int i = 0; i < 9; ++i) { wha[i] = (_Float16)wa[i]; whb[i] = (_Float16)wbp[i]; }

    half8 accA = {0, 0, 0, 0, 0, 0, 0, 0};
    half8 accB = {0, 0, 0, 0, 0, 0, 0, 0};
#pragma unroll
    for (int r = 0; r < 3; ++r) {
        int yy = y - 1 + r;
        if (yy < 0 || yy > 127) continue;
        {
            const _Float16* ra = pa + yy * W + x0;
            half8 m = *(const half8*)ra;
            half8 pv = {0, 0, 0, 0, 0, 0, 0, 0};
            half8 nv = {0, 0, 0, 0, 0, 0, 0, 0};
            pv[7] = (x0 > 0) ? ra[-1] : (_Float16)0.f;
            nv[0] = (x0 < 120) ? ra[8] : (_Float16)0.f;
            half8 sL = __builtin_shufflevector(pv, m, 7, 8, 9, 10, 11, 12, 13, 14);
            half8 sR = __builtin_shufflevector(m, nv, 1, 2, 3, 4, 5, 6, 7, 8);
            accA += sL * wha[r * 3 + 0] + m * wha[r * 3 + 1] + sR * wha[r * 3 + 2];
        }
        {
            const _Float16* rb = pb + yy * W + x0;
            half8 m = *(const half8*)rb;
            half8 pv = {0, 0, 0, 0, 0, 0, 0, 0};
            half8 nv = {0, 0, 0, 0, 0, 0, 0, 0};
            pv[7] = (x0 > 0) ? rb[-1] : (_Float16)0.f;
            nv[0] = (x0 < 120) ? rb[8] : (_Float16)0.f;
            half8 sL = __builtin_shufflevector(pv, m, 7, 8, 9, 10, 11, 12, 13, 14);
            half8 sR = __builtin_shufflevector(m, nv, 1, 2, 3, 4, 5, 6, 7, 8);
            accB += sL * whb[r * 3 + 0] + m * whb[r * 3 + 1] + sR * whb[r * 3 + 2];
        }
    }
    half8 o;
#pragma unroll
    for (int i = 0; i < 8; ++i) {
        float a = (float)accA[i];
        float g2 = (float)accB[i];
        o[i] = (_Float16)(gelu_fast(a) * g2);
    }
    *(half8*)(gated + ((size_t)b * 170 + c) * N + n0) = o;
}

// =========== GSA phase A ===========
__global__ __launch_bounds__(256, 1) void gsa_part_kernel(
    const _Float16* __restrict__ qkv, float* __restrict__ part)
{
    int bh = blockIdx.y, chunk = blockIdx.x;
    int b = bh >> 3, h = bh & 7;
    int t = threadIdx.x;
    const _Float16* qb = qkv + ((size_t)b * QKVC + h * 8) * N;
    const _Float16* kb = qb + (size_t)64 * N;
    float acc[80];
#pragma unroll
    for (int j = 0; j < 80; ++j) acc[j] = 0.f;
    for (int i = 0; i < 2; ++i) {
        int n = chunk * 512 + i * 256 + t;
        float qv[8], kv[8];
#pragma unroll
        for (int c = 0; c < 8; ++c) { qv[c] = (float)qb[(size_t)c * N + n]; kv[c] = (float)kb[(size_t)c * N + n]; }
#pragma unroll
        for (int c = 0; c < 8; ++c) {
            acc[64 + c] += qv[c] * qv[c];
            acc[72 + c] += kv[c] * kv[c];
#pragma unroll
            for (int d = 0; d < 8; ++d) acc[c * 8 + d] += qv[c] * kv[d];
        }
    }
#pragma unroll
    for (int j = 0; j < 80; ++j) {
        float v = acc[j];
#pragma unroll
        for (int m = 1; m < 64; m <<= 1) v += __shfl_xor(v, m, 64);
        acc[j] = v;
    }
    __shared__ float red[4 * 80];
    if ((t & 63) == 0) {
#pragma unroll
        for (int j = 0; j < 80; ++j) red[(t >> 6) * 80 + j] = acc[j];
    }
    __syncthreads();
    if (t < 80) {
        float s = red[t] + red[80 + t] + red[160 + t] + red[240 + t];
        part[((size_t)bh * 32 + chunk) * 80 + t] = s;
    }
}

// =========== GSA phase B ===========
__global__ __launch_bounds__(128) void gsa_fin_kernel(
    const float* __restrict__ part, const float* __restrict__ temp_p,
    float* __restrict__ attn)
{
    int bh = blockIdx.x;
    int t = threadIdx.x;
    __shared__ float red[80];
    if (t < 80) {
        float s = 0.f;
        for (int ch = 0; ch < 32; ++ch) s += part[((size_t)bh * 32 + ch) * 80 + t];
        red[t] = s;
    }
    __syncthreads();
    if (t < 64) {
        int c = t >> 3, d = t & 7;
        float S  = red[c * 8 + d];
        float qn = fmaxf(sqrtf(red[64 + c]), 1e-12f);
        float kn = fmaxf(sqrtf(red[72 + d]), 1e-12f);
        attn[(size_t)bh * 64 + t] = fmaxf(temp_p[0] * S / (qn * kn), 0.f);
    }
}

// =========== GSA phase C: W_eff ===========
__global__ __launch_bounds__(64) void weff_kernel(
    const float* __restrict__ attn, const float* __restrict__ pw,
    float* __restrict__ weff)
{
    int b = blockIdx.x;
    int o = threadIdx.x;
    __shared__ float al[512];
    for (int idx = o; idx < 512; idx += 64) al[idx] = attn[(size_t)b * 512 + idx];
    __syncthreads();
    for (int hd = 0; hd < 64; ++hd) {
        int h = hd >> 3, d = hd & 7;
        float acc = 0.f;
#pragma unroll
        for (int c = 0; c < 8; ++c)
            acc += pw[o * 64 + c * 8 + h] * al[h * 64 + c * 8 + d];
        weff[((size_t)b * 64 + o) * 64 + hd] = acc;
    }
}

// =========== sentinel ===========
__global__ void sentinel_kernel(float* out, int n) {
    int i = blockIdx.x * 256 + threadIdx.x;
    if (i < n) out[i] = 12345.0f;
}

extern "C" void kernel_launch(void* const* d_in, const int* in_sizes, int n_in,
                              void* d_out, int out_size, void* d_ws, size_t ws_size,
                              hipStream_t stream)
{
    const float* x         = (const float*)d_in[0];
    const float* ln_s0_w   = (const float*)d_in[1];
    const float* ln_s0_b   = (const float*)d_in[2];
    const float* ln_s2_w   = (const float*)d_in[3];
    const float* ln_s2_b   = (const float*)d_in[4];
    const float* rsa_qkv_w = (const float*)d_in[5];
    const float* rsa_dw_w  = (const float*)d_in[6];
    const float* rsa_proj_w= (const float*)d_in[7];
    const float* rsa_temp  = (const float*)d_in[8];
    const float* ffs_in_w  = (const float*)d_in[9];
    const float* ffs_dw_w  = (const float*)d_in[10];
    const float* ffs_out_w = (const float*)d_in[11];
    const float* ln_c0_w   = (const float*)d_in[12];
    const float* ln_c0_b   = (const float*)d_in[13];
    const float* ln_c2_w   = (const float*)d_in[14];
    const float* ln_c2_b   = (const float*)d_in[15];
    const float* gsa_qkv_w = (const float*)d_in[16];
    const float* gsa_dw_w  = (const float*)d_in[17];
    const float* gsa_proj_w= (const float*)d_in[18];
    const float* gsa_temp  = (const float*)d_in[19];
    const float* ffc_in_w  = (const float*)d_in[20];
    const float* ffc_dw_w  = (const float*)d_in[21];
    const float* ffc_out_w = (const float*)d_in[22];
    float* outp = (float*)d_out;

    // ---- workspace layout (total 168,828,928 B; same footprint as verified rounds) ----
    char* ws = (char*)d_ws;
    _Float16* tmp192 = (_Float16*)(ws + 0);            // (B,192,N) fp16 [0, 50,331,648)
    _Float16* Qbuf16 = (_Float16*)(ws + 50331648ull);  // (B,192,N) fp16 [50,331,648, 100,663,296)
    _Float16* hidA   = (_Float16*)(ws + 0);            // (B,340,N) fp16 overlay [0, 89,128,960)
    _Float16* gated  = (_Float16*)(ws + 89128960ull);  // (B,170,N) fp16, ends 133,693,440
    _Float16* wp_rsap= (_Float16*)(ws + 133693440ull); // 8,192 B
    _Float16* S2h    = (_Float16*)(ws + 134217728ull); // (B,64,N) fp16 = 16,777,216 B
    float*    part   = (float*)(ws + 167772160ull);    // 655,360
    float*    attn_s = (float*)(ws + 168427520ull);    // 16,384
    float*    weffb  = (float*)(ws + 168443904ull);    // 131,072
    _Float16* wp_rsa = (_Float16*)(ws + 168574976ull); // 24,576
    _Float16* wp_gsa = (_Float16*)(ws + 168599552ull); // 24,576
    _Float16* wp_fsi = (_Float16*)(ws + 168624128ull); // 45,056
    _Float16* wp_fci = (_Float16*)(ws + 168669184ull); // 45,056
    _Float16* wp_fso = (_Float16*)(ws + 168714240ull); // 24,576
    _Float16* wp_fco = (_Float16*)(ws + 168738816ull); // 24,576
    _Float16* wp_pbw = (_Float16*)(ws + 168763392ull); // 65,536 -> ends 168,828,928
    if (ws_size < 168828928ull) {
        int n = out_size < 4096 ? out_size : 4096;
        sentinel_kernel<<<16, 256, 0, stream>>>(outp, n);
        return;
    }

    dim3 blk256(256);

    wpack_kernel<<<24, 64, 0, stream>>>(rsa_qkv_w, 192, 64, 2, wp_rsa);
    wpack_kernel<<<24, 64, 0, stream>>>(gsa_qkv_w, 192, 64, 2, wp_gsa);
    wpack_kernel<<<44, 64, 0, stream>>>(ffs_in_w, 340, 64, 2, wp_fsi);
    wpack_kernel<<<44, 64, 0, stream>>>(ffc_in_w, 340, 64, 2, wp_fci);
    wpack_kernel<<<24, 64, 0, stream>>>(ffs_out_w, 64, 170, 6, wp_fso);
    wpack_kernel<<<24, 64, 0, stream>>>(ffc_out_w, 64, 170, 6, wp_fco);
    wpack_kernel<<<8, 64, 0, stream>>>(rsa_proj_w, 64, 64, 2, wp_rsap);

    // ---- spatial (RSA) half ----
    lngemm_kernel<6, 192, false, false><<<2048, blk256, 0, stream>>>(x, nullptr, ln_s0_w, ln_s0_b, wp_rsa, tmp192);
    dw16_kernel<true><<<dim3(8, B * 192), blk256, 0, stream>>>(tmp192, rsa_dw_w, Qbuf16);   // -> window-major
    rsa_win_kernel<<<2048, blk256, 0, stream>>>(Qbuf16, rsa_temp, wp_rsap, S2h);            // x_ spatial (fp16)
    lngemm_kernel<11, 340, true, true><<<2048, blk256, 0, stream>>>(S2h, x, ln_s2_w, ln_s2_b, wp_fsi, hidA);
    ffn_b_kernel<<<dim3(8, B * 170), blk256, 0, stream>>>(hidA, ffs_dw_w, gated);
    gemm_kernel<2, 6, 2, 2, 170, 64, 170, false, true, true>
        <<<2048, blk256, 0, stream>>>(gated, wp_fso, S2h, outp);                            // x -> d_out

    // ---- channel (GSA) half ----
    lngemm_kernel<6, 192, false, false><<<2048, blk256, 0, stream>>>(outp, nullptr, ln_c0_w, ln_c0_b, wp_gsa, tmp192);
    dw16_kernel<false><<<dim3(8, B * 192), blk256, 0, stream>>>(tmp192, gsa_dw_w, Qbuf16);  // linear
    gsa_part_kernel<<<dim3(32, 64), blk256, 0, stream>>>(Qbuf16, part);
    gsa_fin_kernel<<<64, dim3(128), 0, stream>>>(part, gsa_temp, attn_s);
    weff_kernel<<<8, dim3(64), 0, stream>>>(attn_s, gsa_proj_w, weffb);
    weffpack_kernel<<<8, dim3(512), 0, stream>>>(weffb, wp_pbw);
    gemm_kernel<4, 2, 1, 1, 64, 64, 192, true, false, false>
        <<<2048, blk256, 0, stream>>>(Qbuf16 + (size_t)128 * N, wp_pbw, nullptr, S2h);      // x_ channel (fp16)
    lngemm_kernel<11, 340, true, true><<<2048, blk256, 0, stream>>>(S2h, outp, ln_c2_w, ln_c2_b, wp_fci, hidA);
    ffn_b_kernel<<<dim3(8, B * 170), blk256, 0, stream>>>(hidA, ffc_dw_w, gated);
    gemm_kernel<2, 6, 2, 2, 170, 64, 170, false, true, true>
        <<<2048, blk256, 0, stream>>>(gated, wp_fco, S2h, outp);                            // final
}